// Round 1
// baseline (8096.703 us; speedup 1.0000x reference)
//
#include <hip/hip_runtime.h>
#include <hip/hip_bf16.h>

// ---------------------------------------------------------------------------
// FaceXHuBERT decoder: 2-layer GRU (H=256) over T=512 + fc to V=70110 with
// teacher-forcing feedback through red_w [A=768, V].
//
// Restructure so the T-loop never touches V:
//   OUT_G = red_w @ [vert^T | template^T]      (split-K bf16 MFMA, atomicAdd)
//   OUT_M = red_w @ [fc_w | fc_b]              (ditto)
//   Gf[r][a] = OUT_G[a][r] + red_b[a]  (r<1026; row 1026 = fbred+red_b)
//   P   = Gf @ Wr^T        (rows 0..1023 = P_t; 1024/1025 = c0term; 1026 = d2)
//   gihs= hs @ Wl^T + b_ih_l0
//   M2  = Wr @ (red_w@fc_w)            [768x256]
// In-loop: gi_l0 = gihs_t + (t==0 ? c0term : tf[t-1] ? P_{t-1} : h1@M2^T+d2)
// Final: preds = h1s @ fc_w^T + fc_b (bf16 MFMA) fused with MSE loss.
//
// MFMA layout assumption (16x16x32 bf16): A row=lane&15, k=(lane>>4)*8+elem
// (contiguous 8 per lane); C/D col=lane&15, row=(lane>>4)*4+reg (HW-verified).
// ---------------------------------------------------------------------------

#define TT 512
#define VD 70110
#define NR 1024  // B*T

using bf16x8 = __attribute__((ext_vector_type(8))) short;
using f32x4  = __attribute__((ext_vector_type(4))) float;

static __device__ __forceinline__ unsigned short f2bf(float f) {
  unsigned u = __float_as_uint(f);
  u += 0x7FFFu + ((u >> 16) & 1u);   // RNE
  return (unsigned short)(u >> 16);
}

// ---------------- big split-K GEMM over V (bf16 MFMA, atomicAdd epilogue) ---
// C[m][n] += sum_{k in chunk} A[m][k]*Bval(n,k);  A = red_w (lda == K)
// BFORM=false: Bval(n,k) = n<1024 ? vert[n*VD+k] : n<N ? tmpl[(n-1024)*VD+k] : 0
// BFORM=true : Bval(n,k) = n<256 ? fcw[k*256+n] : n==256 ? fcb[k] : 0
template<bool BFORM>
__global__ __launch_bounds__(512, 1)
void bigk_kernel(const float* __restrict__ A, const float* __restrict__ Bv,
                 const float* __restrict__ Bt, float* __restrict__ C, int ldc,
                 int M, int N, int K, int CHK)
{
  __shared__ unsigned short Al[256][40];
  __shared__ unsigned short Bl[256][40];
  const int tid = threadIdx.x;
  const int n0 = blockIdx.x * 256, m0 = blockIdx.y * 256;
  const int kc0 = blockIdx.z * CHK;
  const int kc1 = min(K, kc0 + CHK);
  const int wave = tid >> 6, lane = tid & 63;
  const int wm = wave >> 1, wn = wave & 1;
  const int kq = lane >> 4, ln = lane & 15;
  f32x4 acc[4][8] = {};
  for (int kc = kc0; kc < kc1; kc += 32) {
    __syncthreads();
    { // stage A: 256 rows x 32 k  (rows of red_w; stride VD is only 8B-aligned)
      const int m = tid >> 1, kh = (tid & 1) << 4;
      const bool mok = (m0 + m) < M;
      const float* arow = A + (long)(m0 + m) * (long)K;
      unsigned short tmp[16] __attribute__((aligned(16)));
      if (mok && (kc + 32 <= kc1)) {
        const float2* ap2 = (const float2*)(arow + kc + kh);
#pragma unroll
        for (int i = 0; i < 8; ++i) { float2 v = ap2[i]; tmp[2*i] = f2bf(v.x); tmp[2*i+1] = f2bf(v.y); }
      } else {
#pragma unroll
        for (int i = 0; i < 16; ++i) {
          int kk = kc + kh + i;
          tmp[i] = f2bf((mok && kk < kc1) ? arow[kk] : 0.f);
        }
      }
      ((int4*)&Al[m][kh])[0] = *(int4*)&tmp[0];
      ((int4*)&Al[m][kh])[1] = *(int4*)&tmp[8];
    }
    if (!BFORM) { // stage B from row-major rows (vert / template)
      const int n = tid >> 1, kh = (tid & 1) << 4;
      const int gn = n0 + n;
      const float* bp = nullptr;
      if (gn < 1024) bp = Bv + (long)gn * (long)VD;
      else if (gn < N) bp = Bt + (long)(gn - 1024) * (long)VD;
      unsigned short tmp[16] __attribute__((aligned(16)));
      if (bp && (kc + 32 <= kc1)) {
        const float2* bp2 = (const float2*)(bp + kc + kh);
#pragma unroll
        for (int i = 0; i < 8; ++i) { float2 v = bp2[i]; tmp[2*i] = f2bf(v.x); tmp[2*i+1] = f2bf(v.y); }
      } else {
#pragma unroll
        for (int i = 0; i < 16; ++i) {
          int kk = kc + kh + i;
          tmp[i] = f2bf((bp && kk < kc1) ? bp[kk] : 0.f);
        }
      }
      ((int4*)&Bl[n][kh])[0] = *(int4*)&tmp[0];
      ((int4*)&Bl[n][kh])[1] = *(int4*)&tmp[8];
    } else {      // stage B from k-major fc_w (transpose into LDS, coalesced n)
      const int n = tid & 255, kh = (tid >> 8) << 4;
      const int gn = n0 + n;
      unsigned short tmp[16] __attribute__((aligned(16)));
#pragma unroll
      for (int i = 0; i < 16; ++i) {
        int kk = kc + kh + i;
        float v = 0.f;
        if (kk < kc1) {
          if (gn < 256) v = Bv[(long)kk * 256 + gn];
          else if (gn == 256) v = Bt[kk];
        }
        tmp[i] = f2bf(v);
      }
      ((int4*)&Bl[n][kh])[0] = *(int4*)&tmp[0];
      ((int4*)&Bl[n][kh])[1] = *(int4*)&tmp[8];
    }
    __syncthreads();
    bf16x8 af[4], bfv[8];
#pragma unroll
    for (int i = 0; i < 4; ++i) af[i] = *(const bf16x8*)&Al[wm*64 + i*16 + ln][kq*8];
#pragma unroll
    for (int j = 0; j < 8; ++j) bfv[j] = *(const bf16x8*)&Bl[wn*128 + j*16 + ln][kq*8];
#pragma unroll
    for (int i = 0; i < 4; ++i)
#pragma unroll
      for (int j = 0; j < 8; ++j)
        acc[i][j] = __builtin_amdgcn_mfma_f32_16x16x32_bf16(af[i], bfv[j], acc[i][j], 0, 0, 0);
  }
#pragma unroll
  for (int i = 0; i < 4; ++i)
#pragma unroll
    for (int j = 0; j < 8; ++j)
#pragma unroll
      for (int r = 0; r < 4; ++r) {
        int gm = m0 + wm*64 + i*16 + kq*4 + r;
        int gn = n0 + wn*128 + j*16 + ln;
        if (gm < M && gn < N) unsafeAtomicAdd(&C[(long)gm * ldc + gn], acc[i][j][r]);
      }
}

// ---------------- generic 128x128 bf16-MFMA GEMM: C = A @ B^T (+bias) -------
// EPI==0: store (+bias if non-null). EPI==2: +bias, store to C(=d_out), and
// accumulate sum((C - vert)^2) into lossp[block].
template<int EPI>
__global__ __launch_bounds__(256, 2)
void gemm128(const float* __restrict__ A, int lda,
             const float* __restrict__ B, int ldb,
             float* __restrict__ C, long ldc,
             const float* __restrict__ bias,
             int M, int N, int K,
             const float* __restrict__ vert, float* __restrict__ lossp)
{
  __shared__ unsigned short Al[128][40];
  __shared__ unsigned short Bl[128][40];
  const int tid = threadIdx.x;
  const int m0 = blockIdx.x * 128, n0 = blockIdx.y * 128;
  const int wave = tid >> 6, lane = tid & 63;
  const int wm = wave >> 1, wn = wave & 1;
  const int kq = lane >> 4, ln = lane & 15;
  f32x4 acc[4][4] = {};
  for (int kc = 0; kc < K; kc += 32) {
    __syncthreads();
    {
      const int m = tid >> 1, kh = (tid & 1) << 4;
      unsigned short tmp[16] __attribute__((aligned(16)));
      const bool mok = (m0 + m) < M;
      if (mok) {
        const float4* ap4 = (const float4*)(A + (long)(m0 + m) * lda + kc + kh);
#pragma unroll
        for (int i = 0; i < 4; ++i) {
          float4 v = ap4[i];
          tmp[4*i+0] = f2bf(v.x); tmp[4*i+1] = f2bf(v.y);
          tmp[4*i+2] = f2bf(v.z); tmp[4*i+3] = f2bf(v.w);
        }
      } else {
#pragma unroll
        for (int i = 0; i < 16; ++i) tmp[i] = 0;
      }
      ((int4*)&Al[m][kh])[0] = *(int4*)&tmp[0];
      ((int4*)&Al[m][kh])[1] = *(int4*)&tmp[8];
      const int n = m;  // same mapping for B
      unsigned short tmb[16] __attribute__((aligned(16)));
      const bool nok = (n0 + n) < N;
      if (nok) {
        const float4* bp4 = (const float4*)(B + (long)(n0 + n) * ldb + kc + kh);
#pragma unroll
        for (int i = 0; i < 4; ++i) {
          float4 v = bp4[i];
          tmb[4*i+0] = f2bf(v.x); tmb[4*i+1] = f2bf(v.y);
          tmb[4*i+2] = f2bf(v.z); tmb[4*i+3] = f2bf(v.w);
        }
      } else {
#pragma unroll
        for (int i = 0; i < 16; ++i) tmb[i] = 0;
      }
      ((int4*)&Bl[n][kh])[0] = *(int4*)&tmb[0];
      ((int4*)&Bl[n][kh])[1] = *(int4*)&tmb[8];
    }
    __syncthreads();
    bf16x8 af[4], bfv[4];
#pragma unroll
    for (int i = 0; i < 4; ++i) af[i]  = *(const bf16x8*)&Al[wm*64 + i*16 + ln][kq*8];
#pragma unroll
    for (int j = 0; j < 4; ++j) bfv[j] = *(const bf16x8*)&Bl[wn*64 + j*16 + ln][kq*8];
#pragma unroll
    for (int i = 0; i < 4; ++i)
#pragma unroll
      for (int j = 0; j < 4; ++j)
        acc[i][j] = __builtin_amdgcn_mfma_f32_16x16x32_bf16(af[i], bfv[j], acc[i][j], 0, 0, 0);
  }
  float ls = 0.f;
#pragma unroll
  for (int i = 0; i < 4; ++i)
#pragma unroll
    for (int j = 0; j < 4; ++j)
#pragma unroll
      for (int r = 0; r < 4; ++r) {
        const int gm = m0 + wm*64 + i*16 + kq*4 + r;
        const int gn = n0 + wn*64 + j*16 + ln;
        if (gm < M && gn < N) {
          float v = acc[i][j][r];
          if (bias) v += bias[gn];
          C[(long)gm * ldc + gn] = v;
          if (EPI == 2) { float d = v - vert[(long)gm * VD + gn]; ls += d * d; }
        }
      }
  if (EPI == 2) {
#pragma unroll
    for (int o = 32; o > 0; o >>= 1) ls += __shfl_down(ls, o);
    __shared__ float wred[4];
    if ((tid & 63) == 0) wred[wave] = ls;
    __syncthreads();
    if (tid == 0) lossp[blockIdx.y * gridDim.x + blockIdx.x] = wred[0] + wred[1] + wred[2] + wred[3];
  }
}

// ---------------- transpose with optional bias: dst[r][c] = src[c][row0+r]+b[c]
__global__ void transpose_bias(const float* __restrict__ src, int lds, int row0,
                               float* __restrict__ dst, int ldd,
                               int rows, int cols, const float* __restrict__ bias)
{
  __shared__ float tile[32][33];
  const int rb = blockIdx.x * 32, cb = blockIdx.y * 32;
  const int tx = threadIdx.x & 31, ty = threadIdx.x >> 5;
  for (int yy = ty; yy < 32; yy += 8) {
    int c = cb + yy, r = rb + tx;
    tile[yy][tx] = (c < cols && r < rows) ? src[(long)c * lds + row0 + r] : 0.f;
  }
  __syncthreads();
  for (int yy = ty; yy < 32; yy += 8) {
    int r = rb + yy, c = cb + tx;
    if (r < rows && c < cols)
      dst[(long)r * ldd + c] = tile[tx][yy] + (bias ? bias[c] : 0.f);
  }
}

// ---------------- persistent sequential GRU kernel (32 WGs, 1/CU) -----------
__device__ __forceinline__ void flag_barrier(unsigned* __restrict__ seqf, int wg, unsigned target) {
  __syncthreads();
  const int tid = threadIdx.x;
  if (tid == 0) {
    __threadfence();
    __hip_atomic_store(&seqf[wg * 16], target, __ATOMIC_RELEASE, __HIP_MEMORY_SCOPE_AGENT);
  }
  if (tid < 32) {
    int spins = 0;
    while (__hip_atomic_load(&seqf[tid * 16], __ATOMIC_ACQUIRE, __HIP_MEMORY_SCOPE_AGENT) < target) {
      __builtin_amdgcn_s_sleep(1);
      if (++spins > (1 << 18)) break;   // fail fast rather than hang
    }
  }
  __syncthreads();
  __threadfence();   // invalidate L1 so following global reads see peers' data
}

#define RUN_DOTS(W0, W1, H0, H1)                                              \
  {                                                                           \
    _Pragma("unroll")                                                         \
    for (int pass = 0; pass < 6; ++pass) {                                    \
      const int D = pass * 16 + wave * 4 + dsub;                              \
      const int mat = (D >= 48) ? 1 : 0;                                      \
      const int rem = D - mat * 48;                                           \
      const int row = rem >> 1, bb = rem & 1;                                 \
      const float4* w4 = (const float4*)(mat ? W1[row] : W0[row]);            \
      const float4* h4 = (const float4*)(mat ? H1[bb] : H0[bb]);              \
      float s = 0.f;                                                          \
      _Pragma("unroll")                                                       \
      for (int i = 0; i < 4; ++i) {                                           \
        const float4 a = w4[kl * 4 + i], h = h4[kl * 4 + i];                  \
        s += a.x * h.x + a.y * h.y + a.z * h.z + a.w * h.w;                   \
      }                                                                       \
      s += __shfl_xor(s, 1); s += __shfl_xor(s, 2);                           \
      s += __shfl_xor(s, 4); s += __shfl_xor(s, 8);                           \
      if (kl == 0) dotsS[mat][bb][row >> 3][row & 7] = s;                     \
    }                                                                         \
  }

__global__ __launch_bounds__(256, 1)
void k3_seq(const float* __restrict__ gihs, const float* __restrict__ Pm,
            const float* __restrict__ M2m,
            const float* __restrict__ whh0, const float* __restrict__ bhh0,
            const float* __restrict__ wih1, const float* __restrict__ bih1,
            const float* __restrict__ whh1, const float* __restrict__ bhh1,
            const int* __restrict__ tfm,
            float* __restrict__ h1s, float* __restrict__ h0g, float* __restrict__ h1g,
            unsigned* __restrict__ seqf)
{
  __shared__ float wq[24][260], wh0s[24][260], wi1s[24][260], wh1s[24][260];
  __shared__ float h0c[2][256], h1c[2][256];
  __shared__ float dotsS[2][2][3][8];
  __shared__ int tfl[TT];
  const int tid = threadIdx.x;
  const int wg = blockIdx.x;
  const int j0 = wg * 8;           // this WG owns h dims [j0, j0+8)

  for (int row = 0; row < 24; ++row) {
    const int g = row >> 3, jj = row & 7;
    const long gr = g * 256 + j0 + jj;
    wq[row][tid]   = M2m[gr * 256 + tid];
    wh0s[row][tid] = whh0[gr * 256 + tid];
    wi1s[row][tid] = wih1[gr * 256 + tid];
    wh1s[row][tid] = whh1[gr * 256 + tid];
  }
  ((float*)h0c)[tid] = 0.f; ((float*)h0c)[tid + 256] = 0.f;
  ((float*)h1c)[tid] = 0.f; ((float*)h1c)[tid + 256] = 0.f;
  for (int t = tid; t < TT; t += 256) tfl[t] = tfm[t];

  const int cb = tid >> 3, cjj = tid & 7, cj = j0 + cjj;   // combine threads (tid<16)
  float bh0v[3], bi1v[3], bh1v[3], d2v[3];
  if (tid < 16) {
#pragma unroll
    for (int g = 0; g < 3; ++g) {
      bh0v[g] = bhh0[g*256 + cj];
      bi1v[g] = bih1[g*256 + cj];
      bh1v[g] = bhh1[g*256 + cj];
      d2v[g]  = Pm[(long)1026 * 768 + g*256 + cj];
    }
  }
  __syncthreads();

  const int wave = tid >> 6, dsub = (tid >> 4) & 3, kl = tid & 15;
  unsigned bt = 0;
  for (int t = 0; t < TT; ++t) {
    // prefetch combine inputs (independent of dots)
    float gihsv[3], piv[3];
    if (tid < 16) {
      const long r = (long)cb * TT + t;
      const long prow = (t == 0) ? (1024 + cb) : ((long)cb * TT + (t - 1));
#pragma unroll
      for (int g = 0; g < 3; ++g) {
        gihsv[g] = gihs[r * 768 + g*256 + cj];
        piv[g]   = Pm[prow * 768 + g*256 + cj];
      }
    }
    // phase 0: q = h1_prev @ M2^T ; gh = h0_prev @ whh0^T
    RUN_DOTS(wq, wh0s, h1c, h0c);
    __syncthreads();
    if (tid < 16) {
      const int tfprev = (t == 0) ? 1 : tfl[t - 1];
      float gi[3], gh[3];
#pragma unroll
      for (int g = 0; g < 3; ++g) {
        const float q = dotsS[0][cb][g][cjj] + d2v[g];
        gi[g] = gihsv[g] + (tfprev ? piv[g] : q);
        gh[g] = dotsS[1][cb][g][cjj] + bh0v[g];
      }
      const float rr = 1.f / (1.f + __expf(-(gi[0] + gh[0])));
      const float zz = 1.f / (1.f + __expf(-(gi[1] + gh[1])));
      const float nn = tanhf(gi[2] + rr * gh[2]);
      const float h0n = (1.f - zz) * nn + zz * h0c[cb][cj];
      h0g[(t & 1) * 512 + cb * 256 + cj] = h0n;
    }
    flag_barrier(seqf, wg, ++bt);
    ((float*)h0c)[tid]       = h0g[(t & 1) * 512 + tid];
    ((float*)h0c)[tid + 256] = h0g[(t & 1) * 512 + tid + 256];
    __syncthreads();
    // phase 1: gi1 = h0_new @ wih1^T ; gh1 = h1_prev @ whh1^T
    RUN_DOTS(wi1s, wh1s, h0c, h1c);
    __syncthreads();
    if (tid < 16) {
      float gi[3], gh[3];
#pragma unroll
      for (int g = 0; g < 3; ++g) {
        gi[g] = dotsS[0][cb][g][cjj] + bi1v[g];
        gh[g] = dotsS[1][cb][g][cjj] + bh1v[g];
      }
      const float rr = 1.f / (1.f + __expf(-(gi[0] + gh[0])));
      const float zz = 1.f / (1.f + __expf(-(gi[1] + gh[1])));
      const float nn = tanhf(gi[2] + rr * gh[2]);
      const float h1n = (1.f - zz) * nn + zz * h1c[cb][cj];
      h1g[(t & 1) * 512 + cb * 256 + cj] = h1n;
      h1s[((long)cb * TT + t) * 256 + cj] = h1n;
    }
    flag_barrier(seqf, wg, ++bt);
    ((float*)h1c)[tid]       = h1g[(t & 1) * 512 + tid];
    ((float*)h1c)[tid + 256] = h1g[(t & 1) * 512 + tid + 256];
    __syncthreads();
  }
}

__global__ void loss_finalize(const float* __restrict__ lossp, int n, float* __restrict__ out) {
  __shared__ float red[256];
  float s = 0.f;
  for (int i = threadIdx.x; i < n; i += 256) s += lossp[i];
  red[threadIdx.x] = s;
  __syncthreads();
  for (int st = 128; st > 0; st >>= 1) {
    if (threadIdx.x < st) red[threadIdx.x] += red[threadIdx.x + st];
    __syncthreads();
  }
  if (threadIdx.x == 0) out[0] = red[0] * (1.0f / 71792640.0f);
}

// ---------------------------------------------------------------------------
extern "C" void kernel_launch(void* const* d_in, const int* in_sizes, int n_in,
                              void* d_out, int out_size, void* d_ws, size_t ws_size,
                              hipStream_t stream) {
  (void)in_sizes; (void)n_in; (void)out_size; (void)ws_size;
  const float* hs   = (const float*)d_in[0];
  const float* tmpl = (const float*)d_in[1];
  const float* vert = (const float*)d_in[2];
  const int*   tfm  = (const int*)  d_in[3];
  const float* wih0 = (const float*)d_in[4];
  const float* whh0 = (const float*)d_in[5];
  const float* bih0 = (const float*)d_in[6];
  const float* bhh0 = (const float*)d_in[7];
  const float* wih1 = (const float*)d_in[8];
  const float* whh1 = (const float*)d_in[9];
  const float* bih1 = (const float*)d_in[10];
  const float* bhh1 = (const float*)d_in[11];
  const float* fcw  = (const float*)d_in[12];
  const float* fcb  = (const float*)d_in[13];
  const float* redw = (const float*)d_in[14];
  const float* redb = (const float*)d_in[15];
  float* out = (float*)d_out;

  char* ws = (char*)d_ws;
  float*    OUTG  = (float*)(ws + 0);          // [768][1026] = G^T (no red_b)
  float*    OUTM  = (float*)(ws + 3151872);    // [768][257]  = [M | fbred]
  unsigned* SEQ   = (unsigned*)(ws + 3941376); // 32 flags, 64B apart
  float*    GF    = (float*)(ws + 3943424);    // [1027][768]
  float*    MT    = (float*)(ws + 7098368);    // [256][768]  = M^T
  float*    GIHS  = (float*)(ws + 7884800);    // [1024][768]
  float*    PM    = (float*)(ws + 11030528);   // [1027][768]
  float*    M2    = (float*)(ws + 14185472);   // [768][256]
  float*    H1S   = (float*)(ws + 14971904);   // [1024][256]
  float*    H0G   = (float*)(ws + 16020480);   // [2][512]
  float*    H1G   = (float*)(ws + 16024576);   // [2][512]
  float*    LOSSP = (float*)(ws + 16028672);   // [4384]

  // zero split-K accumulators + barrier flags (must happen every call)
  hipMemsetAsync(d_ws, 0, 3943424, stream);

  // big V-contractions (split-K, 24 chunks of 2922)
  bigk_kernel<false><<<dim3(5, 3, 24), 512, 0, stream>>>(redw, vert, tmpl, OUTG, 1026, 768, 1026, VD, 2922);
  bigk_kernel<true ><<<dim3(2, 3, 24), 512, 0, stream>>>(redw, fcw,  fcb,  OUTM, 257,  768, 257,  VD, 2922);

  // transposes (+red_b fold)
  transpose_bias<<<dim3(33, 24), 256, 0, stream>>>(OUTG, 1026, 0,   GF,                 768, 1026, 768, redb);
  transpose_bias<<<dim3(8, 24),  256, 0, stream>>>(OUTM, 257,  0,   MT,                 768, 256,  768, nullptr);
  transpose_bias<<<dim3(1, 24),  256, 0, stream>>>(OUTM, 257,  256, GF + (long)1026*768, 768, 1,   768, redb);

  // small GEMMs: gihs, P (incl. c0term rows 1024/1025 and d2 row 1026), M2
  gemm128<0><<<dim3(8, 6), 256, 0, stream>>>(hs,        768,  wih0,       1536, GIHS, 768, bih0,    1024, 768, 768, nullptr, nullptr);
  gemm128<0><<<dim3(9, 6), 256, 0, stream>>>(GF,        768,  wih0 + 768, 1536, PM,   768, nullptr, 1027, 768, 768, nullptr, nullptr);
  gemm128<0><<<dim3(6, 2), 256, 0, stream>>>(wih0 + 768, 1536, MT,        768,  M2,   256, nullptr, 768,  256, 768, nullptr, nullptr);

  // sequential recurrence (persistent, 32 WGs)
  k3_seq<<<32, 256, 0, stream>>>(GIHS, PM, M2, whh0, bhh0, wih1, bih1, whh1, bhh1,
                                 tfm, H1S, H0G, H1G, SEQ);

  // final fc GEMM + fused MSE partials, then loss
  gemm128<2><<<dim3(8, 548), 256, 0, stream>>>(H1S, 256, fcw, 256, out, VD, fcb, 1024, VD, 256, vert, LOSSP);
  loss_finalize<<<1, 256, 0, stream>>>(LOSSP, 4384, out + 71792640L);
}

// Round 2
// 5296.133 us; speedup vs baseline: 1.5288x; 1.5288x over previous
//
#include <hip/hip_runtime.h>
#include <hip/hip_bf16.h>

// ---------------------------------------------------------------------------
// FaceXHuBERT decoder: 2-layer GRU (H=256) over T=512 + fc to V=70110 with
// teacher-forcing feedback through red_w [A=768, V].
//
// Restructure so the T-loop never touches V:
//   OUT_G = red_w @ [vert^T | template^T]      (split-K bf16 MFMA, atomicAdd)
//   OUT_M = red_w @ [fc_w | fc_b]              (ditto)
//   Gf[r][a] = OUT_G[a][r] + red_b[a]  (r<1026; row 1026 = fbred+red_b)
//   P   = Gf @ Wr^T        (rows 0..1023 = P_t; 1024/1025 = c0term; 1026 = d2)
//   gihs= hs @ Wl^T + b_ih_l0
//   M2  = Wr @ (red_w@fc_w)            [768x256]
// In-loop: gi_l0 = gihs_t + (t==0 ? c0term : tf[t-1] ? P_{t-1} : h1@M2^T+d2)
// Final: preds = h1s @ fc_w^T + fc_b (bf16 MFMA) fused with MSE loss.
//
// Round 2: cross-WG sync rebuilt on fence-free relaxed agent atomics (sc1,
// cache-bypassing) — the old __threadfence() pair cost a full L2 wb/inv per
// phase (6.4 us/barrier). Data-before-flag ordering via wave-local
// s_waitcnt vmcnt(0). Also fixed 8-way LDS bank conflict in RUN_DOTS.
// ---------------------------------------------------------------------------

#define TT 512
#define VD 70110
#define NR 1024  // B*T

using bf16x8 = __attribute__((ext_vector_type(8))) short;
using f32x4  = __attribute__((ext_vector_type(4))) float;

static __device__ __forceinline__ unsigned short f2bf(float f) {
  unsigned u = __float_as_uint(f);
  u += 0x7FFFu + ((u >> 16) & 1u);   // RNE
  return (unsigned short)(u >> 16);
}

// ---------------- big split-K GEMM over V (bf16 MFMA, atomicAdd epilogue) ---
// C[m][n] += sum_{k in chunk} A[m][k]*Bval(n,k);  A = red_w (lda == K)
// BFORM=false: Bval(n,k) = n<1024 ? vert[n*VD+k] : n<N ? tmpl[(n-1024)*VD+k] : 0
// BFORM=true : Bval(n,k) = n<256 ? fcw[k*256+n] : n==256 ? fcb[k] : 0
template<bool BFORM>
__global__ __launch_bounds__(512, 1)
void bigk_kernel(const float* __restrict__ A, const float* __restrict__ Bv,
                 const float* __restrict__ Bt, float* __restrict__ C, int ldc,
                 int M, int N, int K, int CHK)
{
  __shared__ unsigned short Al[256][40];
  __shared__ unsigned short Bl[256][40];
  const int tid = threadIdx.x;
  const int n0 = blockIdx.x * 256, m0 = blockIdx.y * 256;
  const int kc0 = blockIdx.z * CHK;
  const int kc1 = min(K, kc0 + CHK);
  const int wave = tid >> 6, lane = tid & 63;
  const int wm = wave >> 1, wn = wave & 1;
  const int kq = lane >> 4, ln = lane & 15;
  f32x4 acc[4][8] = {};
  for (int kc = kc0; kc < kc1; kc += 32) {
    __syncthreads();
    { // stage A: 256 rows x 32 k  (rows of red_w; stride VD is only 8B-aligned)
      const int m = tid >> 1, kh = (tid & 1) << 4;
      const bool mok = (m0 + m) < M;
      const float* arow = A + (long)(m0 + m) * (long)K;
      unsigned short tmp[16] __attribute__((aligned(16)));
      if (mok && (kc + 32 <= kc1)) {
        const float2* ap2 = (const float2*)(arow + kc + kh);
#pragma unroll
        for (int i = 0; i < 8; ++i) { float2 v = ap2[i]; tmp[2*i] = f2bf(v.x); tmp[2*i+1] = f2bf(v.y); }
      } else {
#pragma unroll
        for (int i = 0; i < 16; ++i) {
          int kk = kc + kh + i;
          tmp[i] = f2bf((mok && kk < kc1) ? arow[kk] : 0.f);
        }
      }
      ((int4*)&Al[m][kh])[0] = *(int4*)&tmp[0];
      ((int4*)&Al[m][kh])[1] = *(int4*)&tmp[8];
    }
    if (!BFORM) { // stage B from row-major rows (vert / template)
      const int n = tid >> 1, kh = (tid & 1) << 4;
      const int gn = n0 + n;
      const float* bp = nullptr;
      if (gn < 1024) bp = Bv + (long)gn * (long)VD;
      else if (gn < N) bp = Bt + (long)(gn - 1024) * (long)VD;
      unsigned short tmp[16] __attribute__((aligned(16)));
      if (bp && (kc + 32 <= kc1)) {
        const float2* bp2 = (const float2*)(bp + kc + kh);
#pragma unroll
        for (int i = 0; i < 8; ++i) { float2 v = bp2[i]; tmp[2*i] = f2bf(v.x); tmp[2*i+1] = f2bf(v.y); }
      } else {
#pragma unroll
        for (int i = 0; i < 16; ++i) {
          int kk = kc + kh + i;
          tmp[i] = f2bf((bp && kk < kc1) ? bp[kk] : 0.f);
        }
      }
      ((int4*)&Bl[n][kh])[0] = *(int4*)&tmp[0];
      ((int4*)&Bl[n][kh])[1] = *(int4*)&tmp[8];
    } else {      // stage B from k-major fc_w (transpose into LDS, coalesced n)
      const int n = tid & 255, kh = (tid >> 8) << 4;
      const int gn = n0 + n;
      unsigned short tmp[16] __attribute__((aligned(16)));
#pragma unroll
      for (int i = 0; i < 16; ++i) {
        int kk = kc + kh + i;
        float v = 0.f;
        if (kk < kc1) {
          if (gn < 256) v = Bv[(long)kk * 256 + gn];
          else if (gn == 256) v = Bt[kk];
        }
        tmp[i] = f2bf(v);
      }
      ((int4*)&Bl[n][kh])[0] = *(int4*)&tmp[0];
      ((int4*)&Bl[n][kh])[1] = *(int4*)&tmp[8];
    }
    __syncthreads();
    bf16x8 af[4], bfv[8];
#pragma unroll
    for (int i = 0; i < 4; ++i) af[i] = *(const bf16x8*)&Al[wm*64 + i*16 + ln][kq*8];
#pragma unroll
    for (int j = 0; j < 8; ++j) bfv[j] = *(const bf16x8*)&Bl[wn*128 + j*16 + ln][kq*8];
#pragma unroll
    for (int i = 0; i < 4; ++i)
#pragma unroll
      for (int j = 0; j < 8; ++j)
        acc[i][j] = __builtin_amdgcn_mfma_f32_16x16x32_bf16(af[i], bfv[j], acc[i][j], 0, 0, 0);
  }
#pragma unroll
  for (int i = 0; i < 4; ++i)
#pragma unroll
    for (int j = 0; j < 8; ++j)
#pragma unroll
      for (int r = 0; r < 4; ++r) {
        int gm = m0 + wm*64 + i*16 + kq*4 + r;
        int gn = n0 + wn*128 + j*16 + ln;
        if (gm < M && gn < N) unsafeAtomicAdd(&C[(long)gm * ldc + gn], acc[i][j][r]);
      }
}

// ---------------- generic 128x128 bf16-MFMA GEMM: C = A @ B^T (+bias) -------
// EPI==0: store (+bias if non-null). EPI==2: +bias, store to C(=d_out), and
// accumulate sum((C - vert)^2) into lossp[block].
template<int EPI>
__global__ __launch_bounds__(256, 2)
void gemm128(const float* __restrict__ A, int lda,
             const float* __restrict__ B, int ldb,
             float* __restrict__ C, long ldc,
             const float* __restrict__ bias,
             int M, int N, int K,
             const float* __restrict__ vert, float* __restrict__ lossp)
{
  __shared__ unsigned short Al[128][40];
  __shared__ unsigned short Bl[128][40];
  const int tid = threadIdx.x;
  const int m0 = blockIdx.x * 128, n0 = blockIdx.y * 128;
  const int wave = tid >> 6, lane = tid & 63;
  const int wm = wave >> 1, wn = wave & 1;
  const int kq = lane >> 4, ln = lane & 15;
  f32x4 acc[4][4] = {};
  for (int kc = 0; kc < K; kc += 32) {
    __syncthreads();
    {
      const int m = tid >> 1, kh = (tid & 1) << 4;
      unsigned short tmp[16] __attribute__((aligned(16)));
      const bool mok = (m0 + m) < M;
      if (mok) {
        const float4* ap4 = (const float4*)(A + (long)(m0 + m) * lda + kc + kh);
#pragma unroll
        for (int i = 0; i < 4; ++i) {
          float4 v = ap4[i];
          tmp[4*i+0] = f2bf(v.x); tmp[4*i+1] = f2bf(v.y);
          tmp[4*i+2] = f2bf(v.z); tmp[4*i+3] = f2bf(v.w);
        }
      } else {
#pragma unroll
        for (int i = 0; i < 16; ++i) tmp[i] = 0;
      }
      ((int4*)&Al[m][kh])[0] = *(int4*)&tmp[0];
      ((int4*)&Al[m][kh])[1] = *(int4*)&tmp[8];
      const int n = m;  // same mapping for B
      unsigned short tmb[16] __attribute__((aligned(16)));
      const bool nok = (n0 + n) < N;
      if (nok) {
        const float4* bp4 = (const float4*)(B + (long)(n0 + n) * ldb + kc + kh);
#pragma unroll
        for (int i = 0; i < 4; ++i) {
          float4 v = bp4[i];
          tmb[4*i+0] = f2bf(v.x); tmb[4*i+1] = f2bf(v.y);
          tmb[4*i+2] = f2bf(v.z); tmb[4*i+3] = f2bf(v.w);
        }
      } else {
#pragma unroll
        for (int i = 0; i < 16; ++i) tmb[i] = 0;
      }
      ((int4*)&Bl[n][kh])[0] = *(int4*)&tmb[0];
      ((int4*)&Bl[n][kh])[1] = *(int4*)&tmb[8];
    }
    __syncthreads();
    bf16x8 af[4], bfv[4];
#pragma unroll
    for (int i = 0; i < 4; ++i) af[i]  = *(const bf16x8*)&Al[wm*64 + i*16 + ln][kq*8];
#pragma unroll
    for (int j = 0; j < 4; ++j) bfv[j] = *(const bf16x8*)&Bl[wn*64 + j*16 + ln][kq*8];
#pragma unroll
    for (int i = 0; i < 4; ++i)
#pragma unroll
      for (int j = 0; j < 4; ++j)
        acc[i][j] = __builtin_amdgcn_mfma_f32_16x16x32_bf16(af[i], bfv[j], acc[i][j], 0, 0, 0);
  }
  float ls = 0.f;
#pragma unroll
  for (int i = 0; i < 4; ++i)
#pragma unroll
    for (int j = 0; j < 4; ++j)
#pragma unroll
      for (int r = 0; r < 4; ++r) {
        const int gm = m0 + wm*64 + i*16 + kq*4 + r;
        const int gn = n0 + wn*64 + j*16 + ln;
        if (gm < M && gn < N) {
          float v = acc[i][j][r];
          if (bias) v += bias[gn];
          C[(long)gm * ldc + gn] = v;
          if (EPI == 2) { float d = v - vert[(long)gm * VD + gn]; ls += d * d; }
        }
      }
  if (EPI == 2) {
#pragma unroll
    for (int o = 32; o > 0; o >>= 1) ls += __shfl_down(ls, o);
    __shared__ float wred[4];
    if ((tid & 63) == 0) wred[wave] = ls;
    __syncthreads();
    if (tid == 0) lossp[blockIdx.y * gridDim.x + blockIdx.x] = wred[0] + wred[1] + wred[2] + wred[3];
  }
}

// ---------------- transpose with optional bias: dst[r][c] = src[c][row0+r]+b[c]
__global__ void transpose_bias(const float* __restrict__ src, int lds, int row0,
                               float* __restrict__ dst, int ldd,
                               int rows, int cols, const float* __restrict__ bias)
{
  __shared__ float tile[32][33];
  const int rb = blockIdx.x * 32, cb = blockIdx.y * 32;
  const int tx = threadIdx.x & 31, ty = threadIdx.x >> 5;
  for (int yy = ty; yy < 32; yy += 8) {
    int c = cb + yy, r = rb + tx;
    tile[yy][tx] = (c < cols && r < rows) ? src[(long)c * lds + row0 + r] : 0.f;
  }
  __syncthreads();
  for (int yy = ty; yy < 32; yy += 8) {
    int r = rb + yy, c = cb + tx;
    if (r < rows && c < cols)
      dst[(long)r * ldd + c] = tile[tx][yy] + (bias ? bias[c] : 0.f);
  }
}

// ---------------- persistent sequential GRU kernel (32 WGs, 1/CU) -----------
// Fence-free barrier: all cross-WG data moves via relaxed AGENT-scope atomics
// (sc1, cache-bypassing -> cross-XCD coherence point). Ordering of
// data-before-flag is a wave-local s_waitcnt vmcnt(0) (data stores and the
// flag store are both issued by wave 0). No __threadfence (no L2 wb/inv).
__device__ __forceinline__ void flag_barrier(unsigned* __restrict__ seqf, int wg, unsigned target) {
  __syncthreads();
  const int tid = threadIdx.x;
  if (tid == 0) {
    asm volatile("s_waitcnt vmcnt(0)" ::: "memory");
    __hip_atomic_store(&seqf[wg * 16], target, __ATOMIC_RELAXED, __HIP_MEMORY_SCOPE_AGENT);
  }
  if (tid < 32) {
    int spins = 0;
    while (__hip_atomic_load(&seqf[tid * 16], __ATOMIC_RELAXED, __HIP_MEMORY_SCOPE_AGENT) < target) {
      if (++spins > (1 << 14)) break;   // fail fast rather than hang
    }
  }
  __syncthreads();
}

// Conflict-free LDS dot: 16 lanes (kl) read 256 contiguous bytes per i-step.
#define RUN_DOTS(W0, W1, H0, H1)                                              \
  {                                                                           \
    _Pragma("unroll")                                                         \
    for (int pass = 0; pass < 6; ++pass) {                                    \
      const int D = pass * 16 + wave * 4 + dsub;                              \
      const int mat = (D >= 48) ? 1 : 0;                                      \
      const int rem = D - mat * 48;                                           \
      const int row = rem >> 1, bb = rem & 1;                                 \
      const float4* w4 = (const float4*)(mat ? W1[row] : W0[row]);            \
      const float4* h4 = (const float4*)(mat ? H1[bb] : H0[bb]);              \
      float s = 0.f;                                                          \
      _Pragma("unroll")                                                       \
      for (int i = 0; i < 4; ++i) {                                           \
        const float4 a = w4[i * 16 + kl], h = h4[i * 16 + kl];                \
        s += a.x * h.x + a.y * h.y + a.z * h.z + a.w * h.w;                   \
      }                                                                       \
      s += __shfl_xor(s, 1); s += __shfl_xor(s, 2);                           \
      s += __shfl_xor(s, 4); s += __shfl_xor(s, 8);                           \
      if (kl == 0) dotsS[mat][bb][row >> 3][row & 7] = s;                     \
    }                                                                         \
  }

__global__ __launch_bounds__(256, 1)
void k3_seq(const float* __restrict__ gihs, const float* __restrict__ Pm,
            const float* __restrict__ M2m,
            const float* __restrict__ whh0, const float* __restrict__ bhh0,
            const float* __restrict__ wih1, const float* __restrict__ bih1,
            const float* __restrict__ whh1, const float* __restrict__ bhh1,
            const int* __restrict__ tfm,
            float* __restrict__ h1s, float* __restrict__ h0g, float* __restrict__ h1g,
            unsigned* __restrict__ seqf)
{
  __shared__ float wq[24][260], wh0s[24][260], wi1s[24][260], wh1s[24][260];
  __shared__ float h0c[2][256], h1c[2][256];
  __shared__ float dotsS[2][2][3][8];
  __shared__ int tfl[TT];
  const int tid = threadIdx.x;
  const int wg = blockIdx.x;
  const int j0 = wg * 8;           // this WG owns h dims [j0, j0+8)

  for (int row = 0; row < 24; ++row) {
    const int g = row >> 3, jj = row & 7;
    const long gr = g * 256 + j0 + jj;
    wq[row][tid]   = M2m[gr * 256 + tid];
    wh0s[row][tid] = whh0[gr * 256 + tid];
    wi1s[row][tid] = wih1[gr * 256 + tid];
    wh1s[row][tid] = whh1[gr * 256 + tid];
  }
  ((float*)h0c)[tid] = 0.f; ((float*)h0c)[tid + 256] = 0.f;
  ((float*)h1c)[tid] = 0.f; ((float*)h1c)[tid + 256] = 0.f;
  for (int t = tid; t < TT; t += 256) tfl[t] = tfm[t];

  const int cb = tid >> 3, cjj = tid & 7, cj = j0 + cjj;   // combine threads (tid<16)
  float bh0v[3], bi1v[3], bh1v[3], d2v[3];
  if (tid < 16) {
#pragma unroll
    for (int g = 0; g < 3; ++g) {
      bh0v[g] = bhh0[g*256 + cj];
      bi1v[g] = bih1[g*256 + cj];
      bh1v[g] = bhh1[g*256 + cj];
      d2v[g]  = Pm[(long)1026 * 768 + g*256 + cj];
    }
  }
  __syncthreads();

  const int wave = tid >> 6, dsub = (tid >> 4) & 3, kl = tid & 15;
  unsigned bt = 0;
  for (int t = 0; t < TT; ++t) {
    // prefetch combine inputs (independent of dots)
    float gihsv[3], piv[3];
    if (tid < 16) {
      const long r = (long)cb * TT + t;
      const long prow = (t == 0) ? (1024 + cb) : ((long)cb * TT + (t - 1));
#pragma unroll
      for (int g = 0; g < 3; ++g) {
        gihsv[g] = gihs[r * 768 + g*256 + cj];
        piv[g]   = Pm[prow * 768 + g*256 + cj];
      }
    }
    // phase 0: q = h1_prev @ M2^T ; gh = h0_prev @ whh0^T
    RUN_DOTS(wq, wh0s, h1c, h0c);
    __syncthreads();
    if (tid < 16) {
      const int tfprev = (t == 0) ? 1 : tfl[t - 1];
      float gi[3], gh[3];
#pragma unroll
      for (int g = 0; g < 3; ++g) {
        const float q = dotsS[0][cb][g][cjj] + d2v[g];
        gi[g] = gihsv[g] + (tfprev ? piv[g] : q);
        gh[g] = dotsS[1][cb][g][cjj] + bh0v[g];
      }
      const float rr = 1.f / (1.f + __expf(-(gi[0] + gh[0])));
      const float zz = 1.f / (1.f + __expf(-(gi[1] + gh[1])));
      const float nn = tanhf(gi[2] + rr * gh[2]);
      const float h0n = (1.f - zz) * nn + zz * h0c[cb][cj];
      __hip_atomic_store(&h0g[(t & 1) * 512 + cb * 256 + cj], h0n,
                         __ATOMIC_RELAXED, __HIP_MEMORY_SCOPE_AGENT);
    }
    flag_barrier(seqf, wg, ++bt);
    ((float*)h0c)[tid]       = __hip_atomic_load(&h0g[(t & 1) * 512 + tid],
                                                 __ATOMIC_RELAXED, __HIP_MEMORY_SCOPE_AGENT);
    ((float*)h0c)[tid + 256] = __hip_atomic_load(&h0g[(t & 1) * 512 + tid + 256],
                                                 __ATOMIC_RELAXED, __HIP_MEMORY_SCOPE_AGENT);
    __syncthreads();
    // phase 1: gi1 = h0_new @ wih1^T ; gh1 = h1_prev @ whh1^T
    RUN_DOTS(wi1s, wh1s, h0c, h1c);
    __syncthreads();
    if (tid < 16) {
      float gi[3], gh[3];
#pragma unroll
      for (int g = 0; g < 3; ++g) {
        gi[g] = dotsS[0][cb][g][cjj] + bi1v[g];
        gh[g] = dotsS[1][cb][g][cjj] + bh1v[g];
      }
      const float rr = 1.f / (1.f + __expf(-(gi[0] + gh[0])));
      const float zz = 1.f / (1.f + __expf(-(gi[1] + gh[1])));
      const float nn = tanhf(gi[2] + rr * gh[2]);
      const float h1n = (1.f - zz) * nn + zz * h1c[cb][cj];
      __hip_atomic_store(&h1g[(t & 1) * 512 + cb * 256 + cj], h1n,
                         __ATOMIC_RELAXED, __HIP_MEMORY_SCOPE_AGENT);
      h1s[((long)cb * TT + t) * 256 + cj] = h1n;   // consumed by a later kernel
    }
    flag_barrier(seqf, wg, ++bt);
    ((float*)h1c)[tid]       = __hip_atomic_load(&h1g[(t & 1) * 512 + tid],
                                                 __ATOMIC_RELAXED, __HIP_MEMORY_SCOPE_AGENT);
    ((float*)h1c)[tid + 256] = __hip_atomic_load(&h1g[(t & 1) * 512 + tid + 256],
                                                 __ATOMIC_RELAXED, __HIP_MEMORY_SCOPE_AGENT);
    __syncthreads();
  }
}

__global__ void loss_finalize(const float* __restrict__ lossp, int n, float* __restrict__ out) {
  __shared__ float red[256];
  float s = 0.f;
  for (int i = threadIdx.x; i < n; i += 256) s += lossp[i];
  red[threadIdx.x] = s;
  __syncthreads();
  for (int st = 128; st > 0; st >>= 1) {
    if (threadIdx.x < st) red[threadIdx.x] += red[threadIdx.x + st];
    __syncthreads();
  }
  if (threadIdx.x == 0) out[0] = red[0] * (1.0f / 71792640.0f);
}

// ---------------------------------------------------------------------------
extern "C" void kernel_launch(void* const* d_in, const int* in_sizes, int n_in,
                              void* d_out, int out_size, void* d_ws, size_t ws_size,
                              hipStream_t stream) {
  (void)in_sizes; (void)n_in; (void)out_size; (void)ws_size;
  const float* hs   = (const float*)d_in[0];
  const float* tmpl = (const float*)d_in[1];
  const float* vert = (const float*)d_in[2];
  const int*   tfm  = (const int*)  d_in[3];
  const float* wih0 = (const float*)d_in[4];
  const float* whh0 = (const float*)d_in[5];
  const float* bih0 = (const float*)d_in[6];
  const float* bhh0 = (const float*)d_in[7];
  const float* wih1 = (const float*)d_in[8];
  const float* whh1 = (const float*)d_in[9];
  const float* bih1 = (const float*)d_in[10];
  const float* bhh1 = (const float*)d_in[11];
  const float* fcw  = (const float*)d_in[12];
  const float* fcb  = (const float*)d_in[13];
  const float* redw = (const float*)d_in[14];
  const float* redb = (const float*)d_in[15];
  float* out = (float*)d_out;

  char* ws = (char*)d_ws;
  float*    OUTG  = (float*)(ws + 0);          // [768][1026] = G^T (no red_b)
  float*    OUTM  = (float*)(ws + 3151872);    // [768][257]  = [M | fbred]
  unsigned* SEQ   = (unsigned*)(ws + 3941376); // 32 flags, 64B apart
  float*    GF    = (float*)(ws + 3943424);    // [1027][768]
  float*    MT    = (float*)(ws + 7098368);    // [256][768]  = M^T
  float*    GIHS  = (float*)(ws + 7884800);    // [1024][768]
  float*    PM    = (float*)(ws + 11030528);   // [1027][768]
  float*    M2    = (float*)(ws + 14185472);   // [768][256]
  float*    H1S   = (float*)(ws + 14971904);   // [1024][256]
  float*    H0G   = (float*)(ws + 16020480);   // [2][512]
  float*    H1G   = (float*)(ws + 16024576);   // [2][512]
  float*    LOSSP = (float*)(ws + 16028672);   // [4384]

  // zero split-K accumulators + barrier flags (must happen every call)
  hipMemsetAsync(d_ws, 0, 3943424, stream);

  // big V-contractions (split-K, 24 chunks of 2922)
  bigk_kernel<false><<<dim3(5, 3, 24), 512, 0, stream>>>(redw, vert, tmpl, OUTG, 1026, 768, 1026, VD, 2922);
  bigk_kernel<true ><<<dim3(2, 3, 24), 512, 0, stream>>>(redw, fcw,  fcb,  OUTM, 257,  768, 257,  VD, 2922);

  // transposes (+red_b fold)
  transpose_bias<<<dim3(33, 24), 256, 0, stream>>>(OUTG, 1026, 0,   GF,                 768, 1026, 768, redb);
  transpose_bias<<<dim3(8, 24),  256, 0, stream>>>(OUTM, 257,  0,   MT,                 768, 256,  768, nullptr);
  transpose_bias<<<dim3(1, 24),  256, 0, stream>>>(OUTM, 257,  256, GF + (long)1026*768, 768, 1,   768, redb);

  // small GEMMs: gihs, P (incl. c0term rows 1024/1025 and d2 row 1026), M2
  gemm128<0><<<dim3(8, 6), 256, 0, stream>>>(hs,        768,  wih0,       1536, GIHS, 768, bih0,    1024, 768, 768, nullptr, nullptr);
  gemm128<0><<<dim3(9, 6), 256, 0, stream>>>(GF,        768,  wih0 + 768, 1536, PM,   768, nullptr, 1027, 768, 768, nullptr, nullptr);
  gemm128<0><<<dim3(6, 2), 256, 0, stream>>>(wih0 + 768, 1536, MT,        768,  M2,   256, nullptr, 768,  256, 768, nullptr, nullptr);

  // sequential recurrence (persistent, 32 WGs)
  k3_seq<<<32, 256, 0, stream>>>(GIHS, PM, M2, whh0, bhh0, wih1, bih1, whh1, bhh1,
                                 tfm, H1S, H0G, H1G, SEQ);

  // final fc GEMM + fused MSE partials, then loss
  gemm128<2><<<dim3(8, 548), 256, 0, stream>>>(H1S, 256, fcw, 256, out, VD, fcb, 1024, VD, 256, vert, LOSSP);
  loss_finalize<<<1, 256, 0, stream>>>(LOSSP, 4384, out + 71792640L);
}

// Round 3
// 4629.688 us; speedup vs baseline: 1.7489x; 1.1440x over previous
//
#include <hip/hip_runtime.h>
#include <hip/hip_bf16.h>

// ---------------------------------------------------------------------------
// FaceXHuBERT decoder: 2-layer GRU (H=256) over T=512 + fc to V=70110 with
// teacher-forcing feedback through red_w [A=768, V].
//
// Restructure so the T-loop never touches V:
//   OUT_G = red_w @ [vert^T | template^T]      (split-K bf16 MFMA, atomicAdd)
//   OUT_M = red_w @ [fc_w | fc_b]              (ditto)
//   Gf[r][a] = OUT_G[a][r] + red_b[a]  (r<1026; row 1026 = fbred+red_b)
//   P   = Gf @ Wr^T        (rows 0..1023 = P_t; 1024/1025 = c0term; 1026 = d2)
//   gihs= hs @ Wl^T + b_ih_l0
//   M2  = Wr @ (red_w@fc_w)            [768x256]
// In-loop: gi_l0 = gihs_t + (t==0 ? c0term : tf[t-1] ? P_{t-1} : h1@M2^T+d2)
// Final: preds = h1s @ fc_w^T + fc_b (bf16 MFMA) fused with MSE loss.
//
// Round 3: cross-WG exchange is now TAGGED DATA — each h element is a packed
// {tag:32|value:32} u64 stored with ONE relaxed agent-scope atomic; consumers
// poll the packed word itself (tag >= phase). One-way propagate + poll detect,
// no flag, no vmcnt ack, no fences. Tag buffers are zeroed each call.
// ---------------------------------------------------------------------------

#define TT 512
#define VD 70110
#define NR 1024  // B*T

using bf16x8 = __attribute__((ext_vector_type(8))) short;
using f32x4  = __attribute__((ext_vector_type(4))) float;

static __device__ __forceinline__ unsigned short f2bf(float f) {
  unsigned u = __float_as_uint(f);
  u += 0x7FFFu + ((u >> 16) & 1u);   // RNE
  return (unsigned short)(u >> 16);
}

// ---------------- big split-K GEMM over V (bf16 MFMA, atomicAdd epilogue) ---
// C[m][n] += sum_{k in chunk} A[m][k]*Bval(n,k);  A = red_w (lda == K)
// BFORM=false: Bval(n,k) = n<1024 ? vert[n*VD+k] : n<N ? tmpl[(n-1024)*VD+k] : 0
// BFORM=true : Bval(n,k) = n<256 ? fcw[k*256+n] : n==256 ? fcb[k] : 0
template<bool BFORM>
__global__ __launch_bounds__(512, 1)
void bigk_kernel(const float* __restrict__ A, const float* __restrict__ Bv,
                 const float* __restrict__ Bt, float* __restrict__ C, int ldc,
                 int M, int N, int K, int CHK)
{
  __shared__ unsigned short Al[256][40];
  __shared__ unsigned short Bl[256][40];
  const int tid = threadIdx.x;
  const int n0 = blockIdx.x * 256, m0 = blockIdx.y * 256;
  const int kc0 = blockIdx.z * CHK;
  const int kc1 = min(K, kc0 + CHK);
  const int wave = tid >> 6, lane = tid & 63;
  const int wm = wave >> 1, wn = wave & 1;
  const int kq = lane >> 4, ln = lane & 15;
  f32x4 acc[4][8] = {};
  for (int kc = kc0; kc < kc1; kc += 32) {
    __syncthreads();
    { // stage A: 256 rows x 32 k  (rows of red_w; stride VD is only 8B-aligned)
      const int m = tid >> 1, kh = (tid & 1) << 4;
      const bool mok = (m0 + m) < M;
      const float* arow = A + (long)(m0 + m) * (long)K;
      unsigned short tmp[16] __attribute__((aligned(16)));
      if (mok && (kc + 32 <= kc1)) {
        const float2* ap2 = (const float2*)(arow + kc + kh);
#pragma unroll
        for (int i = 0; i < 8; ++i) { float2 v = ap2[i]; tmp[2*i] = f2bf(v.x); tmp[2*i+1] = f2bf(v.y); }
      } else {
#pragma unroll
        for (int i = 0; i < 16; ++i) {
          int kk = kc + kh + i;
          tmp[i] = f2bf((mok && kk < kc1) ? arow[kk] : 0.f);
        }
      }
      ((int4*)&Al[m][kh])[0] = *(int4*)&tmp[0];
      ((int4*)&Al[m][kh])[1] = *(int4*)&tmp[8];
    }
    if (!BFORM) { // stage B from row-major rows (vert / template)
      const int n = tid >> 1, kh = (tid & 1) << 4;
      const int gn = n0 + n;
      const float* bp = nullptr;
      if (gn < 1024) bp = Bv + (long)gn * (long)VD;
      else if (gn < N) bp = Bt + (long)(gn - 1024) * (long)VD;
      unsigned short tmp[16] __attribute__((aligned(16)));
      if (bp && (kc + 32 <= kc1)) {
        const float2* bp2 = (const float2*)(bp + kc + kh);
#pragma unroll
        for (int i = 0; i < 8; ++i) { float2 v = bp2[i]; tmp[2*i] = f2bf(v.x); tmp[2*i+1] = f2bf(v.y); }
      } else {
#pragma unroll
        for (int i = 0; i < 16; ++i) {
          int kk = kc + kh + i;
          tmp[i] = f2bf((bp && kk < kc1) ? bp[kk] : 0.f);
        }
      }
      ((int4*)&Bl[n][kh])[0] = *(int4*)&tmp[0];
      ((int4*)&Bl[n][kh])[1] = *(int4*)&tmp[8];
    } else {      // stage B from k-major fc_w (transpose into LDS, coalesced n)
      const int n = tid & 255, kh = (tid >> 8) << 4;
      const int gn = n0 + n;
      unsigned short tmp[16] __attribute__((aligned(16)));
#pragma unroll
      for (int i = 0; i < 16; ++i) {
        int kk = kc + kh + i;
        float v = 0.f;
        if (kk < kc1) {
          if (gn < 256) v = Bv[(long)kk * 256 + gn];
          else if (gn == 256) v = Bt[kk];
        }
        tmp[i] = f2bf(v);
      }
      ((int4*)&Bl[n][kh])[0] = *(int4*)&tmp[0];
      ((int4*)&Bl[n][kh])[1] = *(int4*)&tmp[8];
    }
    __syncthreads();
    bf16x8 af[4], bfv[8];
#pragma unroll
    for (int i = 0; i < 4; ++i) af[i] = *(const bf16x8*)&Al[wm*64 + i*16 + ln][kq*8];
#pragma unroll
    for (int j = 0; j < 8; ++j) bfv[j] = *(const bf16x8*)&Bl[wn*128 + j*16 + ln][kq*8];
#pragma unroll
    for (int i = 0; i < 4; ++i)
#pragma unroll
      for (int j = 0; j < 8; ++j)
        acc[i][j] = __builtin_amdgcn_mfma_f32_16x16x32_bf16(af[i], bfv[j], acc[i][j], 0, 0, 0);
  }
#pragma unroll
  for (int i = 0; i < 4; ++i)
#pragma unroll
    for (int j = 0; j < 8; ++j)
#pragma unroll
      for (int r = 0; r < 4; ++r) {
        int gm = m0 + wm*64 + i*16 + kq*4 + r;
        int gn = n0 + wn*128 + j*16 + ln;
        if (gm < M && gn < N) unsafeAtomicAdd(&C[(long)gm * ldc + gn], acc[i][j][r]);
      }
}

// ---------------- generic 128x128 bf16-MFMA GEMM: C = A @ B^T (+bias) -------
// EPI==0: store (+bias if non-null). EPI==2: +bias, store to C(=d_out), and
// accumulate sum((C - vert)^2) into lossp[block].
template<int EPI>
__global__ __launch_bounds__(256, 2)
void gemm128(const float* __restrict__ A, int lda,
             const float* __restrict__ B, int ldb,
             float* __restrict__ C, long ldc,
             const float* __restrict__ bias,
             int M, int N, int K,
             const float* __restrict__ vert, float* __restrict__ lossp)
{
  __shared__ unsigned short Al[128][40];
  __shared__ unsigned short Bl[128][40];
  const int tid = threadIdx.x;
  const int m0 = blockIdx.x * 128, n0 = blockIdx.y * 128;
  const int wave = tid >> 6, lane = tid & 63;
  const int wm = wave >> 1, wn = wave & 1;
  const int kq = lane >> 4, ln = lane & 15;
  f32x4 acc[4][4] = {};
  for (int kc = 0; kc < K; kc += 32) {
    __syncthreads();
    {
      const int m = tid >> 1, kh = (tid & 1) << 4;
      unsigned short tmp[16] __attribute__((aligned(16)));
      const bool mok = (m0 + m) < M;
      if (mok) {
        const float4* ap4 = (const float4*)(A + (long)(m0 + m) * lda + kc + kh);
#pragma unroll
        for (int i = 0; i < 4; ++i) {
          float4 v = ap4[i];
          tmp[4*i+0] = f2bf(v.x); tmp[4*i+1] = f2bf(v.y);
          tmp[4*i+2] = f2bf(v.z); tmp[4*i+3] = f2bf(v.w);
        }
      } else {
#pragma unroll
        for (int i = 0; i < 16; ++i) tmp[i] = 0;
      }
      ((int4*)&Al[m][kh])[0] = *(int4*)&tmp[0];
      ((int4*)&Al[m][kh])[1] = *(int4*)&tmp[8];
      const int n = m;  // same mapping for B
      unsigned short tmb[16] __attribute__((aligned(16)));
      const bool nok = (n0 + n) < N;
      if (nok) {
        const float4* bp4 = (const float4*)(B + (long)(n0 + n) * ldb + kc + kh);
#pragma unroll
        for (int i = 0; i < 4; ++i) {
          float4 v = bp4[i];
          tmb[4*i+0] = f2bf(v.x); tmb[4*i+1] = f2bf(v.y);
          tmb[4*i+2] = f2bf(v.z); tmb[4*i+3] = f2bf(v.w);
        }
      } else {
#pragma unroll
        for (int i = 0; i < 16; ++i) tmb[i] = 0;
      }
      ((int4*)&Bl[n][kh])[0] = *(int4*)&tmb[0];
      ((int4*)&Bl[n][kh])[1] = *(int4*)&tmb[8];
    }
    __syncthreads();
    bf16x8 af[4], bfv[4];
#pragma unroll
    for (int i = 0; i < 4; ++i) af[i]  = *(const bf16x8*)&Al[wm*64 + i*16 + ln][kq*8];
#pragma unroll
    for (int j = 0; j < 4; ++j) bfv[j] = *(const bf16x8*)&Bl[wn*64 + j*16 + ln][kq*8];
#pragma unroll
    for (int i = 0; i < 4; ++i)
#pragma unroll
      for (int j = 0; j < 4; ++j)
        acc[i][j] = __builtin_amdgcn_mfma_f32_16x16x32_bf16(af[i], bfv[j], acc[i][j], 0, 0, 0);
  }
  float ls = 0.f;
#pragma unroll
  for (int i = 0; i < 4; ++i)
#pragma unroll
    for (int j = 0; j < 4; ++j)
#pragma unroll
      for (int r = 0; r < 4; ++r) {
        const int gm = m0 + wm*64 + i*16 + kq*4 + r;
        const int gn = n0 + wn*64 + j*16 + ln;
        if (gm < M && gn < N) {
          float v = acc[i][j][r];
          if (bias) v += bias[gn];
          C[(long)gm * ldc + gn] = v;
          if (EPI == 2) { float d = v - vert[(long)gm * VD + gn]; ls += d * d; }
        }
      }
  if (EPI == 2) {
#pragma unroll
    for (int o = 32; o > 0; o >>= 1) ls += __shfl_down(ls, o);
    __shared__ float wred[4];
    if ((tid & 63) == 0) wred[wave] = ls;
    __syncthreads();
    if (tid == 0) lossp[blockIdx.y * gridDim.x + blockIdx.x] = wred[0] + wred[1] + wred[2] + wred[3];
  }
}

// ---------------- transpose with optional bias: dst[r][c] = src[c][row0+r]+b[c]
__global__ void transpose_bias(const float* __restrict__ src, int lds, int row0,
                               float* __restrict__ dst, int ldd,
                               int rows, int cols, const float* __restrict__ bias)
{
  __shared__ float tile[32][33];
  const int rb = blockIdx.x * 32, cb = blockIdx.y * 32;
  const int tx = threadIdx.x & 31, ty = threadIdx.x >> 5;
  for (int yy = ty; yy < 32; yy += 8) {
    int c = cb + yy, r = rb + tx;
    tile[yy][tx] = (c < cols && r < rows) ? src[(long)c * lds + row0 + r] : 0.f;
  }
  __syncthreads();
  for (int yy = ty; yy < 32; yy += 8) {
    int r = rb + yy, c = cb + tx;
    if (r < rows && c < cols)
      dst[(long)r * ldd + c] = tile[tx][yy] + (bias ? bias[c] : 0.f);
  }
}

// ---------------- persistent sequential GRU kernel (32 WGs, 1/CU) -----------
// Cross-WG exchange via tagged packed values: u64 = {tag:32 | f32 bits:32},
// single relaxed agent-scope atomic store; consumers poll the word directly.
// No flags, no fences, no store-ack — one-way latency + poll detect.

// Conflict-free LDS dot: 16 lanes (kl) read 256 contiguous bytes per i-step.
#define RUN_DOTS(W0, W1, H0, H1)                                              \
  {                                                                           \
    _Pragma("unroll")                                                         \
    for (int pass = 0; pass < 6; ++pass) {                                    \
      const int D = pass * 16 + wave * 4 + dsub;                              \
      const int mat = (D >= 48) ? 1 : 0;                                      \
      const int rem = D - mat * 48;                                           \
      const int row = rem >> 1, bb = rem & 1;                                 \
      const float4* w4 = (const float4*)(mat ? W1[row] : W0[row]);            \
      const float4* h4 = (const float4*)(mat ? H1[bb] : H0[bb]);              \
      float s = 0.f;                                                          \
      _Pragma("unroll")                                                       \
      for (int i = 0; i < 4; ++i) {                                           \
        const float4 a = w4[i * 16 + kl], h = h4[i * 16 + kl];                \
        s += a.x * h.x + a.y * h.y + a.z * h.z + a.w * h.w;                   \
      }                                                                       \
      s += __shfl_xor(s, 1); s += __shfl_xor(s, 2);                           \
      s += __shfl_xor(s, 4); s += __shfl_xor(s, 8);                           \
      if (kl == 0) dotsS[mat][bb][row >> 3][row & 7] = s;                     \
    }                                                                         \
  }

// Poll two packed entries (tid, tid+256) until tag >= want; write values to LDS.
#define POLL_FILL(buf, dstLds, want)                                          \
  {                                                                           \
    const unsigned w_ = (unsigned)(want);                                     \
    unsigned long long a_ = __hip_atomic_load(&buf[tid],       __ATOMIC_RELAXED, __HIP_MEMORY_SCOPE_AGENT); \
    unsigned long long b_ = __hip_atomic_load(&buf[tid + 256], __ATOMIC_RELAXED, __HIP_MEMORY_SCOPE_AGENT); \
    int sp_ = 0;                                                              \
    while ((unsigned)(a_ >> 32) < w_ && ++sp_ < (1 << 15))                    \
      a_ = __hip_atomic_load(&buf[tid],       __ATOMIC_RELAXED, __HIP_MEMORY_SCOPE_AGENT); \
    sp_ = 0;                                                                  \
    while ((unsigned)(b_ >> 32) < w_ && ++sp_ < (1 << 15))                    \
      b_ = __hip_atomic_load(&buf[tid + 256], __ATOMIC_RELAXED, __HIP_MEMORY_SCOPE_AGENT); \
    ((float*)dstLds)[tid]       = __uint_as_float((unsigned)a_);              \
    ((float*)dstLds)[tid + 256] = __uint_as_float((unsigned)b_);              \
  }

__global__ __launch_bounds__(256, 1)
void k3_seq(const float* __restrict__ gihs, const float* __restrict__ Pm,
            const float* __restrict__ M2m,
            const float* __restrict__ whh0, const float* __restrict__ bhh0,
            const float* __restrict__ wih1, const float* __restrict__ bih1,
            const float* __restrict__ whh1, const float* __restrict__ bhh1,
            const int* __restrict__ tfm,
            float* __restrict__ h1s,
            unsigned long long* __restrict__ h0p, unsigned long long* __restrict__ h1p)
{
  __shared__ float wq[24][260], wh0s[24][260], wi1s[24][260], wh1s[24][260];
  __shared__ float h0c[2][256], h1c[2][256];
  __shared__ float dotsS[2][2][3][8];
  __shared__ int tfl[TT];
  const int tid = threadIdx.x;
  const int wg = blockIdx.x;
  const int j0 = wg * 8;           // this WG owns h dims [j0, j0+8)

  for (int row = 0; row < 24; ++row) {
    const int g = row >> 3, jj = row & 7;
    const long gr = g * 256 + j0 + jj;
    wq[row][tid]   = M2m[gr * 256 + tid];
    wh0s[row][tid] = whh0[gr * 256 + tid];
    wi1s[row][tid] = wih1[gr * 256 + tid];
    wh1s[row][tid] = whh1[gr * 256 + tid];
  }
  ((float*)h0c)[tid] = 0.f; ((float*)h0c)[tid + 256] = 0.f;
  ((float*)h1c)[tid] = 0.f; ((float*)h1c)[tid + 256] = 0.f;
  for (int t = tid; t < TT; t += 256) tfl[t] = tfm[t];

  const int cb = tid >> 3, cjj = tid & 7, cj = j0 + cjj;   // combine threads (tid<16)
  float bh0v[3], bi1v[3], bh1v[3], d2v[3];
  if (tid < 16) {
#pragma unroll
    for (int g = 0; g < 3; ++g) {
      bh0v[g] = bhh0[g*256 + cj];
      bi1v[g] = bih1[g*256 + cj];
      bh1v[g] = bhh1[g*256 + cj];
      d2v[g]  = Pm[(long)1026 * 768 + g*256 + cj];
    }
  }
  __syncthreads();

  const int wave = tid >> 6, dsub = (tid >> 4) & 3, kl = tid & 15;
  for (int t = 0; t < TT; ++t) {
    // prefetch combine inputs (independent of dots; hidden under RUN_DOTS)
    float gihsv[3], piv[3];
    if (tid < 16) {
      const long r = (long)cb * TT + t;
      const long prow = (t == 0) ? (1024 + cb) : ((long)cb * TT + (t - 1));
#pragma unroll
      for (int g = 0; g < 3; ++g) {
        gihsv[g] = gihs[r * 768 + g*256 + cj];
        piv[g]   = Pm[prow * 768 + g*256 + cj];
      }
    }
    // phase A: q = h1_{t-1} @ M2^T ; gh = h0_{t-1} @ whh0^T
    RUN_DOTS(wq, wh0s, h1c, h0c);
    __syncthreads();
    if (tid < 16) {
      const int tfprev = (t == 0) ? 1 : tfl[t - 1];
      float gi[3], gh[3];
#pragma unroll
      for (int g = 0; g < 3; ++g) {
        const float q = dotsS[0][cb][g][cjj] + d2v[g];
        gi[g] = gihsv[g] + (tfprev ? piv[g] : q);
        gh[g] = dotsS[1][cb][g][cjj] + bh0v[g];
      }
      const float rr = 1.f / (1.f + __expf(-(gi[0] + gh[0])));
      const float zz = 1.f / (1.f + __expf(-(gi[1] + gh[1])));
      const float nn = tanhf(gi[2] + rr * gh[2]);
      const float h0n = (1.f - zz) * nn + zz * h0c[cb][cj];
      const unsigned long long pk =
          ((unsigned long long)(unsigned)(t + 1) << 32) | (unsigned long long)__float_as_uint(h0n);
      __hip_atomic_store(&h0p[cb * 256 + cj], pk, __ATOMIC_RELAXED, __HIP_MEMORY_SCOPE_AGENT);
    }
    __syncthreads();            // old h0c fully read before overwrite
    POLL_FILL(h0p, h0c, t + 1); // gather h0_t from all WGs
    __syncthreads();
    // phase B: gi1 = h0_t @ wih1^T ; gh1 = h1_{t-1} @ whh1^T
    RUN_DOTS(wi1s, wh1s, h0c, h1c);
    __syncthreads();
    if (tid < 16) {
      float gi[3], gh[3];
#pragma unroll
      for (int g = 0; g < 3; ++g) {
        gi[g] = dotsS[0][cb][g][cjj] + bi1v[g];
        gh[g] = dotsS[1][cb][g][cjj] + bh1v[g];
      }
      const float rr = 1.f / (1.f + __expf(-(gi[0] + gh[0])));
      const float zz = 1.f / (1.f + __expf(-(gi[1] + gh[1])));
      const float nn = tanhf(gi[2] + rr * gh[2]);
      const float h1n = (1.f - zz) * nn + zz * h1c[cb][cj];
      h1s[((long)cb * TT + t) * 256 + cj] = h1n;   // consumed by a later kernel
      const unsigned long long pk =
          ((unsigned long long)(unsigned)(t + 1) << 32) | (unsigned long long)__float_as_uint(h1n);
      __hip_atomic_store(&h1p[cb * 256 + cj], pk, __ATOMIC_RELAXED, __HIP_MEMORY_SCOPE_AGENT);
    }
    __syncthreads();            // old h1c fully read before overwrite
    POLL_FILL(h1p, h1c, t + 1); // gather h1_t from all WGs
    __syncthreads();
  }
}

__global__ void loss_finalize(const float* __restrict__ lossp, int n, float* __restrict__ out) {
  __shared__ float red[256];
  float s = 0.f;
  for (int i = threadIdx.x; i < n; i += 256) s += lossp[i];
  red[threadIdx.x] = s;
  __syncthreads();
  for (int st = 128; st > 0; st >>= 1) {
    if (threadIdx.x < st) red[threadIdx.x] += red[threadIdx.x + st];
    __syncthreads();
  }
  if (threadIdx.x == 0) out[0] = red[0] * (1.0f / 71792640.0f);
}

// ---------------------------------------------------------------------------
extern "C" void kernel_launch(void* const* d_in, const int* in_sizes, int n_in,
                              void* d_out, int out_size, void* d_ws, size_t ws_size,
                              hipStream_t stream) {
  (void)in_sizes; (void)n_in; (void)out_size; (void)ws_size;
  const float* hs   = (const float*)d_in[0];
  const float* tmpl = (const float*)d_in[1];
  const float* vert = (const float*)d_in[2];
  const int*   tfm  = (const int*)  d_in[3];
  const float* wih0 = (const float*)d_in[4];
  const float* whh0 = (const float*)d_in[5];
  const float* bih0 = (const float*)d_in[6];
  const float* bhh0 = (const float*)d_in[7];
  const float* wih1 = (const float*)d_in[8];
  const float* whh1 = (const float*)d_in[9];
  const float* bih1 = (const float*)d_in[10];
  const float* bhh1 = (const float*)d_in[11];
  const float* fcw  = (const float*)d_in[12];
  const float* fcb  = (const float*)d_in[13];
  const float* redw = (const float*)d_in[14];
  const float* redb = (const float*)d_in[15];
  float* out = (float*)d_out;

  char* ws = (char*)d_ws;
  float*    OUTG  = (float*)(ws + 0);          // [768][1026] = G^T (no red_b)
  float*    OUTM  = (float*)(ws + 3151872);    // [768][257]  = [M | fbred]
  unsigned long long* H0P = (unsigned long long*)(ws + 3941376); // 512 packed
  unsigned long long* H1P = (unsigned long long*)(ws + 3945472); // 512 packed
  float*    GF    = (float*)(ws + 3949568);    // [1027][768]
  float*    MT    = (float*)(ws + 7104512);    // [256][768]  = M^T
  float*    GIHS  = (float*)(ws + 7890944);    // [1024][768]
  float*    PM    = (float*)(ws + 11036672);   // [1027][768]
  float*    M2    = (float*)(ws + 14191616);   // [768][256]
  float*    H1S   = (float*)(ws + 14978048);   // [1024][256]
  float*    LOSSP = (float*)(ws + 16026624);   // [4384]

  // zero split-K accumulators + packed tag buffers (must happen every call)
  hipMemsetAsync(d_ws, 0, 3949568, stream);

  // big V-contractions (split-K, 24 chunks of 2922)
  bigk_kernel<false><<<dim3(5, 3, 24), 512, 0, stream>>>(redw, vert, tmpl, OUTG, 1026, 768, 1026, VD, 2922);
  bigk_kernel<true ><<<dim3(2, 3, 24), 512, 0, stream>>>(redw, fcw,  fcb,  OUTM, 257,  768, 257,  VD, 2922);

  // transposes (+red_b fold)
  transpose_bias<<<dim3(33, 24), 256, 0, stream>>>(OUTG, 1026, 0,   GF,                 768, 1026, 768, redb);
  transpose_bias<<<dim3(8, 24),  256, 0, stream>>>(OUTM, 257,  0,   MT,                 768, 256,  768, nullptr);
  transpose_bias<<<dim3(1, 24),  256, 0, stream>>>(OUTM, 257,  256, GF + (long)1026*768, 768, 1,   768, redb);

  // small GEMMs: gihs, P (incl. c0term rows 1024/1025 and d2 row 1026), M2
  gemm128<0><<<dim3(8, 6), 256, 0, stream>>>(hs,        768,  wih0,       1536, GIHS, 768, bih0,    1024, 768, 768, nullptr, nullptr);
  gemm128<0><<<dim3(9, 6), 256, 0, stream>>>(GF,        768,  wih0 + 768, 1536, PM,   768, nullptr, 1027, 768, 768, nullptr, nullptr);
  gemm128<0><<<dim3(6, 2), 256, 0, stream>>>(wih0 + 768, 1536, MT,        768,  M2,   256, nullptr, 768,  256, 768, nullptr, nullptr);

  // sequential recurrence (persistent, 32 WGs, tagged-data sync)
  k3_seq<<<32, 256, 0, stream>>>(GIHS, PM, M2, whh0, bhh0, wih1, bih1, whh1, bhh1,
                                 tfm, H1S, H0P, H1P);

  // final fc GEMM + fused MSE partials, then loss
  gemm128<2><<<dim3(8, 548), 256, 0, stream>>>(H1S, 256, fcw, 256, out, VD, fcb, 1024, VD, 256, vert, LOSSP);
  loss_finalize<<<1, 256, 0, stream>>>(LOSSP, 4384, out + 71792640L);
}

// Round 6
// 3724.841 us; speedup vs baseline: 2.1737x; 1.2429x over previous
//
#include <hip/hip_runtime.h>
#include <hip/hip_bf16.h>

// ---------------------------------------------------------------------------
// FaceXHuBERT decoder: 2-layer GRU (H=256) over T=512 + fc to V=70110 with
// teacher-forcing feedback through red_w [A=768, V].
//
// Restructure so the T-loop never touches V:
//   OUT_G = red_w @ [vert^T | template^T]      (split-K bf16 MFMA, atomicAdd)
//   OUT_M = red_w @ [fc_w | fc_b]              (ditto)
//   Gf[r][a] = OUT_G[a][r] + red_b[a]  (r<1026; row 1026 = fbred+red_b)
//   P   = Gf @ Wr^T        (rows 0..1023 = P_t; 1024/1025 = c0term; 1026 = d2)
//   gihs= hs @ Wl^T + b_ih_l0
//   M2  = Wr @ (red_w@fc_w)            [768x256]
// In-loop: gi_l0 = gihs_t + (t==0 ? c0term : tf[t-1] ? P_{t-1} : h1@M2^T+d2)
// Final: preds = h1s @ fc_w^T + fc_b (bf16 MFMA) fused with MSE loss.
//
// Round 6: revert exchange to round-3's KNOWN-GOOD agent-scope tagged-u64
// protocol (rounds 4/5 showed no HW-exposed XCD-local scope exists). Attack
// round-3's measured overheads instead:
//   - 512 threads/WG: each thread polls exactly ONE tagged word (round 3
//     serialized two spin loops per thread = two IC latencies per phase)
//   - s_sleep(1) backoff in the poll (tight spinning by 512 lanes hammered
//     the IC and delayed the producers' own stores)
//   - RUN_DOTS: 3 passes instead of 6 (more lanes per phase)
// ---------------------------------------------------------------------------

#define TT 512
#define VD 70110
#define NR 1024  // B*T

using bf16x8 = __attribute__((ext_vector_type(8))) short;
using f32x4  = __attribute__((ext_vector_type(4))) float;

static __device__ __forceinline__ unsigned short f2bf(float f) {
  unsigned u = __float_as_uint(f);
  u += 0x7FFFu + ((u >> 16) & 1u);   // RNE
  return (unsigned short)(u >> 16);
}

// ---------------- big split-K GEMM over V (bf16 MFMA, atomicAdd epilogue) ---
template<bool BFORM>
__global__ __launch_bounds__(512, 1)
void bigk_kernel(const float* __restrict__ A, const float* __restrict__ Bv,
                 const float* __restrict__ Bt, float* __restrict__ C, int ldc,
                 int M, int N, int K, int CHK)
{
  __shared__ unsigned short Al[256][40];
  __shared__ unsigned short Bl[256][40];
  const int tid = threadIdx.x;
  const int n0 = blockIdx.x * 256, m0 = blockIdx.y * 256;
  const int kc0 = blockIdx.z * CHK;
  const int kc1 = min(K, kc0 + CHK);
  const int wave = tid >> 6, lane = tid & 63;
  const int wm = wave >> 1, wn = wave & 1;
  const int kq = lane >> 4, ln = lane & 15;
  f32x4 acc[4][8] = {};
  for (int kc = kc0; kc < kc1; kc += 32) {
    __syncthreads();
    { // stage A: 256 rows x 32 k
      const int m = tid >> 1, kh = (tid & 1) << 4;
      const bool mok = (m0 + m) < M;
      const float* arow = A + (long)(m0 + m) * (long)K;
      unsigned short tmp[16] __attribute__((aligned(16)));
      if (mok && (kc + 32 <= kc1)) {
        const float2* ap2 = (const float2*)(arow + kc + kh);
#pragma unroll
        for (int i = 0; i < 8; ++i) { float2 v = ap2[i]; tmp[2*i] = f2bf(v.x); tmp[2*i+1] = f2bf(v.y); }
      } else {
#pragma unroll
        for (int i = 0; i < 16; ++i) {
          int kk = kc + kh + i;
          tmp[i] = f2bf((mok && kk < kc1) ? arow[kk] : 0.f);
        }
      }
      ((int4*)&Al[m][kh])[0] = *(int4*)&tmp[0];
      ((int4*)&Al[m][kh])[1] = *(int4*)&tmp[8];
    }
    if (!BFORM) { // stage B from row-major rows (vert / template)
      const int n = tid >> 1, kh = (tid & 1) << 4;
      const int gn = n0 + n;
      const float* bp = nullptr;
      if (gn < 1024) bp = Bv + (long)gn * (long)VD;
      else if (gn < N) bp = Bt + (long)(gn - 1024) * (long)VD;
      unsigned short tmp[16] __attribute__((aligned(16)));
      if (bp && (kc + 32 <= kc1)) {
        const float2* bp2 = (const float2*)(bp + kc + kh);
#pragma unroll
        for (int i = 0; i < 8; ++i) { float2 v = bp2[i]; tmp[2*i] = f2bf(v.x); tmp[2*i+1] = f2bf(v.y); }
      } else {
#pragma unroll
        for (int i = 0; i < 16; ++i) {
          int kk = kc + kh + i;
          tmp[i] = f2bf((bp && kk < kc1) ? bp[kk] : 0.f);
        }
      }
      ((int4*)&Bl[n][kh])[0] = *(int4*)&tmp[0];
      ((int4*)&Bl[n][kh])[1] = *(int4*)&tmp[8];
    } else {      // stage B from k-major fc_w (transpose into LDS, coalesced n)
      const int n = tid & 255, kh = (tid >> 8) << 4;
      const int gn = n0 + n;
      unsigned short tmp[16] __attribute__((aligned(16)));
#pragma unroll
      for (int i = 0; i < 16; ++i) {
        int kk = kc + kh + i;
        float v = 0.f;
        if (kk < kc1) {
          if (gn < 256) v = Bv[(long)kk * 256 + gn];
          else if (gn == 256) v = Bt[kk];
        }
        tmp[i] = f2bf(v);
      }
      ((int4*)&Bl[n][kh])[0] = *(int4*)&tmp[0];
      ((int4*)&Bl[n][kh])[1] = *(int4*)&tmp[8];
    }
    __syncthreads();
    bf16x8 af[4], bfv[8];
#pragma unroll
    for (int i = 0; i < 4; ++i) af[i] = *(const bf16x8*)&Al[wm*64 + i*16 + ln][kq*8];
#pragma unroll
    for (int j = 0; j < 8; ++j) bfv[j] = *(const bf16x8*)&Bl[wn*128 + j*16 + ln][kq*8];
#pragma unroll
    for (int i = 0; i < 4; ++i)
#pragma unroll
      for (int j = 0; j < 8; ++j)
        acc[i][j] = __builtin_amdgcn_mfma_f32_16x16x32_bf16(af[i], bfv[j], acc[i][j], 0, 0, 0);
  }
#pragma unroll
  for (int i = 0; i < 4; ++i)
#pragma unroll
    for (int j = 0; j < 8; ++j)
#pragma unroll
      for (int r = 0; r < 4; ++r) {
        int gm = m0 + wm*64 + i*16 + kq*4 + r;
        int gn = n0 + wn*128 + j*16 + ln;
        if (gm < M && gn < N) unsafeAtomicAdd(&C[(long)gm * ldc + gn], acc[i][j][r]);
      }
}

// ---------------- generic 128x128 bf16-MFMA GEMM: C = A @ B^T (+bias) -------
template<int EPI>
__global__ __launch_bounds__(256, 2)
void gemm128(const float* __restrict__ A, int lda,
             const float* __restrict__ B, int ldb,
             float* __restrict__ C, long ldc,
             const float* __restrict__ bias,
             int M, int N, int K,
             const float* __restrict__ vert, float* __restrict__ lossp)
{
  __shared__ unsigned short Al[128][40];
  __shared__ unsigned short Bl[128][40];
  const int tid = threadIdx.x;
  const int m0 = blockIdx.x * 128, n0 = blockIdx.y * 128;
  const int wave = tid >> 6, lane = tid & 63;
  const int wm = wave >> 1, wn = wave & 1;
  const int kq = lane >> 4, ln = lane & 15;
  f32x4 acc[4][4] = {};
  for (int kc = 0; kc < K; kc += 32) {
    __syncthreads();
    {
      const int m = tid >> 1, kh = (tid & 1) << 4;
      unsigned short tmp[16] __attribute__((aligned(16)));
      const bool mok = (m0 + m) < M;
      if (mok) {
        const float4* ap4 = (const float4*)(A + (long)(m0 + m) * lda + kc + kh);
#pragma unroll
        for (int i = 0; i < 4; ++i) {
          float4 v = ap4[i];
          tmp[4*i+0] = f2bf(v.x); tmp[4*i+1] = f2bf(v.y);
          tmp[4*i+2] = f2bf(v.z); tmp[4*i+3] = f2bf(v.w);
        }
      } else {
#pragma unroll
        for (int i = 0; i < 16; ++i) tmp[i] = 0;
      }
      ((int4*)&Al[m][kh])[0] = *(int4*)&tmp[0];
      ((int4*)&Al[m][kh])[1] = *(int4*)&tmp[8];
      const int n = m;  // same mapping for B
      unsigned short tmb[16] __attribute__((aligned(16)));
      const bool nok = (n0 + n) < N;
      if (nok) {
        const float4* bp4 = (const float4*)(B + (long)(n0 + n) * ldb + kc + kh);
#pragma unroll
        for (int i = 0; i < 4; ++i) {
          float4 v = bp4[i];
          tmb[4*i+0] = f2bf(v.x); tmb[4*i+1] = f2bf(v.y);
          tmb[4*i+2] = f2bf(v.z); tmb[4*i+3] = f2bf(v.w);
        }
      } else {
#pragma unroll
        for (int i = 0; i < 16; ++i) tmb[i] = 0;
      }
      ((int4*)&Bl[n][kh])[0] = *(int4*)&tmb[0];
      ((int4*)&Bl[n][kh])[1] = *(int4*)&tmb[8];
    }
    __syncthreads();
    bf16x8 af[4], bfv[4];
#pragma unroll
    for (int i = 0; i < 4; ++i) af[i]  = *(const bf16x8*)&Al[wm*64 + i*16 + ln][kq*8];
#pragma unroll
    for (int j = 0; j < 4; ++j) bfv[j] = *(const bf16x8*)&Bl[wn*64 + j*16 + ln][kq*8];
#pragma unroll
    for (int i = 0; i < 4; ++i)
#pragma unroll
      for (int j = 0; j < 4; ++j)
        acc[i][j] = __builtin_amdgcn_mfma_f32_16x16x32_bf16(af[i], bfv[j], acc[i][j], 0, 0, 0);
  }
  float ls = 0.f;
#pragma unroll
  for (int i = 0; i < 4; ++i)
#pragma unroll
    for (int j = 0; j < 4; ++j)
#pragma unroll
      for (int r = 0; r < 4; ++r) {
        const int gm = m0 + wm*64 + i*16 + kq*4 + r;
        const int gn = n0 + wn*64 + j*16 + ln;
        if (gm < M && gn < N) {
          float v = acc[i][j][r];
          if (bias) v += bias[gn];
          C[(long)gm * ldc + gn] = v;
          if (EPI == 2) { float d = v - vert[(long)gm * VD + gn]; ls += d * d; }
        }
      }
  if (EPI == 2) {
#pragma unroll
    for (int o = 32; o > 0; o >>= 1) ls += __shfl_down(ls, o);
    __shared__ float wred[4];
    if ((tid & 63) == 0) wred[wave] = ls;
    __syncthreads();
    if (tid == 0) lossp[blockIdx.y * gridDim.x + blockIdx.x] = wred[0] + wred[1] + wred[2] + wred[3];
  }
}

// ---------------- transpose with optional bias ------------------------------
__global__ void transpose_bias(const float* __restrict__ src, int lds, int row0,
                               float* __restrict__ dst, int ldd,
                               int rows, int cols, const float* __restrict__ bias)
{
  __shared__ float tile[32][33];
  const int rb = blockIdx.x * 32, cb = blockIdx.y * 32;
  const int tx = threadIdx.x & 31, ty = threadIdx.x >> 5;
  for (int yy = ty; yy < 32; yy += 8) {
    int c = cb + yy, r = rb + tx;
    tile[yy][tx] = (c < cols && r < rows) ? src[(long)c * lds + row0 + r] : 0.f;
  }
  __syncthreads();
  for (int yy = ty; yy < 32; yy += 8) {
    int r = rb + yy, c = cb + tx;
    if (r < rows && c < cols)
      dst[(long)r * ldd + c] = tile[tx][yy] + (bias ? bias[c] : 0.f);
  }
}

// ---------------- persistent sequential GRU kernel (32 WGs x 512 thr) -------
// Cross-WG exchange: tagged packed u64 = {tag:32 | f32 bits:32}, one relaxed
// AGENT-scope atomic store per element; consumers poll the word itself with
// s_sleep backoff (one word per thread). Known-correct round-3 protocol.

// Conflict-free LDS dot; 512 threads -> 3 passes cover 96 dot-groups.
#define RUN_DOTS(W0, W1, H0, H1)                                              \
  {                                                                           \
    _Pragma("unroll")                                                         \
    for (int pass = 0; pass < 3; ++pass) {                                    \
      const int D = pass * 32 + wave * 4 + dsub;                              \
      const int mat = (D >= 48) ? 1 : 0;                                      \
      const int rem = D - mat * 48;                                           \
      const int row = rem >> 1, bb = rem & 1;                                 \
      const float4* w4 = (const float4*)(mat ? W1[row] : W0[row]);            \
      const float4* h4 = (const float4*)(mat ? H1[bb] : H0[bb]);              \
      float s = 0.f;                                                          \
      _Pragma("unroll")                                                       \
      for (int i = 0; i < 4; ++i) {                                           \
        const float4 a = w4[i * 16 + kl], h = h4[i * 16 + kl];                \
        s += a.x * h.x + a.y * h.y + a.z * h.z + a.w * h.w;                   \
      }                                                                       \
      s += __shfl_xor(s, 1); s += __shfl_xor(s, 2);                           \
      s += __shfl_xor(s, 4); s += __shfl_xor(s, 8);                           \
      if (kl == 0) dotsS[mat][bb][row >> 3][row & 7] = s;                     \
    }                                                                         \
  }

// Each of 512 threads polls exactly ONE packed word until tag >= want.
#define POLL_FILL(buf, dstLds, want)                                          \
  {                                                                           \
    const unsigned w_ = (unsigned)(want);                                     \
    unsigned long long a_ = __hip_atomic_load(&buf[tid], __ATOMIC_RELAXED, __HIP_MEMORY_SCOPE_AGENT); \
    int sp_ = 0;                                                              \
    while ((unsigned)(a_ >> 32) < w_ && ++sp_ < (1 << 15)) {                  \
      __builtin_amdgcn_s_sleep(1);                                            \
      a_ = __hip_atomic_load(&buf[tid], __ATOMIC_RELAXED, __HIP_MEMORY_SCOPE_AGENT); \
    }                                                                         \
    ((float*)dstLds)[tid] = __uint_as_float((unsigned)a_);                    \
  }

__global__ __launch_bounds__(512, 1)
void k3_seq(const float* __restrict__ gihs, const float* __restrict__ Pm,
            const float* __restrict__ M2m,
            const float* __restrict__ whh0, const float* __restrict__ bhh0,
            const float* __restrict__ wih1, const float* __restrict__ bih1,
            const float* __restrict__ whh1, const float* __restrict__ bhh1,
            const int* __restrict__ tfm,
            float* __restrict__ h1s,
            unsigned long long* __restrict__ h0p, unsigned long long* __restrict__ h1p)
{
  __shared__ float wq[24][260], wh0s[24][260], wi1s[24][260], wh1s[24][260];
  __shared__ float h0c[2][256], h1c[2][256];
  __shared__ float dotsS[2][2][3][8];
  __shared__ int tfl[TT];
  const int tid = threadIdx.x;
  const int wg = blockIdx.x;
  const int j0 = wg * 8;           // this WG owns h dims [j0, j0+8)

  { // weight LDS init: both 256-thread halves load alternating rows
    const int col = tid & 255, rh = tid >> 8;
    for (int row = rh; row < 24; row += 2) {
      const int g = row >> 3, jj = row & 7;
      const long gr = g * 256 + j0 + jj;
      wq[row][col]   = M2m[gr * 256 + col];
      wh0s[row][col] = whh0[gr * 256 + col];
      wi1s[row][col] = wih1[gr * 256 + col];
      wh1s[row][col] = whh1[gr * 256 + col];
    }
  }
  ((float*)h0c)[tid] = 0.f;
  ((float*)h1c)[tid] = 0.f;
  if (tid < TT) tfl[tid] = tfm[tid];

  const int cb = tid >> 3, cjj = tid & 7, cj = j0 + cjj;   // combine threads (tid<16)
  float bh0v[3], bi1v[3], bh1v[3], d2v[3];
  if (tid < 16) {
#pragma unroll
    for (int g = 0; g < 3; ++g) {
      bh0v[g] = bhh0[g*256 + cj];
      bi1v[g] = bih1[g*256 + cj];
      bh1v[g] = bhh1[g*256 + cj];
      d2v[g]  = Pm[(long)1026 * 768 + g*256 + cj];
    }
  }
  __syncthreads();

  const int wave = tid >> 6, dsub = (tid >> 4) & 3, kl = tid & 15;
  for (int t = 0; t < TT; ++t) {
    // prefetch combine inputs (independent of dots; hidden under RUN_DOTS)
    float gihsv[3], piv[3];
    if (tid < 16) {
      const long r = (long)cb * TT + t;
      const long prow = (t == 0) ? (1024 + cb) : ((long)cb * TT + (t - 1));
#pragma unroll
      for (int g = 0; g < 3; ++g) {
        gihsv[g] = gihs[r * 768 + g*256 + cj];
        piv[g]   = Pm[prow * 768 + g*256 + cj];
      }
    }
    // phase A: q = h1_{t-1} @ M2^T ; gh = h0_{t-1} @ whh0^T
    RUN_DOTS(wq, wh0s, h1c, h0c);
    __syncthreads();
    if (tid < 16) {
      const int tfprev = (t == 0) ? 1 : tfl[t - 1];
      float gi[3], gh[3];
#pragma unroll
      for (int g = 0; g < 3; ++g) {
        const float q = dotsS[0][cb][g][cjj] + d2v[g];
        gi[g] = gihsv[g] + (tfprev ? piv[g] : q);
        gh[g] = dotsS[1][cb][g][cjj] + bh0v[g];
      }
      const float rr = 1.f / (1.f + __expf(-(gi[0] + gh[0])));
      const float zz = 1.f / (1.f + __expf(-(gi[1] + gh[1])));
      const float nn = tanhf(gi[2] + rr * gh[2]);
      const float h0n = (1.f - zz) * nn + zz * h0c[cb][cj];
      const unsigned long long pk =
          ((unsigned long long)(unsigned)(t + 1) << 32) | (unsigned long long)__float_as_uint(h0n);
      __hip_atomic_store(&h0p[cb * 256 + cj], pk, __ATOMIC_RELAXED, __HIP_MEMORY_SCOPE_AGENT);
    }
    __syncthreads();            // old h0c fully read before overwrite
    POLL_FILL(h0p, h0c, t + 1); // gather h0_t from all WGs
    __syncthreads();
    // phase B: gi1 = h0_t @ wih1^T ; gh1 = h1_{t-1} @ whh1^T
    RUN_DOTS(wi1s, wh1s, h0c, h1c);
    __syncthreads();
    if (tid < 16) {
      float gi[3], gh[3];
#pragma unroll
      for (int g = 0; g < 3; ++g) {
        gi[g] = dotsS[0][cb][g][cjj] + bi1v[g];
        gh[g] = dotsS[1][cb][g][cjj] + bh1v[g];
      }
      const float rr = 1.f / (1.f + __expf(-(gi[0] + gh[0])));
      const float zz = 1.f / (1.f + __expf(-(gi[1] + gh[1])));
      const float nn = tanhf(gi[2] + rr * gh[2]);
      const float h1n = (1.f - zz) * nn + zz * h1c[cb][cj];
      h1s[((long)cb * TT + t) * 256 + cj] = h1n;   // consumed by a later kernel
      const unsigned long long pk =
          ((unsigned long long)(unsigned)(t + 1) << 32) | (unsigned long long)__float_as_uint(h1n);
      __hip_atomic_store(&h1p[cb * 256 + cj], pk, __ATOMIC_RELAXED, __HIP_MEMORY_SCOPE_AGENT);
    }
    __syncthreads();            // old h1c fully read before overwrite
    POLL_FILL(h1p, h1c, t + 1); // gather h1_t from all WGs
    __syncthreads();
  }
}

__global__ void loss_finalize(const float* __restrict__ lossp, int n, float* __restrict__ out) {
  __shared__ float red[256];
  float s = 0.f;
  for (int i = threadIdx.x; i < n; i += 256) s += lossp[i];
  red[threadIdx.x] = s;
  __syncthreads();
  for (int st = 128; st > 0; st >>= 1) {
    if (threadIdx.x < st) red[threadIdx.x] += red[threadIdx.x + st];
    __syncthreads();
  }
  if (threadIdx.x == 0) out[0] = red[0] * (1.0f / 71792640.0f);
}

// ---------------------------------------------------------------------------
extern "C" void kernel_launch(void* const* d_in, const int* in_sizes, int n_in,
                              void* d_out, int out_size, void* d_ws, size_t ws_size,
                              hipStream_t stream) {
  (void)in_sizes; (void)n_in; (void)out_size; (void)ws_size;
  const float* hs   = (const float*)d_in[0];
  const float* tmpl = (const float*)d_in[1];
  const float* vert = (const float*)d_in[2];
  const int*   tfm  = (const int*)  d_in[3];
  const float* wih0 = (const float*)d_in[4];
  const float* whh0 = (const float*)d_in[5];
  const float* bih0 = (const float*)d_in[6];
  const float* bhh0 = (const float*)d_in[7];
  const float* wih1 = (const float*)d_in[8];
  const float* whh1 = (const float*)d_in[9];
  const float* bih1 = (const float*)d_in[10];
  const float* bhh1 = (const float*)d_in[11];
  const float* fcw  = (const float*)d_in[12];
  const float* fcb  = (const float*)d_in[13];
  const float* redw = (const float*)d_in[14];
  const float* redb = (const float*)d_in[15];
  float* out = (float*)d_out;

  char* ws = (char*)d_ws;
  float*    OUTG  = (float*)(ws + 0);          // [768][1026] = G^T (no red_b)
  float*    OUTM  = (float*)(ws + 3151872);    // [768][257]  = [M | fbred]
  unsigned long long* H0P = (unsigned long long*)(ws + 3941376); // 512 packed
  unsigned long long* H1P = (unsigned long long*)(ws + 3945472); // 512 packed
  float*    GF    = (float*)(ws + 3949568);    // [1027][768]
  float*    MT    = (float*)(ws + 7104512);    // [256][768]  = M^T
  float*    GIHS  = (float*)(ws + 7890944);    // [1024][768]
  float*    PM    = (float*)(ws + 11036672);   // [1027][768]
  float*    M2    = (float*)(ws + 14191616);   // [768][256]
  float*    H1S   = (float*)(ws + 14978048);   // [1024][256]
  float*    LOSSP = (float*)(ws + 16026624);   // [4384]

  // zero split-K accumulators + packed tag buffers (must happen every call)
  hipMemsetAsync(d_ws, 0, 3949568, stream);

  // big V-contractions (split-K, 24 chunks of 2922)
  bigk_kernel<false><<<dim3(5, 3, 24), 512, 0, stream>>>(redw, vert, tmpl, OUTG, 1026, 768, 1026, VD, 2922);
  bigk_kernel<true ><<<dim3(2, 3, 24), 512, 0, stream>>>(redw, fcw,  fcb,  OUTM, 257,  768, 257,  VD, 2922);

  // transposes (+red_b fold)
  transpose_bias<<<dim3(33, 24), 256, 0, stream>>>(OUTG, 1026, 0,   GF,                 768, 1026, 768, redb);
  transpose_bias<<<dim3(8, 24),  256, 0, stream>>>(OUTM, 257,  0,   MT,                 768, 256,  768, nullptr);
  transpose_bias<<<dim3(1, 24),  256, 0, stream>>>(OUTM, 257,  256, GF + (long)1026*768, 768, 1,   768, redb);

  // small GEMMs: gihs, P (incl. c0term rows 1024/1025 and d2 row 1026), M2
  gemm128<0><<<dim3(8, 6), 256, 0, stream>>>(hs,        768,  wih0,       1536, GIHS, 768, bih0,    1024, 768, 768, nullptr, nullptr);
  gemm128<0><<<dim3(9, 6), 256, 0, stream>>>(GF,        768,  wih0 + 768, 1536, PM,   768, nullptr, 1027, 768, 768, nullptr, nullptr);
  gemm128<0><<<dim3(6, 2), 256, 0, stream>>>(wih0 + 768, 1536, MT,        768,  M2,   256, nullptr, 768,  256, 768, nullptr, nullptr);

  // sequential recurrence (persistent, 32 WGs x 512 threads, tagged-data sync)
  k3_seq<<<32, 512, 0, stream>>>(GIHS, PM, M2, whh0, bhh0, wih1, bih1, whh1, bhh1,
                                 tfm, H1S, H0P, H1P);

  // final fc GEMM + fused MSE partials, then loss
  gemm128<2><<<dim3(8, 548), 256, 0, stream>>>(H1S, 256, fcw, 256, out, VD, fcb, 1024, VD, 256, vert, LOSSP);
  loss_finalize<<<1, 256, 0, stream>>>(LOSSP, 4384, out + 71792640L);
}

// Round 7
// 3598.792 us; speedup vs baseline: 2.2498x; 1.0350x over previous
//
#include <hip/hip_runtime.h>
#include <hip/hip_bf16.h>

// ---------------------------------------------------------------------------
// FaceXHuBERT decoder: 2-layer GRU (H=256) over T=512 + fc to V=70110 with
// teacher-forcing feedback through red_w [A=768, V].
//
// Restructure so the T-loop never touches V:
//   OUT_G = red_w @ vert^T (1024 cols)         (split-K bf16 MFMA, atomicAdd)
//   OUT_M = red_w @ fc_w   (256 cols)          (ditto)
//   EXTRA = red_w @ [tmpl0|tmpl1|fc_b]         (gemv3, memory-bound)
//   Gf[r][a] = OUT_G[a][r] + red_b[a]; rows 1024/1025 = tmpl-cols + red_b;
//              row 1026 = fbred + red_b        (fixup)
//   P   = Gf @ Wr^T        (rows 0..1023 = P_t; 1024/1025 = c0term; 1026 = d2)
//   gihs= hs @ Wl^T + b_ih_l0 ;  M2 = Wr @ (red_w@fc_w)   [768x256]
// In-loop: gi_l0 = gihs_t + (t==0 ? c0term : tf[t-1] ? P_{t-1} : h1@M2^T+d2)
// Final: preds = h1s @ fc_w^T + fc_b (bf16 MFMA) fused with MSE loss.
//
// Round 7: tf-aware exchange DECOUPLING in k3_seq. h0_t needs h1_{t-1} only
// when tf[t-1]==0; otherwise the h1 wait is deferred past the h0 exchange
// (where it has already landed). Critical path: 1 IC exchange per tf=1 step,
// 2 per tf=0 step (~1.5 avg vs 2.0). Requires parity double-buffers on the
// tagged h0p/h1p words (tag chain proof: writer of tag k+2 to a parity buffer
// is gated through all-WGs' publish of h0 tag k+2, which implies consumption
// of tag k). Plus: one-step-ahead gihs/Pm prefetch; bigk padding removed
// (template/fcb columns -> gemv3 kernel; bigk grids exact 1024/256).
// ---------------------------------------------------------------------------

#define TT 512
#define VD 70110
#define NR 1024  // B*T

using bf16x8 = __attribute__((ext_vector_type(8))) short;
using f32x4  = __attribute__((ext_vector_type(4))) float;

static __device__ __forceinline__ unsigned short f2bf(float f) {
  unsigned u = __float_as_uint(f);
  u += 0x7FFFu + ((u >> 16) & 1u);   // RNE
  return (unsigned short)(u >> 16);
}

// ---------------- big split-K GEMM over V (bf16 MFMA, atomicAdd epilogue) ---
template<bool BFORM>
__global__ __launch_bounds__(512, 1)
void bigk_kernel(const float* __restrict__ A, const float* __restrict__ Bv,
                 const float* __restrict__ Bt, float* __restrict__ C, int ldc,
                 int M, int N, int K, int CHK)
{
  __shared__ unsigned short Al[256][40];
  __shared__ unsigned short Bl[256][40];
  const int tid = threadIdx.x;
  const int n0 = blockIdx.x * 256, m0 = blockIdx.y * 256;
  const int kc0 = blockIdx.z * CHK;
  const int kc1 = min(K, kc0 + CHK);
  const int wave = tid >> 6, lane = tid & 63;
  const int wm = wave >> 1, wn = wave & 1;
  const int kq = lane >> 4, ln = lane & 15;
  f32x4 acc[4][8] = {};
  for (int kc = kc0; kc < kc1; kc += 32) {
    __syncthreads();
    { // stage A: 256 rows x 32 k
      const int m = tid >> 1, kh = (tid & 1) << 4;
      const bool mok = (m0 + m) < M;
      const float* arow = A + (long)(m0 + m) * (long)K;
      unsigned short tmp[16] __attribute__((aligned(16)));
      if (mok && (kc + 32 <= kc1)) {
        const float2* ap2 = (const float2*)(arow + kc + kh);
#pragma unroll
        for (int i = 0; i < 8; ++i) { float2 v = ap2[i]; tmp[2*i] = f2bf(v.x); tmp[2*i+1] = f2bf(v.y); }
      } else {
#pragma unroll
        for (int i = 0; i < 16; ++i) {
          int kk = kc + kh + i;
          tmp[i] = f2bf((mok && kk < kc1) ? arow[kk] : 0.f);
        }
      }
      ((int4*)&Al[m][kh])[0] = *(int4*)&tmp[0];
      ((int4*)&Al[m][kh])[1] = *(int4*)&tmp[8];
    }
    if (!BFORM) { // stage B from row-major rows (vert)
      const int n = tid >> 1, kh = (tid & 1) << 4;
      const int gn = n0 + n;
      const float* bp = nullptr;
      if (gn < 1024) bp = Bv + (long)gn * (long)VD;
      else if (gn < N) bp = Bt + (long)(gn - 1024) * (long)VD;
      unsigned short tmp[16] __attribute__((aligned(16)));
      if (bp && (kc + 32 <= kc1)) {
        const float2* bp2 = (const float2*)(bp + kc + kh);
#pragma unroll
        for (int i = 0; i < 8; ++i) { float2 v = bp2[i]; tmp[2*i] = f2bf(v.x); tmp[2*i+1] = f2bf(v.y); }
      } else {
#pragma unroll
        for (int i = 0; i < 16; ++i) {
          int kk = kc + kh + i;
          tmp[i] = f2bf((bp && kk < kc1) ? bp[kk] : 0.f);
        }
      }
      ((int4*)&Bl[n][kh])[0] = *(int4*)&tmp[0];
      ((int4*)&Bl[n][kh])[1] = *(int4*)&tmp[8];
    } else {      // stage B from k-major fc_w (transpose into LDS, coalesced n)
      const int n = tid & 255, kh = (tid >> 8) << 4;
      const int gn = n0 + n;
      unsigned short tmp[16] __attribute__((aligned(16)));
#pragma unroll
      for (int i = 0; i < 16; ++i) {
        int kk = kc + kh + i;
        float v = 0.f;
        if (kk < kc1 && gn < 256) v = Bv[(long)kk * 256 + gn];
        tmp[i] = f2bf(v);
      }
      ((int4*)&Bl[n][kh])[0] = *(int4*)&tmp[0];
      ((int4*)&Bl[n][kh])[1] = *(int4*)&tmp[8];
    }
    __syncthreads();
    bf16x8 af[4], bfv[8];
#pragma unroll
    for (int i = 0; i < 4; ++i) af[i] = *(const bf16x8*)&Al[wm*64 + i*16 + ln][kq*8];
#pragma unroll
    for (int j = 0; j < 8; ++j) bfv[j] = *(const bf16x8*)&Bl[wn*128 + j*16 + ln][kq*8];
#pragma unroll
    for (int i = 0; i < 4; ++i)
#pragma unroll
      for (int j = 0; j < 8; ++j)
        acc[i][j] = __builtin_amdgcn_mfma_f32_16x16x32_bf16(af[i], bfv[j], acc[i][j], 0, 0, 0);
  }
#pragma unroll
  for (int i = 0; i < 4; ++i)
#pragma unroll
    for (int j = 0; j < 8; ++j)
#pragma unroll
      for (int r = 0; r < 4; ++r) {
        int gm = m0 + wm*64 + i*16 + kq*4 + r;
        int gn = n0 + wn*128 + j*16 + ln;
        if (gm < M && gn < N) unsafeAtomicAdd(&C[(long)gm * ldc + gn], acc[i][j][r]);
      }
}

// ---------------- gemv3: EXTRA[v][a] = sum_k {tmpl0,tmpl1,fcb}[k]*redw[a][k]
__global__ __launch_bounds__(256)
void gemv3(const float* __restrict__ redw, const float* __restrict__ tmpl,
           const float* __restrict__ fcb, float* __restrict__ extra)
{
  const int tid = threadIdx.x;
  const int a0 = blockIdx.x * 8;
  const long k0 = (long)blockIdx.y * 8764;
  const long k1 = (k0 + 8764 < (long)VD) ? (k0 + 8764) : (long)VD;
  float s[3][8] = {};
  for (long k = k0 + tid; k < k1; k += 256) {
    const float c0 = tmpl[k], c1 = tmpl[(long)VD + k], cb2 = fcb[k];
#pragma unroll
    for (int r = 0; r < 8; ++r) {
      const float w = redw[(long)(a0 + r) * VD + k];
      s[0][r] += c0 * w; s[1][r] += c1 * w; s[2][r] += cb2 * w;
    }
  }
#pragma unroll
  for (int v = 0; v < 3; ++v)
#pragma unroll
    for (int r = 0; r < 8; ++r) {
      float x = s[v][r];
#pragma unroll
      for (int o = 32; o > 0; o >>= 1) x += __shfl_down(x, o);
      if ((tid & 63) == 0) unsafeAtomicAdd(&extra[v * 768 + a0 + r], x);
    }
}

// GF rows 1024/1025 (template c0term) and 1026 (fbred) = EXTRA + red_b
__global__ void fixup_gf(const float* __restrict__ extra, const float* __restrict__ redb,
                         float* __restrict__ gf)
{
  for (int i = threadIdx.x; i < 3 * 768; i += 256) {
    const int b = i / 768, a = i - b * 768;
    gf[(long)(1024 + b) * 768 + a] = extra[i] + redb[a];
  }
}

// ---------------- generic 128x128 bf16-MFMA GEMM: C = A @ B^T (+bias) -------
template<int EPI>
__global__ __launch_bounds__(256, 2)
void gemm128(const float* __restrict__ A, int lda,
             const float* __restrict__ B, int ldb,
             float* __restrict__ C, long ldc,
             const float* __restrict__ bias,
             int M, int N, int K,
             const float* __restrict__ vert, float* __restrict__ lossp)
{
  __shared__ unsigned short Al[128][40];
  __shared__ unsigned short Bl[128][40];
  const int tid = threadIdx.x;
  const int m0 = blockIdx.x * 128, n0 = blockIdx.y * 128;
  const int wave = tid >> 6, lane = tid & 63;
  const int wm = wave >> 1, wn = wave & 1;
  const int kq = lane >> 4, ln = lane & 15;
  f32x4 acc[4][4] = {};
  for (int kc = 0; kc < K; kc += 32) {
    __syncthreads();
    {
      const int m = tid >> 1, kh = (tid & 1) << 4;
      unsigned short tmp[16] __attribute__((aligned(16)));
      const bool mok = (m0 + m) < M;
      if (mok) {
        const float4* ap4 = (const float4*)(A + (long)(m0 + m) * lda + kc + kh);
#pragma unroll
        for (int i = 0; i < 4; ++i) {
          float4 v = ap4[i];
          tmp[4*i+0] = f2bf(v.x); tmp[4*i+1] = f2bf(v.y);
          tmp[4*i+2] = f2bf(v.z); tmp[4*i+3] = f2bf(v.w);
        }
      } else {
#pragma unroll
        for (int i = 0; i < 16; ++i) tmp[i] = 0;
      }
      ((int4*)&Al[m][kh])[0] = *(int4*)&tmp[0];
      ((int4*)&Al[m][kh])[1] = *(int4*)&tmp[8];
      const int n = m;  // same mapping for B
      unsigned short tmb[16] __attribute__((aligned(16)));
      const bool nok = (n0 + n) < N;
      if (nok) {
        const float4* bp4 = (const float4*)(B + (long)(n0 + n) * ldb + kc + kh);
#pragma unroll
        for (int i = 0; i < 4; ++i) {
          float4 v = bp4[i];
          tmb[4*i+0] = f2bf(v.x); tmb[4*i+1] = f2bf(v.y);
          tmb[4*i+2] = f2bf(v.z); tmb[4*i+3] = f2bf(v.w);
        }
      } else {
#pragma unroll
        for (int i = 0; i < 16; ++i) tmb[i] = 0;
      }
      ((int4*)&Bl[n][kh])[0] = *(int4*)&tmb[0];
      ((int4*)&Bl[n][kh])[1] = *(int4*)&tmb[8];
    }
    __syncthreads();
    bf16x8 af[4], bfv[4];
#pragma unroll
    for (int i = 0; i < 4; ++i) af[i]  = *(const bf16x8*)&Al[wm*64 + i*16 + ln][kq*8];
#pragma unroll
    for (int j = 0; j < 4; ++j) bfv[j] = *(const bf16x8*)&Bl[wn*64 + j*16 + ln][kq*8];
#pragma unroll
    for (int i = 0; i < 4; ++i)
#pragma unroll
      for (int j = 0; j < 4; ++j)
        acc[i][j] = __builtin_amdgcn_mfma_f32_16x16x32_bf16(af[i], bfv[j], acc[i][j], 0, 0, 0);
  }
  float ls = 0.f;
#pragma unroll
  for (int i = 0; i < 4; ++i)
#pragma unroll
    for (int j = 0; j < 4; ++j)
#pragma unroll
      for (int r = 0; r < 4; ++r) {
        const int gm = m0 + wm*64 + i*16 + kq*4 + r;
        const int gn = n0 + wn*64 + j*16 + ln;
        if (gm < M && gn < N) {
          float v = acc[i][j][r];
          if (bias) v += bias[gn];
          C[(long)gm * ldc + gn] = v;
          if (EPI == 2) { float d = v - vert[(long)gm * VD + gn]; ls += d * d; }
        }
      }
  if (EPI == 2) {
#pragma unroll
    for (int o = 32; o > 0; o >>= 1) ls += __shfl_down(ls, o);
    __shared__ float wred[4];
    if ((tid & 63) == 0) wred[wave] = ls;
    __syncthreads();
    if (tid == 0) lossp[blockIdx.y * gridDim.x + blockIdx.x] = wred[0] + wred[1] + wred[2] + wred[3];
  }
}

// ---------------- transpose with optional bias ------------------------------
__global__ void transpose_bias(const float* __restrict__ src, int lds, int row0,
                               float* __restrict__ dst, int ldd,
                               int rows, int cols, const float* __restrict__ bias)
{
  __shared__ float tile[32][33];
  const int rb = blockIdx.x * 32, cb = blockIdx.y * 32;
  const int tx = threadIdx.x & 31, ty = threadIdx.x >> 5;
  for (int yy = ty; yy < 32; yy += 8) {
    int c = cb + yy, r = rb + tx;
    tile[yy][tx] = (c < cols && r < rows) ? src[(long)c * lds + row0 + r] : 0.f;
  }
  __syncthreads();
  for (int yy = ty; yy < 32; yy += 8) {
    int r = rb + yy, c = cb + tx;
    if (r < rows && c < cols)
      dst[(long)r * ldd + c] = tile[tx][yy] + (bias ? bias[c] : 0.f);
  }
}

// ---------------- persistent sequential GRU kernel (32 WGs x 512 thr) -------
// Tagged packed u64 {tag:32|val:32}, relaxed agent-scope atomics, parity
// double-buffered (h0p/h1p = [2][512]). tf-aware decoupling: the h1 wait is
// issued before dots0 only when tf[t-1]==0 (q-path); otherwise deferred to
// after the h0 exchange where it has already landed (off critical path).

#define RUN_DOTS(W0, W1, H0, H1)                                              \
  {                                                                           \
    _Pragma("unroll")                                                         \
    for (int pass = 0; pass < 3; ++pass) {                                    \
      const int D = pass * 32 + wave * 4 + dsub;                              \
      const int mat = (D >= 48) ? 1 : 0;                                      \
      const int rem = D - mat * 48;                                           \
      const int row = rem >> 1, bb = rem & 1;                                 \
      const float4* w4 = (const float4*)(mat ? W1[row] : W0[row]);            \
      const float4* h4 = (const float4*)(mat ? H1[bb] : H0[bb]);              \
      float s = 0.f;                                                          \
      _Pragma("unroll")                                                       \
      for (int i = 0; i < 4; ++i) {                                           \
        const float4 a = w4[i * 16 + kl], h = h4[i * 16 + kl];                \
        s += a.x * h.x + a.y * h.y + a.z * h.z + a.w * h.w;                   \
      }                                                                       \
      s += __shfl_xor(s, 1); s += __shfl_xor(s, 2);                           \
      s += __shfl_xor(s, 4); s += __shfl_xor(s, 8);                           \
      if (kl == 0) dotsS[mat][bb][row >> 3][row & 7] = s;                     \
    }                                                                         \
  }

// Each of 512 threads polls ONE packed word of `buf` until tag >= want.
#define POLLP(buf, dstLds, want)                                              \
  {                                                                           \
    const unsigned w_ = (unsigned)(want);                                     \
    unsigned long long a_ = __hip_atomic_load(&(buf)[tid], __ATOMIC_RELAXED, __HIP_MEMORY_SCOPE_AGENT); \
    int sp_ = 0;                                                              \
    while ((unsigned)(a_ >> 32) < w_ && ++sp_ < (1 << 15)) {                  \
      __builtin_amdgcn_s_sleep(1);                                            \
      a_ = __hip_atomic_load(&(buf)[tid], __ATOMIC_RELAXED, __HIP_MEMORY_SCOPE_AGENT); \
    }                                                                         \
    ((float*)dstLds)[tid] = __uint_as_float((unsigned)a_);                    \
  }

__global__ __launch_bounds__(512, 1)
void k3_seq(const float* __restrict__ gihs, const float* __restrict__ Pm,
            const float* __restrict__ M2m,
            const float* __restrict__ whh0, const float* __restrict__ bhh0,
            const float* __restrict__ wih1, const float* __restrict__ bih1,
            const float* __restrict__ whh1, const float* __restrict__ bhh1,
            const int* __restrict__ tfm,
            float* __restrict__ h1s,
            unsigned long long* __restrict__ h0p, unsigned long long* __restrict__ h1p)
{
  __shared__ float wq[24][260], wh0s[24][260], wi1s[24][260], wh1s[24][260];
  __shared__ float h0c[2][256], h1c[2][256];
  __shared__ float dotsS[2][2][3][8];
  __shared__ int tfl[TT];
  const int tid = threadIdx.x;
  const int wg = blockIdx.x;
  const int j0 = wg * 8;           // this WG owns h dims [j0, j0+8)

  { // weight LDS init: both 256-thread halves load alternating rows
    const int col = tid & 255, rh = tid >> 8;
    for (int row = rh; row < 24; row += 2) {
      const int g = row >> 3, jj = row & 7;
      const long gr = g * 256 + j0 + jj;
      wq[row][col]   = M2m[gr * 256 + col];
      wh0s[row][col] = whh0[gr * 256 + col];
      wi1s[row][col] = wih1[gr * 256 + col];
      wh1s[row][col] = whh1[gr * 256 + col];
    }
  }
  ((float*)h0c)[tid] = 0.f;
  ((float*)h1c)[tid] = 0.f;
  if (tid < TT) tfl[tid] = tfm[tid];

  const int cb = tid >> 3, cjj = tid & 7, cj = j0 + cjj;   // combine threads (tid<16)
  float bh0v[3], bi1v[3], bh1v[3], d2v[3];
  if (tid < 16) {
#pragma unroll
    for (int g = 0; g < 3; ++g) {
      bh0v[g] = bhh0[g*256 + cj];
      bi1v[g] = bih1[g*256 + cj];
      bh1v[g] = bhh1[g*256 + cj];
      d2v[g]  = Pm[(long)1026 * 768 + g*256 + cj];
    }
  }
  __syncthreads();

  const int wave = tid >> 6, dsub = (tid >> 4) & 3, kl = tid & 15;
  // one-step-ahead prefetch registers (combine inputs for step t)
  float gihsv[3], piv[3];
  if (tid < 16) {
#pragma unroll
    for (int g = 0; g < 3; ++g) {
      gihsv[g] = gihs[((long)cb * TT) * 768 + g*256 + cj];
      piv[g]   = Pm[(long)(1024 + cb) * 768 + g*256 + cj];
    }
  }
  for (int t = 0; t < TT; ++t) {
    const int tfprev = (t == 0) ? 1 : tfl[t - 1];
    if (!tfprev) {               // q-path needs h1_{t-1} BEFORE dots0
      POLLP(h1p + (t & 1) * 512, h1c, t);
      __syncthreads();
    }
    // phase A: q = h1_{t-1} @ M2^T ; gh = h0_{t-1} @ whh0^T
    RUN_DOTS(wq, wh0s, h1c, h0c);
    __syncthreads();
    if (tid < 16) {
      float gi[3], gh[3];
#pragma unroll
      for (int g = 0; g < 3; ++g) {
        const float q = dotsS[0][cb][g][cjj] + d2v[g];
        gi[g] = gihsv[g] + (tfprev ? piv[g] : q);
        gh[g] = dotsS[1][cb][g][cjj] + bh0v[g];
      }
      const float rr = 1.f / (1.f + __expf(-(gi[0] + gh[0])));
      const float zz = 1.f / (1.f + __expf(-(gi[1] + gh[1])));
      const float nn = tanhf(gi[2] + rr * gh[2]);
      const float h0n = (1.f - zz) * nn + zz * h0c[cb][cj];
      const unsigned long long pk =
          ((unsigned long long)(unsigned)(t + 1) << 32) | (unsigned long long)__float_as_uint(h0n);
      __hip_atomic_store(&h0p[((t + 1) & 1) * 512 + cb * 256 + cj], pk,
                         __ATOMIC_RELAXED, __HIP_MEMORY_SCOPE_AGENT);
    }
    // prefetch combine inputs for step t+1 (lands under the exchange)
    if (tid < 16 && t + 1 < TT) {
#pragma unroll
      for (int g = 0; g < 3; ++g) {
        gihsv[g] = gihs[((long)cb * TT + (t + 1)) * 768 + g*256 + cj];
        piv[g]   = Pm[((long)cb * TT + t) * 768 + g*256 + cj];
      }
    }
    __syncthreads();             // dots0 readers of h0c done before overwrite
    POLLP(h0p + ((t + 1) & 1) * 512, h0c, t + 1);  // gather h0_t
    __syncthreads();
    if (tfprev) {                // deferred h1_{t-1} wait (already landed)
      POLLP(h1p + (t & 1) * 512, h1c, t);
      __syncthreads();
    }
    // phase B: gi1 = h0_t @ wih1^T ; gh1 = h1_{t-1} @ whh1^T
    RUN_DOTS(wi1s, wh1s, h0c, h1c);
    __syncthreads();
    if (tid < 16) {
      float gi[3], gh[3];
#pragma unroll
      for (int g = 0; g < 3; ++g) {
        gi[g] = dotsS[0][cb][g][cjj] + bi1v[g];
        gh[g] = dotsS[1][cb][g][cjj] + bh1v[g];
      }
      const float rr = 1.f / (1.f + __expf(-(gi[0] + gh[0])));
      const float zz = 1.f / (1.f + __expf(-(gi[1] + gh[1])));
      const float nn = tanhf(gi[2] + rr * gh[2]);
      const float h1n = (1.f - zz) * nn + zz * h1c[cb][cj];
      h1s[((long)cb * TT + t) * 256 + cj] = h1n;   // consumed by a later kernel
      const unsigned long long pk =
          ((unsigned long long)(unsigned)(t + 1) << 32) | (unsigned long long)__float_as_uint(h1n);
      __hip_atomic_store(&h1p[((t + 1) & 1) * 512 + cb * 256 + cj], pk,
                         __ATOMIC_RELAXED, __HIP_MEMORY_SCOPE_AGENT);
    }
    __syncthreads();             // dots1 readers of h1c done before next poll
  }
}

__global__ void loss_finalize(const float* __restrict__ lossp, int n, float* __restrict__ out) {
  __shared__ float red[256];
  float s = 0.f;
  for (int i = threadIdx.x; i < n; i += 256) s += lossp[i];
  red[threadIdx.x] = s;
  __syncthreads();
  for (int st = 128; st > 0; st >>= 1) {
    if (threadIdx.x < st) red[threadIdx.x] += red[threadIdx.x + st];
    __syncthreads();
  }
  if (threadIdx.x == 0) out[0] = red[0] * (1.0f / 71792640.0f);
}

// ---------------------------------------------------------------------------
extern "C" void kernel_launch(void* const* d_in, const int* in_sizes, int n_in,
                              void* d_out, int out_size, void* d_ws, size_t ws_size,
                              hipStream_t stream) {
  (void)in_sizes; (void)n_in; (void)out_size; (void)ws_size;
  const float* hs   = (const float*)d_in[0];
  const float* tmpl = (const float*)d_in[1];
  const float* vert = (const float*)d_in[2];
  const int*   tfm  = (const int*)  d_in[3];
  const float* wih0 = (const float*)d_in[4];
  const float* whh0 = (const float*)d_in[5];
  const float* bih0 = (const float*)d_in[6];
  const float* bhh0 = (const float*)d_in[7];
  const float* wih1 = (const float*)d_in[8];
  const float* whh1 = (const float*)d_in[9];
  const float* bih1 = (const float*)d_in[10];
  const float* bhh1 = (const float*)d_in[11];
  const float* fcw  = (const float*)d_in[12];
  const float* fcb  = (const float*)d_in[13];
  const float* redw = (const float*)d_in[14];
  const float* redb = (const float*)d_in[15];
  float* out = (float*)d_out;

  char* ws = (char*)d_ws;
  float*    LOSSP = (float*)(ws + 0);          // [4384] overlaps OUTG (dead by then)
  float*    OUTG  = (float*)(ws + 0);          // [768][1024] = G^T (no red_b)
  float*    OUTM  = (float*)(ws + 3145728);    // [768][256]  = M (no bias col)
  float*    EXTRA = (float*)(ws + 3932160);    // [3][768] tmpl0/tmpl1/fcb gemv
  unsigned long long* H0P = (unsigned long long*)(ws + 3941376); // [2][512]
  unsigned long long* H1P = (unsigned long long*)(ws + 3949568); // [2][512]
  float*    GF    = (float*)(ws + 3957760);    // [1027][768]
  float*    MT    = (float*)(ws + 7112704);    // [256][768]  = M^T
  float*    GIHS  = (float*)(ws + 7899136);    // [1024][768]
  float*    PM    = (float*)(ws + 11044864);   // [1027][768]
  float*    M2    = (float*)(ws + 14199808);   // [768][256]
  float*    H1S   = (float*)(ws + 14986240);   // [1024][256]

  // zero split-K accumulators + EXTRA + parity tag buffers (every call)
  hipMemsetAsync(d_ws, 0, 3957760, stream);

  // big V-contractions (split-K, 24 chunks of 2922) — exact tiles, no padding
  bigk_kernel<false><<<dim3(4, 3, 24), 512, 0, stream>>>(redw, vert, tmpl, OUTG, 1024, 768, 1024, VD, 2922);
  bigk_kernel<true ><<<dim3(1, 3, 24), 512, 0, stream>>>(redw, fcw,  fcb,  OUTM, 256,  768, 256,  VD, 2922);
  gemv3<<<dim3(96, 8), 256, 0, stream>>>(redw, tmpl, fcb, EXTRA);

  // transposes (+red_b fold) and odd-row fixup
  transpose_bias<<<dim3(32, 24), 256, 0, stream>>>(OUTG, 1024, 0, GF, 768, 1024, 768, redb);
  transpose_bias<<<dim3(8, 24),  256, 0, stream>>>(OUTM, 256,  0, MT, 768, 256,  768, nullptr);
  fixup_gf<<<1, 256, 0, stream>>>(EXTRA, redb, GF);

  // small GEMMs: gihs, P (incl. c0term rows 1024/1025 and d2 row 1026), M2
  gemm128<0><<<dim3(8, 6), 256, 0, stream>>>(hs,        768,  wih0,       1536, GIHS, 768, bih0,    1024, 768, 768, nullptr, nullptr);
  gemm128<0><<<dim3(9, 6), 256, 0, stream>>>(GF,        768,  wih0 + 768, 1536, PM,   768, nullptr, 1027, 768, 768, nullptr, nullptr);
  gemm128<0><<<dim3(6, 2), 256, 0, stream>>>(wih0 + 768, 1536, MT,        768,  M2,   256, nullptr, 768,  256, 768, nullptr, nullptr);

  // sequential recurrence (32 WGs x 512 threads, tf-decoupled tagged sync)
  k3_seq<<<32, 512, 0, stream>>>(GIHS, PM, M2, whh0, bhh0, wih1, bih1, whh1, bhh1,
                                 tfm, H1S, H0P, H1P);

  // final fc GEMM + fused MSE partials, then loss
  gemm128<2><<<dim3(8, 548), 256, 0, stream>>>(H1S, 256, fcw, 256, out, VD, fcb, 1024, VD, 256, vert, LOSSP);
  loss_finalize<<<1, 256, 0, stream>>>(LOSSP, 4384, out + 71792640L);
}

// Round 8
// 3226.801 us; speedup vs baseline: 2.5092x; 1.1153x over previous
//
#include <hip/hip_runtime.h>
#include <hip/hip_bf16.h>

// ---------------------------------------------------------------------------
// FaceXHuBERT decoder: 2-layer GRU (H=256) over T=512 + fc to V=70110 with
// teacher-forcing feedback through red_w [A=768, V].
//
// Restructure so the T-loop never touches V:
//   OUT_G = red_w @ vert^T (1024 cols)         (split-K bf16 MFMA, atomicAdd)
//   OUT_M = red_w @ fc_w   (256 cols)          (ditto)
//   EXTRA = red_w @ [tmpl0|tmpl1|fc_b]         (gemv3, memory-bound)
//   Gf[r][a] = OUT_G[a][r] + red_b[a]; rows 1024/1025 = tmpl-cols + red_b;
//              row 1026 = fbred + red_b        (fixup)
//   P   = Gf @ Wr^T        (rows 0..1023 = P_t; 1024/1025 = c0term; 1026 = d2)
//   gihs= hs @ Wl^T + b_ih_l0 ;  M2 = Wr @ (red_w@fc_w)   [768x256]
// In-loop: gi_l0 = gihs_t + (t==0 ? c0term : tf[t-1] ? P_{t-1} : h1@M2^T+d2)
// Final: preds = h1s @ fc_w^T + fc_b (bf16 MFMA) fused with MSE loss.
//
// Round 8: (a) k3 dots split into per-matrix HALVES (48 dots x 8 lanes); the
// half not needing the pending h-vector runs while the poll load is in
// flight (issue-early / finish-late), hiding most of the IC RTT. (b) tf=1
// steps skip the wq-half entirely (its result was discarded). (c) bigk grids
// 252/63 blocks (z=21, CHK=3344) -> single occupancy pass, no 256+32 tail.
// ---------------------------------------------------------------------------

#define TT 512
#define VD 70110
#define NR 1024  // B*T

using bf16x8 = __attribute__((ext_vector_type(8))) short;
using f32x4  = __attribute__((ext_vector_type(4))) float;

static __device__ __forceinline__ unsigned short f2bf(float f) {
  unsigned u = __float_as_uint(f);
  u += 0x7FFFu + ((u >> 16) & 1u);   // RNE
  return (unsigned short)(u >> 16);
}

// ---------------- big split-K GEMM over V (bf16 MFMA, atomicAdd epilogue) ---
template<bool BFORM>
__global__ __launch_bounds__(512, 1)
void bigk_kernel(const float* __restrict__ A, const float* __restrict__ Bv,
                 const float* __restrict__ Bt, float* __restrict__ C, int ldc,
                 int M, int N, int K, int CHK)
{
  __shared__ unsigned short Al[256][40];
  __shared__ unsigned short Bl[256][40];
  const int tid = threadIdx.x;
  const int n0 = blockIdx.x * 256, m0 = blockIdx.y * 256;
  const int kc0 = blockIdx.z * CHK;
  const int kc1 = min(K, kc0 + CHK);
  const int wave = tid >> 6, lane = tid & 63;
  const int wm = wave >> 1, wn = wave & 1;
  const int kq = lane >> 4, ln = lane & 15;
  f32x4 acc[4][8] = {};
  for (int kc = kc0; kc < kc1; kc += 32) {
    __syncthreads();
    { // stage A: 256 rows x 32 k
      const int m = tid >> 1, kh = (tid & 1) << 4;
      const bool mok = (m0 + m) < M;
      const float* arow = A + (long)(m0 + m) * (long)K;
      unsigned short tmp[16] __attribute__((aligned(16)));
      if (mok && (kc + 32 <= kc1)) {
        const float2* ap2 = (const float2*)(arow + kc + kh);
#pragma unroll
        for (int i = 0; i < 8; ++i) { float2 v = ap2[i]; tmp[2*i] = f2bf(v.x); tmp[2*i+1] = f2bf(v.y); }
      } else {
#pragma unroll
        for (int i = 0; i < 16; ++i) {
          int kk = kc + kh + i;
          tmp[i] = f2bf((mok && kk < kc1) ? arow[kk] : 0.f);
        }
      }
      ((int4*)&Al[m][kh])[0] = *(int4*)&tmp[0];
      ((int4*)&Al[m][kh])[1] = *(int4*)&tmp[8];
    }
    if (!BFORM) { // stage B from row-major rows (vert)
      const int n = tid >> 1, kh = (tid & 1) << 4;
      const int gn = n0 + n;
      const float* bp = nullptr;
      if (gn < 1024) bp = Bv + (long)gn * (long)VD;
      else if (gn < N) bp = Bt + (long)(gn - 1024) * (long)VD;
      unsigned short tmp[16] __attribute__((aligned(16)));
      if (bp && (kc + 32 <= kc1)) {
        const float2* bp2 = (const float2*)(bp + kc + kh);
#pragma unroll
        for (int i = 0; i < 8; ++i) { float2 v = bp2[i]; tmp[2*i] = f2bf(v.x); tmp[2*i+1] = f2bf(v.y); }
      } else {
#pragma unroll
        for (int i = 0; i < 16; ++i) {
          int kk = kc + kh + i;
          tmp[i] = f2bf((bp && kk < kc1) ? bp[kk] : 0.f);
        }
      }
      ((int4*)&Bl[n][kh])[0] = *(int4*)&tmp[0];
      ((int4*)&Bl[n][kh])[1] = *(int4*)&tmp[8];
    } else {      // stage B from k-major fc_w (transpose into LDS, coalesced n)
      const int n = tid & 255, kh = (tid >> 8) << 4;
      const int gn = n0 + n;
      unsigned short tmp[16] __attribute__((aligned(16)));
#pragma unroll
      for (int i = 0; i < 16; ++i) {
        int kk = kc + kh + i;
        float v = 0.f;
        if (kk < kc1 && gn < 256) v = Bv[(long)kk * 256 + gn];
        tmp[i] = f2bf(v);
      }
      ((int4*)&Bl[n][kh])[0] = *(int4*)&tmp[0];
      ((int4*)&Bl[n][kh])[1] = *(int4*)&tmp[8];
    }
    __syncthreads();
    bf16x8 af[4], bfv[8];
#pragma unroll
    for (int i = 0; i < 4; ++i) af[i] = *(const bf16x8*)&Al[wm*64 + i*16 + ln][kq*8];
#pragma unroll
    for (int j = 0; j < 8; ++j) bfv[j] = *(const bf16x8*)&Bl[wn*128 + j*16 + ln][kq*8];
#pragma unroll
    for (int i = 0; i < 4; ++i)
#pragma unroll
      for (int j = 0; j < 8; ++j)
        acc[i][j] = __builtin_amdgcn_mfma_f32_16x16x32_bf16(af[i], bfv[j], acc[i][j], 0, 0, 0);
  }
#pragma unroll
  for (int i = 0; i < 4; ++i)
#pragma unroll
    for (int j = 0; j < 8; ++j)
#pragma unroll
      for (int r = 0; r < 4; ++r) {
        int gm = m0 + wm*64 + i*16 + kq*4 + r;
        int gn = n0 + wn*128 + j*16 + ln;
        if (gm < M && gn < N) unsafeAtomicAdd(&C[(long)gm * ldc + gn], acc[i][j][r]);
      }
}

// ---------------- gemv3: EXTRA[v][a] = sum_k {tmpl0,tmpl1,fcb}[k]*redw[a][k]
__global__ __launch_bounds__(256)
void gemv3(const float* __restrict__ redw, const float* __restrict__ tmpl,
           const float* __restrict__ fcb, float* __restrict__ extra)
{
  const int tid = threadIdx.x;
  const int a0 = blockIdx.x * 8;
  const long k0 = (long)blockIdx.y * 8764;
  const long k1 = (k0 + 8764 < (long)VD) ? (k0 + 8764) : (long)VD;
  float s[3][8] = {};
  for (long k = k0 + tid; k < k1; k += 256) {
    const float c0 = tmpl[k], c1 = tmpl[(long)VD + k], cb2 = fcb[k];
#pragma unroll
    for (int r = 0; r < 8; ++r) {
      const float w = redw[(long)(a0 + r) * VD + k];
      s[0][r] += c0 * w; s[1][r] += c1 * w; s[2][r] += cb2 * w;
    }
  }
#pragma unroll
  for (int v = 0; v < 3; ++v)
#pragma unroll
    for (int r = 0; r < 8; ++r) {
      float x = s[v][r];
#pragma unroll
      for (int o = 32; o > 0; o >>= 1) x += __shfl_down(x, o);
      if ((tid & 63) == 0) unsafeAtomicAdd(&extra[v * 768 + a0 + r], x);
    }
}

// GF rows 1024/1025 (template c0term) and 1026 (fbred) = EXTRA + red_b
__global__ void fixup_gf(const float* __restrict__ extra, const float* __restrict__ redb,
                         float* __restrict__ gf)
{
  for (int i = threadIdx.x; i < 3 * 768; i += 256) {
    const int b = i / 768, a = i - b * 768;
    gf[(long)(1024 + b) * 768 + a] = extra[i] + redb[a];
  }
}

// ---------------- generic 128x128 bf16-MFMA GEMM: C = A @ B^T (+bias) -------
template<int EPI>
__global__ __launch_bounds__(256, 2)
void gemm128(const float* __restrict__ A, int lda,
             const float* __restrict__ B, int ldb,
             float* __restrict__ C, long ldc,
             const float* __restrict__ bias,
             int M, int N, int K,
             const float* __restrict__ vert, float* __restrict__ lossp)
{
  __shared__ unsigned short Al[128][40];
  __shared__ unsigned short Bl[128][40];
  const int tid = threadIdx.x;
  const int m0 = blockIdx.x * 128, n0 = blockIdx.y * 128;
  const int wave = tid >> 6, lane = tid & 63;
  const int wm = wave >> 1, wn = wave & 1;
  const int kq = lane >> 4, ln = lane & 15;
  f32x4 acc[4][4] = {};
  for (int kc = 0; kc < K; kc += 32) {
    __syncthreads();
    {
      const int m = tid >> 1, kh = (tid & 1) << 4;
      unsigned short tmp[16] __attribute__((aligned(16)));
      const bool mok = (m0 + m) < M;
      if (mok) {
        const float4* ap4 = (const float4*)(A + (long)(m0 + m) * lda + kc + kh);
#pragma unroll
        for (int i = 0; i < 4; ++i) {
          float4 v = ap4[i];
          tmp[4*i+0] = f2bf(v.x); tmp[4*i+1] = f2bf(v.y);
          tmp[4*i+2] = f2bf(v.z); tmp[4*i+3] = f2bf(v.w);
        }
      } else {
#pragma unroll
        for (int i = 0; i < 16; ++i) tmp[i] = 0;
      }
      ((int4*)&Al[m][kh])[0] = *(int4*)&tmp[0];
      ((int4*)&Al[m][kh])[1] = *(int4*)&tmp[8];
      const int n = m;  // same mapping for B
      unsigned short tmb[16] __attribute__((aligned(16)));
      const bool nok = (n0 + n) < N;
      if (nok) {
        const float4* bp4 = (const float4*)(B + (long)(n0 + n) * ldb + kc + kh);
#pragma unroll
        for (int i = 0; i < 4; ++i) {
          float4 v = bp4[i];
          tmb[4*i+0] = f2bf(v.x); tmb[4*i+1] = f2bf(v.y);
          tmb[4*i+2] = f2bf(v.z); tmb[4*i+3] = f2bf(v.w);
        }
      } else {
#pragma unroll
        for (int i = 0; i < 16; ++i) tmb[i] = 0;
      }
      ((int4*)&Bl[n][kh])[0] = *(int4*)&tmb[0];
      ((int4*)&Bl[n][kh])[1] = *(int4*)&tmb[8];
    }
    __syncthreads();
    bf16x8 af[4], bfv[4];
#pragma unroll
    for (int i = 0; i < 4; ++i) af[i]  = *(const bf16x8*)&Al[wm*64 + i*16 + ln][kq*8];
#pragma unroll
    for (int j = 0; j < 4; ++j) bfv[j] = *(const bf16x8*)&Bl[wn*64 + j*16 + ln][kq*8];
#pragma unroll
    for (int i = 0; i < 4; ++i)
#pragma unroll
      for (int j = 0; j < 4; ++j)
        acc[i][j] = __builtin_amdgcn_mfma_f32_16x16x32_bf16(af[i], bfv[j], acc[i][j], 0, 0, 0);
  }
  float ls = 0.f;
#pragma unroll
  for (int i = 0; i < 4; ++i)
#pragma unroll
    for (int j = 0; j < 4; ++j)
#pragma unroll
      for (int r = 0; r < 4; ++r) {
        const int gm = m0 + wm*64 + i*16 + kq*4 + r;
        const int gn = n0 + wn*64 + j*16 + ln;
        if (gm < M && gn < N) {
          float v = acc[i][j][r];
          if (bias) v += bias[gn];
          C[(long)gm * ldc + gn] = v;
          if (EPI == 2) { float d = v - vert[(long)gm * VD + gn]; ls += d * d; }
        }
      }
  if (EPI == 2) {
#pragma unroll
    for (int o = 32; o > 0; o >>= 1) ls += __shfl_down(ls, o);
    __shared__ float wred[4];
    if ((tid & 63) == 0) wred[wave] = ls;
    __syncthreads();
    if (tid == 0) lossp[blockIdx.y * gridDim.x + blockIdx.x] = wred[0] + wred[1] + wred[2] + wred[3];
  }
}

// ---------------- transpose with optional bias ------------------------------
__global__ void transpose_bias(const float* __restrict__ src, int lds, int row0,
                               float* __restrict__ dst, int ldd,
                               int rows, int cols, const float* __restrict__ bias)
{
  __shared__ float tile[32][33];
  const int rb = blockIdx.x * 32, cb = blockIdx.y * 32;
  const int tx = threadIdx.x & 31, ty = threadIdx.x >> 5;
  for (int yy = ty; yy < 32; yy += 8) {
    int c = cb + yy, r = rb + tx;
    tile[yy][tx] = (c < cols && r < rows) ? src[(long)c * lds + row0 + r] : 0.f;
  }
  __syncthreads();
  for (int yy = ty; yy < 32; yy += 8) {
    int r = rb + yy, c = cb + tx;
    if (r < rows && c < cols)
      dst[(long)r * ldd + c] = tile[tx][yy] + (bias ? bias[c] : 0.f);
  }
}

// ---------------- persistent sequential GRU kernel (32 WGs x 512 thr) -------
// Tagged packed u64 {tag:32|val:32}, relaxed agent-scope atomics, parity
// double-buffered. Dots are computed in per-matrix HALVES (48 dots x 8 lanes)
// so the half that doesn't need a pending h-vector overlaps the poll load.

// One half-matrix of dots: 48 dot-products (24 rows x 2 batches), 8 lanes ea.
#define HALF_DOTS(W, H, MS)                                                   \
  {                                                                           \
    const int g8_ = tid >> 3, l8_ = tid & 7;                                  \
    if (g8_ < 48) {                                                           \
      const int row_ = g8_ >> 1, bb_ = g8_ & 1;                               \
      const float4* w4_ = (const float4*)&(W)[row_][0];                       \
      const float4* h4_ = (const float4*)&(H)[bb_][0];                        \
      float s_ = 0.f;                                                         \
      _Pragma("unroll")                                                       \
      for (int i = 0; i < 8; ++i) {                                           \
        const float4 a_ = w4_[i * 8 + l8_], h_ = h4_[i * 8 + l8_];            \
        s_ += a_.x * h_.x + a_.y * h_.y + a_.z * h_.z + a_.w * h_.w;          \
      }                                                                       \
      s_ += __shfl_xor(s_, 1); s_ += __shfl_xor(s_, 2); s_ += __shfl_xor(s_, 4); \
      if (l8_ == 0) dotsS[MS][bb_][row_ >> 3][row_ & 7] = s_;                 \
    }                                                                         \
  }

// issue the tagged-word load early; finish (spin+fill LDS) late
#define POLL_ISSUE(buf, var)                                                  \
  unsigned long long var = __hip_atomic_load(&(buf)[tid], __ATOMIC_RELAXED, __HIP_MEMORY_SCOPE_AGENT);
#define POLL_FINISH(buf, var, dstLds, want)                                   \
  {                                                                           \
    const unsigned w_ = (unsigned)(want); int sp_ = 0;                        \
    while ((unsigned)(var >> 32) < w_ && ++sp_ < (1 << 15)) {                 \
      __builtin_amdgcn_s_sleep(1);                                            \
      var = __hip_atomic_load(&(buf)[tid], __ATOMIC_RELAXED, __HIP_MEMORY_SCOPE_AGENT); \
    }                                                                         \
    ((float*)dstLds)[tid] = __uint_as_float((unsigned)var);                   \
  }
// combined issue+finish (no overlap available)
#define POLLP(buf, dstLds, want)                                              \
  { POLL_ISSUE(buf, pw_); POLL_FINISH(buf, pw_, dstLds, want); }

__global__ __launch_bounds__(512, 1)
void k3_seq(const float* __restrict__ gihs, const float* __restrict__ Pm,
            const float* __restrict__ M2m,
            const float* __restrict__ whh0, const float* __restrict__ bhh0,
            const float* __restrict__ wih1, const float* __restrict__ bih1,
            const float* __restrict__ whh1, const float* __restrict__ bhh1,
            const int* __restrict__ tfm,
            float* __restrict__ h1s,
            unsigned long long* __restrict__ h0p, unsigned long long* __restrict__ h1p)
{
  __shared__ float wq[24][260], wh0s[24][260], wi1s[24][260], wh1s[24][260];
  __shared__ float h0c[2][256], h1c[2][256];
  __shared__ float dotsS[2][2][3][8];
  __shared__ int tfl[TT];
  const int tid = threadIdx.x;
  const int wg = blockIdx.x;
  const int j0 = wg * 8;           // this WG owns h dims [j0, j0+8)

  { // weight LDS init: both 256-thread halves load alternating rows
    const int col = tid & 255, rh = tid >> 8;
    for (int row = rh; row < 24; row += 2) {
      const int g = row >> 3, jj = row & 7;
      const long gr = g * 256 + j0 + jj;
      wq[row][col]   = M2m[gr * 256 + col];
      wh0s[row][col] = whh0[gr * 256 + col];
      wi1s[row][col] = wih1[gr * 256 + col];
      wh1s[row][col] = whh1[gr * 256 + col];
    }
  }
  ((float*)h0c)[tid] = 0.f;
  ((float*)h1c)[tid] = 0.f;
  if (tid < TT) tfl[tid] = tfm[tid];

  const int cb = tid >> 3, cjj = tid & 7, cj = j0 + cjj;   // combine threads (tid<16)
  float bh0v[3], bi1v[3], bh1v[3], d2v[3];
  if (tid < 16) {
#pragma unroll
    for (int g = 0; g < 3; ++g) {
      bh0v[g] = bhh0[g*256 + cj];
      bi1v[g] = bih1[g*256 + cj];
      bh1v[g] = bhh1[g*256 + cj];
      d2v[g]  = Pm[(long)1026 * 768 + g*256 + cj];
    }
  }
  __syncthreads();

  // one-step-ahead prefetch registers (combine inputs for step t)
  float gihsv[3], piv[3];
  if (tid < 16) {
#pragma unroll
    for (int g = 0; g < 3; ++g) {
      gihsv[g] = gihs[((long)cb * TT) * 768 + g*256 + cj];
      piv[g]   = Pm[(long)(1024 + cb) * 768 + g*256 + cj];
    }
  }
  for (int t = 0; t < TT; ++t) {
    const int tfprev = (t == 0) ? 1 : tfl[t - 1];
    // ---- phase A: gh = h0_{t-1} @ whh0^T (always); q = h1_{t-1} @ M2^T (tf=0)
    if (!tfprev) {
      POLL_ISSUE(h1p + (t & 1) * 512, pb);      // h1_{t-1} in flight...
      HALF_DOTS(wh0s, h0c, 1);                  // ...while computing gh half
      POLL_FINISH(h1p + (t & 1) * 512, pb, h1c, t);
      __syncthreads();
      HALF_DOTS(wq, h1c, 0);                    // q half
    } else {
      HALF_DOTS(wh0s, h0c, 1);                  // q half not needed (discarded)
    }
    __syncthreads();
    if (tid < 16) {
      float gi[3], gh[3];
#pragma unroll
      for (int g = 0; g < 3; ++g) {
        const float q = tfprev ? 0.f : (dotsS[0][cb][g][cjj] + d2v[g]);
        gi[g] = gihsv[g] + (tfprev ? piv[g] : q);
        gh[g] = dotsS[1][cb][g][cjj] + bh0v[g];
      }
      const float rr = 1.f / (1.f + __expf(-(gi[0] + gh[0])));
      const float zz = 1.f / (1.f + __expf(-(gi[1] + gh[1])));
      const float nn = tanhf(gi[2] + rr * gh[2]);
      const float h0n = (1.f - zz) * nn + zz * h0c[cb][cj];
      const unsigned long long pk =
          ((unsigned long long)(unsigned)(t + 1) << 32) | (unsigned long long)__float_as_uint(h0n);
      __hip_atomic_store(&h0p[((t + 1) & 1) * 512 + cb * 256 + cj], pk,
                         __ATOMIC_RELAXED, __HIP_MEMORY_SCOPE_AGENT);
    }
    // prefetch combine inputs for step t+1 (lands under the exchange)
    if (tid < 16 && t + 1 < TT) {
#pragma unroll
      for (int g = 0; g < 3; ++g) {
        gihsv[g] = gihs[((long)cb * TT + (t + 1)) * 768 + g*256 + cj];
        piv[g]   = Pm[((long)cb * TT + t) * 768 + g*256 + cj];
      }
    }
    __syncthreads();             // dots readers of h0c done before overwrite
    POLLP(h0p + ((t + 1) & 1) * 512, h0c, t + 1);  // gather h0_t (exposed RTT)
    __syncthreads();
    // ---- phase B: gi1 = h0_t @ wih1^T ; gh1 = h1_{t-1} @ whh1^T
    if (tfprev) {                // deferred h1 wait, hidden under wi1s half
      POLL_ISSUE(h1p + (t & 1) * 512, qb);
      HALF_DOTS(wi1s, h0c, 0);
      POLL_FINISH(h1p + (t & 1) * 512, qb, h1c, t);
      __syncthreads();
      HALF_DOTS(wh1s, h1c, 1);
    } else {                     // h1c already filled in phase A
      HALF_DOTS(wi1s, h0c, 0);
      HALF_DOTS(wh1s, h1c, 1);
    }
    __syncthreads();
    if (tid < 16) {
      float gi[3], gh[3];
#pragma unroll
      for (int g = 0; g < 3; ++g) {
        gi[g] = dotsS[0][cb][g][cjj] + bi1v[g];
        gh[g] = dotsS[1][cb][g][cjj] + bh1v[g];
      }
      const float rr = 1.f / (1.f + __expf(-(gi[0] + gh[0])));
      const float zz = 1.f / (1.f + __expf(-(gi[1] + gh[1])));
      const float nn = tanhf(gi[2] + rr * gh[2]);
      const float h1n = (1.f - zz) * nn + zz * h1c[cb][cj];
      h1s[((long)cb * TT + t) * 256 + cj] = h1n;   // consumed by a later kernel
      const unsigned long long pk =
          ((unsigned long long)(unsigned)(t + 1) << 32) | (unsigned long long)__float_as_uint(h1n);
      __hip_atomic_store(&h1p[((t + 1) & 1) * 512 + cb * 256 + cj], pk,
                         __ATOMIC_RELAXED, __HIP_MEMORY_SCOPE_AGENT);
    }
    __syncthreads();             // dots readers of h1c done before next fill
  }
}

__global__ void loss_finalize(const float* __restrict__ lossp, int n, float* __restrict__ out) {
  __shared__ float red[256];
  float s = 0.f;
  for (int i = threadIdx.x; i < n; i += 256) s += lossp[i];
  red[threadIdx.x] = s;
  __syncthreads();
  for (int st = 128; st > 0; st >>= 1) {
    if (threadIdx.x < st) red[threadIdx.x] += red[threadIdx.x + st];
    __syncthreads();
  }
  if (threadIdx.x == 0) out[0] = red[0] * (1.0f / 71792640.0f);
}

// ---------------------------------------------------------------------------
extern "C" void kernel_launch(void* const* d_in, const int* in_sizes, int n_in,
                              void* d_out, int out_size, void* d_ws, size_t ws_size,
                              hipStream_t stream) {
  (void)in_sizes; (void)n_in; (void)out_size; (void)ws_size;
  const float* hs   = (const float*)d_in[0];
  const float* tmpl = (const float*)d_in[1];
  const float* vert = (const float*)d_in[2];
  const int*   tfm  = (const int*)  d_in[3];
  const float* wih0 = (const float*)d_in[4];
  const float* whh0 = (const float*)d_in[5];
  const float* bih0 = (const float*)d_in[6];
  const float* bhh0 = (const float*)d_in[7];
  const float* wih1 = (const float*)d_in[8];
  const float* whh1 = (const float*)d_in[9];
  const float* bih1 = (const float*)d_in[10];
  const float* bhh1 = (const float*)d_in[11];
  const float* fcw  = (const float*)d_in[12];
  const float* fcb  = (const float*)d_in[13];
  const float* redw = (const float*)d_in[14];
  const float* redb = (const float*)d_in[15];
  float* out = (float*)d_out;

  char* ws = (char*)d_ws;
  float*    LOSSP = (float*)(ws + 0);          // [4384] overlaps OUTG (dead by then)
  float*    OUTG  = (float*)(ws + 0);          // [768][1024] = G^T (no red_b)
  float*    OUTM  = (float*)(ws + 3145728);    // [768][256]  = M (no bias col)
  float*    EXTRA = (float*)(ws + 3932160);    // [3][768] tmpl0/tmpl1/fcb gemv
  unsigned long long* H0P = (unsigned long long*)(ws + 3941376); // [2][512]
  unsigned long long* H1P = (unsigned long long*)(ws + 3949568); // [2][512]
  float*    GF    = (float*)(ws + 3957760);    // [1027][768]
  float*    MT    = (float*)(ws + 7112704);    // [256][768]  = M^T
  float*    GIHS  = (float*)(ws + 7899136);    // [1024][768]
  float*    PM    = (float*)(ws + 11044864);   // [1027][768]
  float*    M2    = (float*)(ws + 14199808);   // [768][256]
  float*    H1S   = (float*)(ws + 14986240);   // [1024][256]

  // zero split-K accumulators + EXTRA + parity tag buffers (every call)
  hipMemsetAsync(d_ws, 0, 3957760, stream);

  // big V-contractions (split-K, 21 chunks of 3344) — 252/63 blocks, 1 pass
  bigk_kernel<false><<<dim3(4, 3, 21), 512, 0, stream>>>(redw, vert, tmpl, OUTG, 1024, 768, 1024, VD, 3344);
  bigk_kernel<true ><<<dim3(1, 3, 21), 512, 0, stream>>>(redw, fcw,  fcb,  OUTM, 256,  768, 256,  VD, 3344);
  gemv3<<<dim3(96, 8), 256, 0, stream>>>(redw, tmpl, fcb, EXTRA);

  // transposes (+red_b fold) and odd-row fixup
  transpose_bias<<<dim3(32, 24), 256, 0, stream>>>(OUTG, 1024, 0, GF, 768, 1024, 768, redb);
  transpose_bias<<<dim3(8, 24),  256, 0, stream>>>(OUTM, 256,  0, MT, 768, 256,  768, nullptr);
  fixup_gf<<<1, 256, 0, stream>>>(EXTRA, redb, GF);

  // small GEMMs: gihs, P (incl. c0term rows 1024/1025 and d2 row 1026), M2
  gemm128<0><<<dim3(8, 6), 256, 0, stream>>>(hs,        768,  wih0,       1536, GIHS, 768, bih0,    1024, 768, 768, nullptr, nullptr);
  gemm128<0><<<dim3(9, 6), 256, 0, stream>>>(GF,        768,  wih0 + 768, 1536, PM,   768, nullptr, 1027, 768, 768, nullptr, nullptr);
  gemm128<0><<<dim3(6, 2), 256, 0, stream>>>(wih0 + 768, 1536, MT,        768,  M2,   256, nullptr, 768,  256, 768, nullptr, nullptr);

  // sequential recurrence (32 WGs x 512 threads, tf-decoupled tagged sync)
  k3_seq<<<32, 512, 0, stream>>>(GIHS, PM, M2, whh0, bhh0, wih1, bih1, whh1, bhh1,
                                 tfm, H1S, H0P, H1P);

  // final fc GEMM + fused MSE partials, then loss
  gemm128<2><<<dim3(8, 548), 256, 0, stream>>>(H1S, 256, fcw, 256, out, VD, fcb, 1024, VD, 256, vert, LOSSP);
  loss_finalize<<<1, 256, 0, stream>>>(LOSSP, 4384, out + 71792640L);
}

// Round 9
// 3046.598 us; speedup vs baseline: 2.6576x; 1.0591x over previous
//
#include <hip/hip_runtime.h>
#include <hip/hip_bf16.h>

// ---------------------------------------------------------------------------
// FaceXHuBERT decoder: 2-layer GRU (H=256) over T=512 + fc to V=70110 with
// teacher-forcing feedback through red_w [A=768, V].
//
// Restructure so the T-loop never touches V (see round 7 header), then fuse
// the final fc GEMM INTO the recurrence dispatch:
//   blocks 0..31   = producers: the 32-WG tagged-u64 GRU recurrence (r8 code)
//                    + bf16 h1 written to H1SB via sc0sc1 (system) stores
//                    + per-WG progress counter published every 16 steps
//                    (vmcnt(0) then agent atomic -> round-2-proven ordering)
//   blocks 32..255 = consumers: 128x128 K=256 bf16-MFMA fc GEMM tiles + MSE
//                    partials, statically assigned to m-quarters weighted by
//                    availability (12/12/24/64 WGs per quarter per batch),
//                    gated on the progress counters, A-tile read once via
//                    agent-scope u64 atomic loads.
// This uses the 224 CUs that idled during the 1797us recurrence.
// ---------------------------------------------------------------------------

#define TT 512
#define VD 70110
#define NR 1024  // B*T

using bf16x8 = __attribute__((ext_vector_type(8))) short;
using f32x4  = __attribute__((ext_vector_type(4))) float;

static __device__ __forceinline__ unsigned short f2bf(float f) {
  unsigned u = __float_as_uint(f);
  u += 0x7FFFu + ((u >> 16) & 1u);   // RNE
  return (unsigned short)(u >> 16);
}

// ---------------- big split-K GEMM over V (bf16 MFMA, atomicAdd epilogue) ---
template<bool BFORM>
__global__ __launch_bounds__(512, 1)
void bigk_kernel(const float* __restrict__ A, const float* __restrict__ Bv,
                 const float* __restrict__ Bt, float* __restrict__ C, int ldc,
                 int M, int N, int K, int CHK)
{
  __shared__ unsigned short Al[256][40];
  __shared__ unsigned short Bl[256][40];
  const int tid = threadIdx.x;
  const int n0 = blockIdx.x * 256, m0 = blockIdx.y * 256;
  const int kc0 = blockIdx.z * CHK;
  const int kc1 = min(K, kc0 + CHK);
  const int wave = tid >> 6, lane = tid & 63;
  const int wm = wave >> 1, wn = wave & 1;
  const int kq = lane >> 4, ln = lane & 15;
  f32x4 acc[4][8] = {};
  for (int kc = kc0; kc < kc1; kc += 32) {
    __syncthreads();
    { // stage A: 256 rows x 32 k
      const int m = tid >> 1, kh = (tid & 1) << 4;
      const bool mok = (m0 + m) < M;
      const float* arow = A + (long)(m0 + m) * (long)K;
      unsigned short tmp[16] __attribute__((aligned(16)));
      if (mok && (kc + 32 <= kc1)) {
        const float2* ap2 = (const float2*)(arow + kc + kh);
#pragma unroll
        for (int i = 0; i < 8; ++i) { float2 v = ap2[i]; tmp[2*i] = f2bf(v.x); tmp[2*i+1] = f2bf(v.y); }
      } else {
#pragma unroll
        for (int i = 0; i < 16; ++i) {
          int kk = kc + kh + i;
          tmp[i] = f2bf((mok && kk < kc1) ? arow[kk] : 0.f);
        }
      }
      ((int4*)&Al[m][kh])[0] = *(int4*)&tmp[0];
      ((int4*)&Al[m][kh])[1] = *(int4*)&tmp[8];
    }
    if (!BFORM) { // stage B from row-major rows (vert)
      const int n = tid >> 1, kh = (tid & 1) << 4;
      const int gn = n0 + n;
      const float* bp = nullptr;
      if (gn < 1024) bp = Bv + (long)gn * (long)VD;
      else if (gn < N) bp = Bt + (long)(gn - 1024) * (long)VD;
      unsigned short tmp[16] __attribute__((aligned(16)));
      if (bp && (kc + 32 <= kc1)) {
        const float2* bp2 = (const float2*)(bp + kc + kh);
#pragma unroll
        for (int i = 0; i < 8; ++i) { float2 v = bp2[i]; tmp[2*i] = f2bf(v.x); tmp[2*i+1] = f2bf(v.y); }
      } else {
#pragma unroll
        for (int i = 0; i < 16; ++i) {
          int kk = kc + kh + i;
          tmp[i] = f2bf((bp && kk < kc1) ? bp[kk] : 0.f);
        }
      }
      ((int4*)&Bl[n][kh])[0] = *(int4*)&tmp[0];
      ((int4*)&Bl[n][kh])[1] = *(int4*)&tmp[8];
    } else {      // stage B from k-major fc_w (transpose into LDS, coalesced n)
      const int n = tid & 255, kh = (tid >> 8) << 4;
      const int gn = n0 + n;
      unsigned short tmp[16] __attribute__((aligned(16)));
#pragma unroll
      for (int i = 0; i < 16; ++i) {
        int kk = kc + kh + i;
        float v = 0.f;
        if (kk < kc1 && gn < 256) v = Bv[(long)kk * 256 + gn];
        tmp[i] = f2bf(v);
      }
      ((int4*)&Bl[n][kh])[0] = *(int4*)&tmp[0];
      ((int4*)&Bl[n][kh])[1] = *(int4*)&tmp[8];
    }
    __syncthreads();
    bf16x8 af[4], bfv[8];
#pragma unroll
    for (int i = 0; i < 4; ++i) af[i] = *(const bf16x8*)&Al[wm*64 + i*16 + ln][kq*8];
#pragma unroll
    for (int j = 0; j < 8; ++j) bfv[j] = *(const bf16x8*)&Bl[wn*128 + j*16 + ln][kq*8];
#pragma unroll
    for (int i = 0; i < 4; ++i)
#pragma unroll
      for (int j = 0; j < 8; ++j)
        acc[i][j] = __builtin_amdgcn_mfma_f32_16x16x32_bf16(af[i], bfv[j], acc[i][j], 0, 0, 0);
  }
#pragma unroll
  for (int i = 0; i < 4; ++i)
#pragma unroll
    for (int j = 0; j < 8; ++j)
#pragma unroll
      for (int r = 0; r < 4; ++r) {
        int gm = m0 + wm*64 + i*16 + kq*4 + r;
        int gn = n0 + wn*128 + j*16 + ln;
        if (gm < M && gn < N) unsafeAtomicAdd(&C[(long)gm * ldc + gn], acc[i][j][r]);
      }
}

// ---------------- gemv3: EXTRA[v][a] = sum_k {tmpl0,tmpl1,fcb}[k]*redw[a][k]
__global__ __launch_bounds__(256)
void gemv3(const float* __restrict__ redw, const float* __restrict__ tmpl,
           const float* __restrict__ fcb, float* __restrict__ extra)
{
  const int tid = threadIdx.x;
  const int a0 = blockIdx.x * 8;
  const long k0 = (long)blockIdx.y * 8764;
  const long k1 = (k0 + 8764 < (long)VD) ? (k0 + 8764) : (long)VD;
  float s[3][8] = {};
  for (long k = k0 + tid; k < k1; k += 256) {
    const float c0 = tmpl[k], c1 = tmpl[(long)VD + k], cb2 = fcb[k];
#pragma unroll
    for (int r = 0; r < 8; ++r) {
      const float w = redw[(long)(a0 + r) * VD + k];
      s[0][r] += c0 * w; s[1][r] += c1 * w; s[2][r] += cb2 * w;
    }
  }
#pragma unroll
  for (int v = 0; v < 3; ++v)
#pragma unroll
    for (int r = 0; r < 8; ++r) {
      float x = s[v][r];
#pragma unroll
      for (int o = 32; o > 0; o >>= 1) x += __shfl_down(x, o);
      if ((tid & 63) == 0) unsafeAtomicAdd(&extra[v * 768 + a0 + r], x);
    }
}

// GF rows 1024/1025 (template c0term) and 1026 (fbred) = EXTRA + red_b
__global__ void fixup_gf(const float* __restrict__ extra, const float* __restrict__ redb,
                         float* __restrict__ gf)
{
  for (int i = threadIdx.x; i < 3 * 768; i += 256) {
    const int b = i / 768, a = i - b * 768;
    gf[(long)(1024 + b) * 768 + a] = extra[i] + redb[a];
  }
}

// ---------------- generic 128x128 bf16-MFMA GEMM: C = A @ B^T (+bias) -------
__global__ __launch_bounds__(256, 2)
void gemm128(const float* __restrict__ A, int lda,
             const float* __restrict__ B, int ldb,
             float* __restrict__ C, long ldc,
             const float* __restrict__ bias,
             int M, int N, int K)
{
  __shared__ unsigned short Al[128][40];
  __shared__ unsigned short Bl[128][40];
  const int tid = threadIdx.x;
  const int m0 = blockIdx.x * 128, n0 = blockIdx.y * 128;
  const int wave = tid >> 6, lane = tid & 63;
  const int wm = wave >> 1, wn = wave & 1;
  const int kq = lane >> 4, ln = lane & 15;
  f32x4 acc[4][4] = {};
  for (int kc = 0; kc < K; kc += 32) {
    __syncthreads();
    {
      const int m = tid >> 1, kh = (tid & 1) << 4;
      unsigned short tmp[16] __attribute__((aligned(16)));
      const bool mok = (m0 + m) < M;
      if (mok) {
        const float4* ap4 = (const float4*)(A + (long)(m0 + m) * lda + kc + kh);
#pragma unroll
        for (int i = 0; i < 4; ++i) {
          float4 v = ap4[i];
          tmp[4*i+0] = f2bf(v.x); tmp[4*i+1] = f2bf(v.y);
          tmp[4*i+2] = f2bf(v.z); tmp[4*i+3] = f2bf(v.w);
        }
      } else {
#pragma unroll
        for (int i = 0; i < 16; ++i) tmp[i] = 0;
      }
      ((int4*)&Al[m][kh])[0] = *(int4*)&tmp[0];
      ((int4*)&Al[m][kh])[1] = *(int4*)&tmp[8];
      const int n = m;
      unsigned short tmb[16] __attribute__((aligned(16)));
      const bool nok = (n0 + n) < N;
      if (nok) {
        const float4* bp4 = (const float4*)(B + (long)(n0 + n) * ldb + kc + kh);
#pragma unroll
        for (int i = 0; i < 4; ++i) {
          float4 v = bp4[i];
          tmb[4*i+0] = f2bf(v.x); tmb[4*i+1] = f2bf(v.y);
          tmb[4*i+2] = f2bf(v.z); tmb[4*i+3] = f2bf(v.w);
        }
      } else {
#pragma unroll
        for (int i = 0; i < 16; ++i) tmb[i] = 0;
      }
      ((int4*)&Bl[n][kh])[0] = *(int4*)&tmb[0];
      ((int4*)&Bl[n][kh])[1] = *(int4*)&tmb[8];
    }
    __syncthreads();
    bf16x8 af[4], bfv[4];
#pragma unroll
    for (int i = 0; i < 4; ++i) af[i]  = *(const bf16x8*)&Al[wm*64 + i*16 + ln][kq*8];
#pragma unroll
    for (int j = 0; j < 4; ++j) bfv[j] = *(const bf16x8*)&Bl[wn*64 + j*16 + ln][kq*8];
#pragma unroll
    for (int i = 0; i < 4; ++i)
#pragma unroll
      for (int j = 0; j < 4; ++j)
        acc[i][j] = __builtin_amdgcn_mfma_f32_16x16x32_bf16(af[i], bfv[j], acc[i][j], 0, 0, 0);
  }
#pragma unroll
  for (int i = 0; i < 4; ++i)
#pragma unroll
    for (int j = 0; j < 4; ++j)
#pragma unroll
      for (int r = 0; r < 4; ++r) {
        const int gm = m0 + wm*64 + i*16 + kq*4 + r;
        const int gn = n0 + wn*64 + j*16 + ln;
        if (gm < M && gn < N) {
          float v = acc[i][j][r];
          if (bias) v += bias[gn];
          C[(long)gm * ldc + gn] = v;
        }
      }
}

// ---------------- transpose with optional bias ------------------------------
__global__ void transpose_bias(const float* __restrict__ src, int lds, int row0,
                               float* __restrict__ dst, int ldd,
                               int rows, int cols, const float* __restrict__ bias)
{
  __shared__ float tile[32][33];
  const int rb = blockIdx.x * 32, cb = blockIdx.y * 32;
  const int tx = threadIdx.x & 31, ty = threadIdx.x >> 5;
  for (int yy = ty; yy < 32; yy += 8) {
    int c = cb + yy, r = rb + tx;
    tile[yy][tx] = (c < cols && r < rows) ? src[(long)c * lds + row0 + r] : 0.f;
  }
  __syncthreads();
  for (int yy = ty; yy < 32; yy += 8) {
    int r = rb + yy, c = cb + tx;
    if (r < rows && c < cols)
      dst[(long)r * ldd + c] = tile[tx][yy] + (bias ? bias[c] : 0.f);
  }
}

// ---------------- fused recurrence + fc GEMM --------------------------------
struct ProdLds {
  float wq[24][260], wh0s[24][260], wi1s[24][260], wh1s[24][260];
  float h0c[2][256], h1c[2][256];
  float dotsS[2][2][3][8];
  int tfl[TT];
};
struct ConsLds {
  unsigned short As[128][264];   // full A tile (bf16 h1), K=256 (+8 pad)
  unsigned short Bl[128][40];    // staged B (fcw), 32 k per stage
  float wred[8];
};

#define HALF_DOTS(W, H, MS)                                                   \
  {                                                                           \
    const int g8_ = tid >> 3, l8_ = tid & 7;                                  \
    if (g8_ < 48) {                                                           \
      const int row_ = g8_ >> 1, bb_ = g8_ & 1;                               \
      const float4* w4_ = (const float4*)&(W)[row_][0];                       \
      const float4* h4_ = (const float4*)&(H)[bb_][0];                        \
      float s_ = 0.f;                                                         \
      _Pragma("unroll")                                                       \
      for (int i = 0; i < 8; ++i) {                                           \
        const float4 a_ = w4_[i * 8 + l8_], h_ = h4_[i * 8 + l8_];            \
        s_ += a_.x * h_.x + a_.y * h_.y + a_.z * h_.z + a_.w * h_.w;          \
      }                                                                       \
      s_ += __shfl_xor(s_, 1); s_ += __shfl_xor(s_, 2); s_ += __shfl_xor(s_, 4); \
      if (l8_ == 0) dotsS[MS][bb_][row_ >> 3][row_ & 7] = s_;                 \
    }                                                                         \
  }

#define POLL_ISSUE(buf, var)                                                  \
  unsigned long long var = __hip_atomic_load(&(buf)[tid], __ATOMIC_RELAXED, __HIP_MEMORY_SCOPE_AGENT);
#define POLL_FINISH(buf, var, dstLds, want)                                   \
  {                                                                           \
    const unsigned w_ = (unsigned)(want); int sp_ = 0;                        \
    while ((unsigned)(var >> 32) < w_ && ++sp_ < (1 << 15)) {                 \
      __builtin_amdgcn_s_sleep(1);                                            \
      var = __hip_atomic_load(&(buf)[tid], __ATOMIC_RELAXED, __HIP_MEMORY_SCOPE_AGENT); \
    }                                                                         \
    ((float*)dstLds)[tid] = __uint_as_float((unsigned)var);                   \
  }
#define POLLP(buf, dstLds, want)                                              \
  { POLL_ISSUE(buf, pw_); POLL_FINISH(buf, pw_, dstLds, want); }

__global__ __launch_bounds__(512, 1)
void k3_fused(const float* __restrict__ gihs, const float* __restrict__ Pm,
              const float* __restrict__ M2m,
              const float* __restrict__ whh0, const float* __restrict__ bhh0,
              const float* __restrict__ wih1, const float* __restrict__ bih1,
              const float* __restrict__ whh1, const float* __restrict__ bhh1,
              const int* __restrict__ tfm,
              unsigned short* __restrict__ h1sb,
              unsigned long long* __restrict__ h0p, unsigned long long* __restrict__ h1p,
              unsigned* __restrict__ prog,
              const float* __restrict__ fcw, const float* __restrict__ fcb,
              const float* __restrict__ vert,
              float* __restrict__ out, float* __restrict__ lossp)
{
  __shared__ union { ProdLds p; ConsLds c; } U;
  const int tid = threadIdx.x;

  if (blockIdx.x >= 32) {
    // ================= CONSUMER: fc GEMM tile sweep ========================
    auto& C = U.c;
    const int idx = blockIdx.x - 32;        // 0..223
    int tx, memb, cnt;
    if (idx < 24)      { tx = 0; memb = (idx)      >> 1; cnt = 12; }
    else if (idx < 48) { tx = 1; memb = (idx - 24) >> 1; cnt = 12; }
    else if (idx < 96) { tx = 2; memb = (idx - 48) >> 1; cnt = 24; }
    else               { tx = 3; memb = (idx - 96) >> 1; cnt = 64; }
    const int b = idx & 1;
    const int nt0 = memb * 548 / cnt, nt1 = (memb + 1) * 548 / cnt;
    if (nt0 >= nt1) return;
    const unsigned want = (unsigned)((tx + 1) * 128);
    // wait for all 32 producers to pass step want (heavy backoff poll)
    if (tid < 32) {
      int sp = 0;
      while (__hip_atomic_load(&prog[tid * 16], __ATOMIC_RELAXED, __HIP_MEMORY_SCOPE_AGENT) < want) {
        if (++sp > (1 << 14)) break;
        for (int j = 0; j < 16; ++j) __builtin_amdgcn_s_sleep(15);
      }
    }
    __syncthreads();
    // load A tile (bf16 h1, 128 rows x 256 k) via agent-scope u64 atomics
    const long rbase = (long)b * 512 + (long)tx * 128;
    {
      const unsigned long long* src = (const unsigned long long*)(h1sb + rbase * 256);
#pragma unroll
      for (int i = 0; i < 16; ++i) {
        const int u = tid * 16 + i;          // 0..8191 ; 64 u64 per row
        unsigned long long v = __hip_atomic_load(&src[u], __ATOMIC_RELAXED, __HIP_MEMORY_SCOPE_AGENT);
        const int row = u >> 6, c4 = u & 63;
        *(unsigned long long*)&C.As[row][c4 * 4] = v;
      }
    }
    __syncthreads();
    const int wave = tid >> 6, lane = tid & 63;
    const int wm = wave >> 2, wn = wave & 3;     // 2 x 4 wave grid
    const int kq = lane >> 4, ln = lane & 15;
    for (int nt = nt0; nt < nt1; ++nt) {
      const int n0 = nt * 128;
      f32x4 acc[4][2] = {};
#pragma unroll 1
      for (int ks = 0; ks < 8; ++ks) {
        __syncthreads();
        { // stage B: fcw rows n0..n0+127, k = ks*32..+31
          const int rn = tid >> 2, kh = (tid & 3) * 8;
          const int gn = n0 + rn;
          unsigned short tmb[8] __attribute__((aligned(16)));
          if (gn < VD) {
            const float4* bp = (const float4*)&fcw[(long)gn * 256 + ks * 32 + kh];
            float4 v0 = bp[0], v1 = bp[1];
            tmb[0] = f2bf(v0.x); tmb[1] = f2bf(v0.y); tmb[2] = f2bf(v0.z); tmb[3] = f2bf(v0.w);
            tmb[4] = f2bf(v1.x); tmb[5] = f2bf(v1.y); tmb[6] = f2bf(v1.z); tmb[7] = f2bf(v1.w);
          } else {
#pragma unroll
            for (int i = 0; i < 8; ++i) tmb[i] = 0;
          }
          *(int4*)&C.Bl[rn][kh] = *(int4*)tmb;
        }
        __syncthreads();
        bf16x8 af[4], bfv[2];
#pragma unroll
        for (int i = 0; i < 4; ++i)
          af[i] = *(const bf16x8*)&C.As[wm*64 + i*16 + ln][ks*32 + kq*8];
#pragma unroll
        for (int j = 0; j < 2; ++j)
          bfv[j] = *(const bf16x8*)&C.Bl[wn*32 + j*16 + ln][kq*8];
#pragma unroll
        for (int i = 0; i < 4; ++i)
#pragma unroll
          for (int j = 0; j < 2; ++j)
            acc[i][j] = __builtin_amdgcn_mfma_f32_16x16x32_bf16(af[i], bfv[j], acc[i][j], 0, 0, 0);
      }
      float ls = 0.f;
#pragma unroll
      for (int i = 0; i < 4; ++i)
#pragma unroll
        for (int j = 0; j < 2; ++j)
#pragma unroll
          for (int r = 0; r < 4; ++r) {
            const int gmL = wm*64 + i*16 + kq*4 + r;
            const int gn = n0 + wn*32 + j*16 + ln;
            if (gn < VD) {
              const float v = acc[i][j][r] + fcb[gn];
              const long grow = rbase + gmL;
              out[grow * VD + gn] = v;
              const float dd = v - vert[grow * VD + gn];
              ls += dd * dd;
            }
          }
#pragma unroll
      for (int o = 32; o > 0; o >>= 1) ls += __shfl_down(ls, o);
      if (lane == 0) C.wred[wave] = ls;
      __syncthreads();
      if (tid == 0) {
        float s = 0.f;
#pragma unroll
        for (int w = 0; w < 8; ++w) s += C.wred[w];
        lossp[(tx * 2 + b) * 548 + nt] = s;
      }
      __syncthreads();
    }
    return;
  }

  // ================= PRODUCER: 32-WG tagged-u64 GRU recurrence =============
  float (&wq)[24][260]   = U.p.wq;
  float (&wh0s)[24][260] = U.p.wh0s;
  float (&wi1s)[24][260] = U.p.wi1s;
  float (&wh1s)[24][260] = U.p.wh1s;
  float (&h0c)[2][256]   = U.p.h0c;
  float (&h1c)[2][256]   = U.p.h1c;
  float (&dotsS)[2][2][3][8] = U.p.dotsS;
  int   (&tfl)[TT]       = U.p.tfl;
  const int wg = blockIdx.x;
  const int j0 = wg * 8;           // this WG owns h dims [j0, j0+8)

  { // weight LDS init: both 256-thread halves load alternating rows
    const int col = tid & 255, rh = tid >> 8;
    for (int row = rh; row < 24; row += 2) {
      const int g = row >> 3, jj = row & 7;
      const long gr = g * 256 + j0 + jj;
      wq[row][col]   = M2m[gr * 256 + col];
      wh0s[row][col] = whh0[gr * 256 + col];
      wi1s[row][col] = wih1[gr * 256 + col];
      wh1s[row][col] = whh1[gr * 256 + col];
    }
  }
  ((float*)h0c)[tid] = 0.f;
  ((float*)h1c)[tid] = 0.f;
  if (tid < TT) tfl[tid] = tfm[tid];

  const int cb = tid >> 3, cjj = tid & 7, cj = j0 + cjj;   // combine threads (tid<16)
  float bh0v[3], bi1v[3], bh1v[3], d2v[3];
  if (tid < 16) {
#pragma unroll
    for (int g = 0; g < 3; ++g) {
      bh0v[g] = bhh0[g*256 + cj];
      bi1v[g] = bih1[g*256 + cj];
      bh1v[g] = bhh1[g*256 + cj];
      d2v[g]  = Pm[(long)1026 * 768 + g*256 + cj];
    }
  }
  __syncthreads();

  const int wave = tid >> 6;
  float gihsv[3], piv[3];
  if (tid < 16) {
#pragma unroll
    for (int g = 0; g < 3; ++g) {
      gihsv[g] = gihs[((long)cb * TT) * 768 + g*256 + cj];
      piv[g]   = Pm[(long)(1024 + cb) * 768 + g*256 + cj];
    }
  }
  for (int t = 0; t < TT; ++t) {
    const int tfprev = (t == 0) ? 1 : tfl[t - 1];
    // ---- phase A
    if (!tfprev) {
      POLL_ISSUE(h1p + (t & 1) * 512, pb);
      HALF_DOTS(wh0s, h0c, 1);
      POLL_FINISH(h1p + (t & 1) * 512, pb, h1c, t);
      __syncthreads();
      HALF_DOTS(wq, h1c, 0);
    } else {
      HALF_DOTS(wh0s, h0c, 1);
    }
    __syncthreads();
    if (tid < 16) {
      float gi[3], gh[3];
#pragma unroll
      for (int g = 0; g < 3; ++g) {
        const float q = tfprev ? 0.f : (dotsS[0][cb][g][cjj] + d2v[g]);
        gi[g] = gihsv[g] + (tfprev ? piv[g] : q);
        gh[g] = dotsS[1][cb][g][cjj] + bh0v[g];
      }
      const float rr = 1.f / (1.f + __expf(-(gi[0] + gh[0])));
      const float zz = 1.f / (1.f + __expf(-(gi[1] + gh[1])));
      const float nn = tanhf(gi[2] + rr * gh[2]);
      const float h0n = (1.f - zz) * nn + zz * h0c[cb][cj];
      const unsigned long long pk =
          ((unsigned long long)(unsigned)(t + 1) << 32) | (unsigned long long)__float_as_uint(h0n);
      __hip_atomic_store(&h0p[((t + 1) & 1) * 512 + cb * 256 + cj], pk,
                         __ATOMIC_RELAXED, __HIP_MEMORY_SCOPE_AGENT);
    }
    if (tid < 16 && t + 1 < TT) {
#pragma unroll
      for (int g = 0; g < 3; ++g) {
        gihsv[g] = gihs[((long)cb * TT + (t + 1)) * 768 + g*256 + cj];
        piv[g]   = Pm[((long)cb * TT + t) * 768 + g*256 + cj];
      }
    }
    __syncthreads();
    POLLP(h0p + ((t + 1) & 1) * 512, h0c, t + 1);
    __syncthreads();
    // ---- phase B
    if (tfprev) {
      POLL_ISSUE(h1p + (t & 1) * 512, qb);
      HALF_DOTS(wi1s, h0c, 0);
      POLL_FINISH(h1p + (t & 1) * 512, qb, h1c, t);
      __syncthreads();
      HALF_DOTS(wh1s, h1c, 1);
    } else {
      HALF_DOTS(wi1s, h0c, 0);
      HALF_DOTS(wh1s, h1c, 1);
    }
    __syncthreads();
    if (tid < 16) {
      float gi[3], gh[3];
#pragma unroll
      for (int g = 0; g < 3; ++g) {
        gi[g] = dotsS[0][cb][g][cjj] + bi1v[g];
        gh[g] = dotsS[1][cb][g][cjj] + bh1v[g];
      }
      const float rr = 1.f / (1.f + __expf(-(gi[0] + gh[0])));
      const float zz = 1.f / (1.f + __expf(-(gi[1] + gh[1])));
      const float nn = tanhf(gi[2] + rr * gh[2]);
      const float h1n = (1.f - zz) * nn + zz * h1c[cb][cj];
      // bf16 h1 to system-visible buffer (consumed in-kernel by consumers)
      const unsigned hb = (unsigned)f2bf(h1n);
      asm volatile("global_store_short %0, %1, off sc0 sc1"
                   :: "v"(&h1sb[((long)cb * TT + t) * 256 + cj]), "v"(hb) : "memory");
      const unsigned long long pk =
          ((unsigned long long)(unsigned)(t + 1) << 32) | (unsigned long long)__float_as_uint(h1n);
      __hip_atomic_store(&h1p[((t + 1) & 1) * 512 + cb * 256 + cj], pk,
                         __ATOMIC_RELAXED, __HIP_MEMORY_SCOPE_AGENT);
    }
    if ((t & 15) == 15) {  // lazy progress publish (data-before-flag via vmcnt)
      if (wave == 0) asm volatile("s_waitcnt vmcnt(0)" ::: "memory");
      if (tid == 0)
        __hip_atomic_store(&prog[wg * 16], (unsigned)(t + 1),
                           __ATOMIC_RELAXED, __HIP_MEMORY_SCOPE_AGENT);
    }
    __syncthreads();
  }
}

__global__ void loss_finalize(const float* __restrict__ lossp, int n, float* __restrict__ out) {
  __shared__ float red[256];
  float s = 0.f;
  for (int i = threadIdx.x; i < n; i += 256) s += lossp[i];
  red[threadIdx.x] = s;
  __syncthreads();
  for (int st = 128; st > 0; st >>= 1) {
    if (threadIdx.x < st) red[threadIdx.x] += red[threadIdx.x + st];
    __syncthreads();
  }
  if (threadIdx.x == 0) out[0] = red[0] * (1.0f / 71792640.0f);
}

// ---------------------------------------------------------------------------
extern "C" void kernel_launch(void* const* d_in, const int* in_sizes, int n_in,
                              void* d_out, int out_size, void* d_ws, size_t ws_size,
                              hipStream_t stream) {
  (void)in_sizes; (void)n_in; (void)out_size; (void)ws_size;
  const float* hs   = (const float*)d_in[0];
  const float* tmpl = (const float*)d_in[1];
  const float* vert = (const float*)d_in[2];
  const int*   tfm  = (const int*)  d_in[3];
  const float* wih0 = (const float*)d_in[4];
  const float* whh0 = (const float*)d_in[5];
  const float* bih0 = (const float*)d_in[6];
  const float* bhh0 = (const float*)d_in[7];
  const float* wih1 = (const float*)d_in[8];
  const float* whh1 = (const float*)d_in[9];
  const float* bih1 = (const float*)d_in[10];
  const float* bhh1 = (const float*)d_in[11];
  const float* fcw  = (const float*)d_in[12];
  const float* fcb  = (const float*)d_in[13];
  const float* redw = (const float*)d_in[14];
  const float* redb = (const float*)d_in[15];
  float* out = (float*)d_out;

  char* ws = (char*)d_ws;
  float*    LOSSP = (float*)(ws + 0);          // overlaps OUTG (dead after transpose)
  float*    OUTG  = (float*)(ws + 0);          // [768][1024]
  float*    OUTM  = (float*)(ws + 3145728);    // [768][256]
  float*    EXTRA = (float*)(ws + 3932160);    // [3][768]
  unsigned long long* H0P = (unsigned long long*)(ws + 3941376); // [2][512]
  unsigned long long* H1P = (unsigned long long*)(ws + 3949568); // [2][512]
  unsigned* PROG  = (unsigned*)(ws + 3957760); // 32 slots x 16 stride
  float*    GF    = (float*)(ws + 3960064);    // [1027][768]
  float*    MT    = (float*)(ws + 7115776);    // [256][768]
  float*    GIHS  = (float*)(ws + 7902208);    // [1024][768]
  float*    PM    = (float*)(ws + 11047936);   // [1027][768]
  float*    M2    = (float*)(ws + 14203648);   // [768][256]
  unsigned short* H1SB = (unsigned short*)(ws + 14990080); // [1024][256] bf16

  // zero split-K accumulators + EXTRA + tag buffers + progress (every call)
  hipMemsetAsync(d_ws, 0, 3960064, stream);

  // big V-contractions (split-K, 21 chunks of 3344)
  bigk_kernel<false><<<dim3(4, 3, 21), 512, 0, stream>>>(redw, vert, tmpl, OUTG, 1024, 768, 1024, VD, 3344);
  bigk_kernel<true ><<<dim3(1, 3, 21), 512, 0, stream>>>(redw, fcw,  fcb,  OUTM, 256,  768, 256,  VD, 3344);
  gemv3<<<dim3(96, 8), 256, 0, stream>>>(redw, tmpl, fcb, EXTRA);

  // transposes (+red_b fold) and odd-row fixup
  transpose_bias<<<dim3(32, 24), 256, 0, stream>>>(OUTG, 1024, 0, GF, 768, 1024, 768, redb);
  transpose_bias<<<dim3(8, 24),  256, 0, stream>>>(OUTM, 256,  0, MT, 768, 256,  768, nullptr);
  fixup_gf<<<1, 256, 0, stream>>>(EXTRA, redb, GF);

  // small GEMMs: gihs, P (incl. c0term rows 1024/1025 and d2 row 1026), M2
  gemm128<<<dim3(8, 6), 256, 0, stream>>>(hs,        768,  wih0,       1536, GIHS, 768, bih0,    1024, 768, 768);
  gemm128<<<dim3(9, 6), 256, 0, stream>>>(GF,        768,  wih0 + 768, 1536, PM,   768, nullptr, 1027, 768, 768);
  gemm128<<<dim3(6, 2), 256, 0, stream>>>(wih0 + 768, 1536, MT,        768,  M2,   256, nullptr, 768,  256, 768);

  // fused recurrence (32 producer WGs) + fc GEMM/MSE (224 consumer WGs)
  k3_fused<<<256, 512, 0, stream>>>(GIHS, PM, M2, whh0, bhh0, wih1, bih1, whh1, bhh1,
                                    tfm, H1SB, H0P, H1P, PROG,
                                    fcw, fcb, vert, out, LOSSP);

  loss_finalize<<<1, 256, 0, stream>>>(LOSSP, 4384, out + 71792640L);
}

// Round 10
// 2890.680 us; speedup vs baseline: 2.8010x; 1.0539x over previous
//
#include <hip/hip_runtime.h>
#include <hip/hip_bf16.h>

// ---------------------------------------------------------------------------
// FaceXHuBERT decoder: 2-layer GRU (H=256) over T=512 + fc to V=70110 with
// teacher-forcing feedback through red_w [A=768, V].
//
// Pipeline (see round 7/9 headers for the algebra):
//   bigk_merged: OUT_G = red_w@vert^T and OUT_M = red_w@fc_w in ONE launch
//   gemv3:       EXTRA = red_w @ [tmpl0|tmpl1|fc_b]
//   transpose_merged: GF/MT transposes + GF odd-row fixup in ONE launch
//   gemm128x3:   GIHS / PM / M2 small GEMMs in ONE launch
//   k3_fused:    32 producer WGs (tagged-u64 GRU recurrence) + 224 consumer
//                WGs (fc GEMM + MSE partials, progress-gated)
//   loss_finalize
//
// Round 10: (a) producer phase B reordered — h0 exchange load issued first,
// wh1s-half (independent of h0_t) computed while it is in flight, h0 finish,
// then wi1s-half: the last naked IC RTT per step is now overlapped.
// (b) prologue launch-tail collapse: bigk pair merged (252+63 blocks, one
// grid), 3 small GEMMs merged, transposes+fixup merged -> 6 launches total.
// ---------------------------------------------------------------------------

#define TT 512
#define VD 70110
#define NR 1024  // B*T

using bf16x8 = __attribute__((ext_vector_type(8))) short;
using f32x4  = __attribute__((ext_vector_type(4))) float;

static __device__ __forceinline__ unsigned short f2bf(float f) {
  unsigned u = __float_as_uint(f);
  u += 0x7FFFu + ((u >> 16) & 1u);   // RNE
  return (unsigned short)(u >> 16);
}

// ---------------- merged big split-K GEMM over V (bf16 MFMA, atomicAdd) -----
// blockIdx.x<4: OUTG problem (B = vert rows, N=1024, col block = x)
// blockIdx.x==4: OUTM problem (B = fc_w k-major, N=256)
__global__ __launch_bounds__(512, 1)
void bigk_merged(const float* __restrict__ A, const float* __restrict__ vert,
                 const float* __restrict__ fcw,
                 float* __restrict__ OUTG, float* __restrict__ OUTM, int CHK)
{
  __shared__ unsigned short Al[256][40];
  __shared__ unsigned short Bl[256][40];
  const int tid = threadIdx.x;
  const bool bform = (blockIdx.x == 4);
  float* C      = bform ? OUTM : OUTG;
  const int ldc = bform ? 256 : 1024;
  const int N   = bform ? 256 : 1024;
  const int n0  = bform ? 0 : blockIdx.x * 256;
  const int m0  = blockIdx.y * 256;          // M = 768
  const int kc0 = blockIdx.z * CHK;
  const int kc1 = min(VD, kc0 + CHK);
  const int wave = tid >> 6, lane = tid & 63;
  const int wm = wave >> 1, wn = wave & 1;
  const int kq = lane >> 4, ln = lane & 15;
  f32x4 acc[4][8] = {};
  for (int kc = kc0; kc < kc1; kc += 32) {
    __syncthreads();
    { // stage A: 256 rows x 32 k (red_w rows)
      const int m = tid >> 1, kh = (tid & 1) << 4;
      const float* arow = A + (long)(m0 + m) * (long)VD;
      unsigned short tmp[16] __attribute__((aligned(16)));
      if (kc + 32 <= kc1) {
        const float2* ap2 = (const float2*)(arow + kc + kh);
#pragma unroll
        for (int i = 0; i < 8; ++i) { float2 v = ap2[i]; tmp[2*i] = f2bf(v.x); tmp[2*i+1] = f2bf(v.y); }
      } else {
#pragma unroll
        for (int i = 0; i < 16; ++i) {
          int kk = kc + kh + i;
          tmp[i] = f2bf((kk < kc1) ? arow[kk] : 0.f);
        }
      }
      ((int4*)&Al[m][kh])[0] = *(int4*)&tmp[0];
      ((int4*)&Al[m][kh])[1] = *(int4*)&tmp[8];
    }
    if (!bform) { // stage B from row-major vert rows
      const int n = tid >> 1, kh = (tid & 1) << 4;
      const float* bp = vert + (long)(n0 + n) * (long)VD;
      unsigned short tmp[16] __attribute__((aligned(16)));
      if (kc + 32 <= kc1) {
        const float2* bp2 = (const float2*)(bp + kc + kh);
#pragma unroll
        for (int i = 0; i < 8; ++i) { float2 v = bp2[i]; tmp[2*i] = f2bf(v.x); tmp[2*i+1] = f2bf(v.y); }
      } else {
#pragma unroll
        for (int i = 0; i < 16; ++i) {
          int kk = kc + kh + i;
          tmp[i] = f2bf((kk < kc1) ? bp[kk] : 0.f);
        }
      }
      ((int4*)&Bl[n][kh])[0] = *(int4*)&tmp[0];
      ((int4*)&Bl[n][kh])[1] = *(int4*)&tmp[8];
    } else {      // stage B from k-major fc_w (transpose into LDS, coalesced n)
      const int n = tid & 255, kh = (tid >> 8) << 4;
      unsigned short tmp[16] __attribute__((aligned(16)));
#pragma unroll
      for (int i = 0; i < 16; ++i) {
        int kk = kc + kh + i;
        float v = 0.f;
        if (kk < kc1 && n < 256) v = fcw[(long)kk * 256 + n];
        tmp[i] = f2bf(v);
      }
      ((int4*)&Bl[n][kh])[0] = *(int4*)&tmp[0];
      ((int4*)&Bl[n][kh])[1] = *(int4*)&tmp[8];
    }
    __syncthreads();
    bf16x8 af[4], bfv[8];
#pragma unroll
    for (int i = 0; i < 4; ++i) af[i] = *(const bf16x8*)&Al[wm*64 + i*16 + ln][kq*8];
#pragma unroll
    for (int j = 0; j < 8; ++j) bfv[j] = *(const bf16x8*)&Bl[wn*128 + j*16 + ln][kq*8];
#pragma unroll
    for (int i = 0; i < 4; ++i)
#pragma unroll
      for (int j = 0; j < 8; ++j)
        acc[i][j] = __builtin_amdgcn_mfma_f32_16x16x32_bf16(af[i], bfv[j], acc[i][j], 0, 0, 0);
  }
#pragma unroll
  for (int i = 0; i < 4; ++i)
#pragma unroll
    for (int j = 0; j < 8; ++j)
#pragma unroll
      for (int r = 0; r < 4; ++r) {
        int gm = m0 + wm*64 + i*16 + kq*4 + r;
        int gn = n0 + wn*128 + j*16 + ln;
        if (gn < N) unsafeAtomicAdd(&C[(long)gm * ldc + gn], acc[i][j][r]);
      }
}

// ---------------- gemv3: EXTRA[v][a] = sum_k {tmpl0,tmpl1,fcb}[k]*redw[a][k]
__global__ __launch_bounds__(256)
void gemv3(const float* __restrict__ redw, const float* __restrict__ tmpl,
           const float* __restrict__ fcb, float* __restrict__ extra)
{
  const int tid = threadIdx.x;
  const int a0 = blockIdx.x * 8;
  const long k0 = (long)blockIdx.y * 8764;
  const long k1 = (k0 + 8764 < (long)VD) ? (k0 + 8764) : (long)VD;
  float s[3][8] = {};
  for (long k = k0 + tid; k < k1; k += 256) {
    const float c0 = tmpl[k], c1 = tmpl[(long)VD + k], cb2 = fcb[k];
#pragma unroll
    for (int r = 0; r < 8; ++r) {
      const float w = redw[(long)(a0 + r) * VD + k];
      s[0][r] += c0 * w; s[1][r] += c1 * w; s[2][r] += cb2 * w;
    }
  }
#pragma unroll
  for (int v = 0; v < 3; ++v)
#pragma unroll
    for (int r = 0; r < 8; ++r) {
      float x = s[v][r];
#pragma unroll
      for (int o = 32; o > 0; o >>= 1) x += __shfl_down(x, o);
      if ((tid & 63) == 0) unsafeAtomicAdd(&extra[v * 768 + a0 + r], x);
    }
}

// ---------------- merged transposes (+red_b fold) + GF odd-row fixup --------
static __device__ __forceinline__ void transpose_body(
    const float* src, int lds, float* dst, int ldd,
    int rows, int cols, const float* bias, int bx, int by)
{
  __shared__ float tile[32][33];
  const int rb = bx * 32, cb = by * 32;
  const int tx = threadIdx.x & 31, ty = threadIdx.x >> 5;
  for (int yy = ty; yy < 32; yy += 8) {
    int c = cb + yy, r = rb + tx;
    tile[yy][tx] = (c < cols && r < rows) ? src[(long)c * lds + r] : 0.f;
  }
  __syncthreads();
  for (int yy = ty; yy < 32; yy += 8) {
    int r = rb + yy, c = cb + tx;
    if (r < rows && c < cols)
      dst[(long)r * ldd + c] = tile[tx][yy] + (bias ? bias[c] : 0.f);
  }
}

__global__ void transpose_merged(const float* __restrict__ OUTG,
                                 const float* __restrict__ OUTM,
                                 const float* __restrict__ extra,
                                 const float* __restrict__ redb,
                                 float* __restrict__ GF, float* __restrict__ MT)
{
  if (blockIdx.z == 0) {
    transpose_body(OUTG, 1024, GF, 768, 1024, 768, redb, blockIdx.x, blockIdx.y);
  } else {
    if (blockIdx.x < 8) {
      transpose_body(OUTM, 256, MT, 768, 256, 768, nullptr, blockIdx.x, blockIdx.y);
    } else if (blockIdx.x == 8 && blockIdx.y == 0) {
      for (int i = threadIdx.x; i < 3 * 768; i += 256) {
        const int b = i / 768, a = i - b * 768;
        GF[(long)(1024 + b) * 768 + a] = extra[i] + redb[a];
      }
    }
  }
}

// ---------------- merged small GEMMs (gihs / PM / M2) -----------------------
__global__ __launch_bounds__(256, 2)
void gemm128x3(const float* __restrict__ hs, const float* __restrict__ wih0,
               float* __restrict__ GIHS, const float* __restrict__ bih0,
               const float* __restrict__ GF, float* __restrict__ PM,
               const float* __restrict__ MT, float* __restrict__ M2)
{
  const float *A, *B, *bias = nullptr; float* C;
  int lda, ldb, M, N, K; long ldc;
  if (blockIdx.z == 0) {
    if (blockIdx.x >= 8) return;
    A = hs; lda = 768; B = wih0; ldb = 1536; C = GIHS; ldc = 768; bias = bih0;
    M = 1024; N = 768; K = 768;
  } else if (blockIdx.z == 1) {
    A = GF; lda = 768; B = wih0 + 768; ldb = 1536; C = PM; ldc = 768;
    M = 1027; N = 768; K = 768;
  } else {
    if (blockIdx.x >= 6 || blockIdx.y >= 2) return;
    A = wih0 + 768; lda = 1536; B = MT; ldb = 768; C = M2; ldc = 256;
    M = 768; N = 256; K = 768;
  }
  __shared__ unsigned short Al[128][40];
  __shared__ unsigned short Bl[128][40];
  const int tid = threadIdx.x;
  const int m0 = blockIdx.x * 128, n0 = blockIdx.y * 128;
  const int wave = tid >> 6, lane = tid & 63;
  const int wm = wave >> 1, wn = wave & 1;
  const int kq = lane >> 4, ln = lane & 15;
  f32x4 acc[4][4] = {};
  for (int kc = 0; kc < K; kc += 32) {
    __syncthreads();
    {
      const int m = tid >> 1, kh = (tid & 1) << 4;
      unsigned short tmp[16] __attribute__((aligned(16)));
      const bool mok = (m0 + m) < M;
      if (mok) {
        const float4* ap4 = (const float4*)(A + (long)(m0 + m) * lda + kc + kh);
#pragma unroll
        for (int i = 0; i < 4; ++i) {
          float4 v = ap4[i];
          tmp[4*i+0] = f2bf(v.x); tmp[4*i+1] = f2bf(v.y);
          tmp[4*i+2] = f2bf(v.z); tmp[4*i+3] = f2bf(v.w);
        }
      } else {
#pragma unroll
        for (int i = 0; i < 16; ++i) tmp[i] = 0;
      }
      ((int4*)&Al[m][kh])[0] = *(int4*)&tmp[0];
      ((int4*)&Al[m][kh])[1] = *(int4*)&tmp[8];
      const int n = m;
      unsigned short tmb[16] __attribute__((aligned(16)));
      const bool nok = (n0 + n) < N;
      if (nok) {
        const float4* bp4 = (const float4*)(B + (long)(n0 + n) * ldb + kc + kh);
#pragma unroll
        for (int i = 0; i < 4; ++i) {
          float4 v = bp4[i];
          tmb[4*i+0] = f2bf(v.x); tmb[4*i+1] = f2bf(v.y);
          tmb[4*i+2] = f2bf(v.z); tmb[4*i+3] = f2bf(v.w);
        }
      } else {
#pragma unroll
        for (int i = 0; i < 16; ++i) tmb[i] = 0;
      }
      ((int4*)&Bl[n][kh])[0] = *(int4*)&tmb[0];
      ((int4*)&Bl[n][kh])[1] = *(int4*)&tmb[8];
    }
    __syncthreads();
    bf16x8 af[4], bfv[4];
#pragma unroll
    for (int i = 0; i < 4; ++i) af[i]  = *(const bf16x8*)&Al[wm*64 + i*16 + ln][kq*8];
#pragma unroll
    for (int j = 0; j < 4; ++j) bfv[j] = *(const bf16x8*)&Bl[wn*64 + j*16 + ln][kq*8];
#pragma unroll
    for (int i = 0; i < 4; ++i)
#pragma unroll
      for (int j = 0; j < 4; ++j)
        acc[i][j] = __builtin_amdgcn_mfma_f32_16x16x32_bf16(af[i], bfv[j], acc[i][j], 0, 0, 0);
  }
#pragma unroll
  for (int i = 0; i < 4; ++i)
#pragma unroll
    for (int j = 0; j < 4; ++j)
#pragma unroll
      for (int r = 0; r < 4; ++r) {
        const int gm = m0 + wm*64 + i*16 + kq*4 + r;
        const int gn = n0 + wn*64 + j*16 + ln;
        if (gm < M && gn < N) {
          float v = acc[i][j][r];
          if (bias) v += bias[gn];
          C[(long)gm * ldc + gn] = v;
        }
      }
}

// ---------------- fused recurrence + fc GEMM --------------------------------
struct ProdLds {
  float wq[24][260], wh0s[24][260], wi1s[24][260], wh1s[24][260];
  float h0c[2][256], h1c[2][256];
  float dotsS[2][2][3][8];
  int tfl[TT];
};
struct ConsLds {
  unsigned short As[128][264];   // full A tile (bf16 h1), K=256 (+8 pad)
  unsigned short Bl[128][40];    // staged B (fcw), 32 k per stage
  float wred[8];
};

#define HALF_DOTS(W, H, MS)                                                   \
  {                                                                           \
    const int g8_ = tid >> 3, l8_ = tid & 7;                                  \
    if (g8_ < 48) {                                                           \
      const int row_ = g8_ >> 1, bb_ = g8_ & 1;                               \
      const float4* w4_ = (const float4*)&(W)[row_][0];                       \
      const float4* h4_ = (const float4*)&(H)[bb_][0];                        \
      float s_ = 0.f;                                                         \
      _Pragma("unroll")                                                       \
      for (int i = 0; i < 8; ++i) {                                           \
        const float4 a_ = w4_[i * 8 + l8_], h_ = h4_[i * 8 + l8_];            \
        s_ += a_.x * h_.x + a_.y * h_.y + a_.z * h_.z + a_.w * h_.w;          \
      }                                                                       \
      s_ += __shfl_xor(s_, 1); s_ += __shfl_xor(s_, 2); s_ += __shfl_xor(s_, 4); \
      if (l8_ == 0) dotsS[MS][bb_][row_ >> 3][row_ & 7] = s_;                 \
    }                                                                         \
  }

#define POLL_ISSUE(buf, var)                                                  \
  unsigned long long var = __hip_atomic_load(&(buf)[tid], __ATOMIC_RELAXED, __HIP_MEMORY_SCOPE_AGENT);
#define POLL_FINISH(buf, var, dstLds, want)                                   \
  {                                                                           \
    const unsigned w_ = (unsigned)(want); int sp_ = 0;                        \
    while ((unsigned)(var >> 32) < w_ && ++sp_ < (1 << 15)) {                 \
      __builtin_amdgcn_s_sleep(1);                                            \
      var = __hip_atomic_load(&(buf)[tid], __ATOMIC_RELAXED, __HIP_MEMORY_SCOPE_AGENT); \
    }                                                                         \
    ((float*)dstLds)[tid] = __uint_as_float((unsigned)var);                   \
  }
#define POLLP(buf, dstLds, want)                                              \
  { POLL_ISSUE(buf, pw_); POLL_FINISH(buf, pw_, dstLds, want); }

__global__ __launch_bounds__(512, 1)
void k3_fused(const float* __restrict__ gihs, const float* __restrict__ Pm,
              const float* __restrict__ M2m,
              const float* __restrict__ whh0, const float* __restrict__ bhh0,
              const float* __restrict__ wih1, const float* __restrict__ bih1,
              const float* __restrict__ whh1, const float* __restrict__ bhh1,
              const int* __restrict__ tfm,
              unsigned short* __restrict__ h1sb,
              unsigned long long* __restrict__ h0p, unsigned long long* __restrict__ h1p,
              unsigned* __restrict__ prog,
              const float* __restrict__ fcw, const float* __restrict__ fcb,
              const float* __restrict__ vert,
              float* __restrict__ out, float* __restrict__ lossp)
{
  __shared__ union { ProdLds p; ConsLds c; } U;
  const int tid = threadIdx.x;

  if (blockIdx.x >= 32) {
    // ================= CONSUMER: fc GEMM tile sweep ========================
    auto& C = U.c;
    const int idx = blockIdx.x - 32;        // 0..223
    int tx, memb, cnt;
    if (idx < 24)      { tx = 0; memb = (idx)      >> 1; cnt = 12; }
    else if (idx < 48) { tx = 1; memb = (idx - 24) >> 1; cnt = 12; }
    else if (idx < 96) { tx = 2; memb = (idx - 48) >> 1; cnt = 24; }
    else               { tx = 3; memb = (idx - 96) >> 1; cnt = 64; }
    const int b = idx & 1;
    const int nt0 = memb * 548 / cnt, nt1 = (memb + 1) * 548 / cnt;
    if (nt0 >= nt1) return;
    const unsigned want = (unsigned)((tx + 1) * 128);
    if (tid < 32) {
      int sp = 0;
      while (__hip_atomic_load(&prog[tid * 16], __ATOMIC_RELAXED, __HIP_MEMORY_SCOPE_AGENT) < want) {
        if (++sp > (1 << 14)) break;
        for (int j = 0; j < 16; ++j) __builtin_amdgcn_s_sleep(15);
      }
    }
    __syncthreads();
    const long rbase = (long)b * 512 + (long)tx * 128;
    {
      const unsigned long long* src = (const unsigned long long*)(h1sb + rbase * 256);
#pragma unroll
      for (int i = 0; i < 16; ++i) {
        const int u = tid * 16 + i;
        unsigned long long v = __hip_atomic_load(&src[u], __ATOMIC_RELAXED, __HIP_MEMORY_SCOPE_AGENT);
        const int row = u >> 6, c4 = u & 63;
        *(unsigned long long*)&C.As[row][c4 * 4] = v;
      }
    }
    __syncthreads();
    const int wave = tid >> 6, lane = tid & 63;
    const int wm = wave >> 2, wn = wave & 3;
    const int kq = lane >> 4, ln = lane & 15;
    for (int nt = nt0; nt < nt1; ++nt) {
      const int n0 = nt * 128;
      f32x4 acc[4][2] = {};
#pragma unroll 1
      for (int ks = 0; ks < 8; ++ks) {
        __syncthreads();
        {
          const int rn = tid >> 2, kh = (tid & 3) * 8;
          const int gn = n0 + rn;
          unsigned short tmb[8] __attribute__((aligned(16)));
          if (gn < VD) {
            const float4* bp = (const float4*)&fcw[(long)gn * 256 + ks * 32 + kh];
            float4 v0 = bp[0], v1 = bp[1];
            tmb[0] = f2bf(v0.x); tmb[1] = f2bf(v0.y); tmb[2] = f2bf(v0.z); tmb[3] = f2bf(v0.w);
            tmb[4] = f2bf(v1.x); tmb[5] = f2bf(v1.y); tmb[6] = f2bf(v1.z); tmb[7] = f2bf(v1.w);
          } else {
#pragma unroll
            for (int i = 0; i < 8; ++i) tmb[i] = 0;
          }
          *(int4*)&C.Bl[rn][kh] = *(int4*)tmb;
        }
        __syncthreads();
        bf16x8 af[4], bfv[2];
#pragma unroll
        for (int i = 0; i < 4; ++i)
          af[i] = *(const bf16x8*)&C.As[wm*64 + i*16 + ln][ks*32 + kq*8];
#pragma unroll
        for (int j = 0; j < 2; ++j)
          bfv[j] = *(const bf16x8*)&C.Bl[wn*32 + j*16 + ln][kq*8];
#pragma unroll
        for (int i = 0; i < 4; ++i)
#pragma unroll
          for (int j = 0; j < 2; ++j)
            acc[i][j] = __builtin_amdgcn_mfma_f32_16x16x32_bf16(af[i], bfv[j], acc[i][j], 0, 0, 0);
      }
      float ls = 0.f;
#pragma unroll
      for (int i = 0; i < 4; ++i)
#pragma unroll
        for (int j = 0; j < 2; ++j)
#pragma unroll
          for (int r = 0; r < 4; ++r) {
            const int gmL = wm*64 + i*16 + kq*4 + r;
            const int gn = n0 + wn*32 + j*16 + ln;
            if (gn < VD) {
              const float v = acc[i][j][r] + fcb[gn];
              const long grow = rbase + gmL;
              out[grow * VD + gn] = v;
              const float dd = v - vert[grow * VD + gn];
              ls += dd * dd;
            }
          }
#pragma unroll
      for (int o = 32; o > 0; o >>= 1) ls += __shfl_down(ls, o);
      if (lane == 0) C.wred[wave] = ls;
      __syncthreads();
      if (tid == 0) {
        float s = 0.f;
#pragma unroll
        for (int w = 0; w < 8; ++w) s += C.wred[w];
        lossp[(tx * 2 + b) * 548 + nt] = s;
      }
      __syncthreads();
    }
    return;
  }

  // ================= PRODUCER: 32-WG tagged-u64 GRU recurrence =============
  float (&wq)[24][260]   = U.p.wq;
  float (&wh0s)[24][260] = U.p.wh0s;
  float (&wi1s)[24][260] = U.p.wi1s;
  float (&wh1s)[24][260] = U.p.wh1s;
  float (&h0c)[2][256]   = U.p.h0c;
  float (&h1c)[2][256]   = U.p.h1c;
  float (&dotsS)[2][2][3][8] = U.p.dotsS;
  int   (&tfl)[TT]       = U.p.tfl;
  const int wg = blockIdx.x;
  const int j0 = wg * 8;

  {
    const int col = tid & 255, rh = tid >> 8;
    for (int row = rh; row < 24; row += 2) {
      const int g = row >> 3, jj = row & 7;
      const long gr = g * 256 + j0 + jj;
      wq[row][col]   = M2m[gr * 256 + col];
      wh0s[row][col] = whh0[gr * 256 + col];
      wi1s[row][col] = wih1[gr * 256 + col];
      wh1s[row][col] = whh1[gr * 256 + col];
    }
  }
  ((float*)h0c)[tid] = 0.f;
  ((float*)h1c)[tid] = 0.f;
  if (tid < TT) tfl[tid] = tfm[tid];

  const int cb = tid >> 3, cjj = tid & 7, cj = j0 + cjj;
  float bh0v[3], bi1v[3], bh1v[3], d2v[3];
  if (tid < 16) {
#pragma unroll
    for (int g = 0; g < 3; ++g) {
      bh0v[g] = bhh0[g*256 + cj];
      bi1v[g] = bih1[g*256 + cj];
      bh1v[g] = bhh1[g*256 + cj];
      d2v[g]  = Pm[(long)1026 * 768 + g*256 + cj];
    }
  }
  __syncthreads();

  const int wave = tid >> 6;
  float gihsv[3], piv[3];
  if (tid < 16) {
#pragma unroll
    for (int g = 0; g < 3; ++g) {
      gihsv[g] = gihs[((long)cb * TT) * 768 + g*256 + cj];
      piv[g]   = Pm[(long)(1024 + cb) * 768 + g*256 + cj];
    }
  }
  for (int t = 0; t < TT; ++t) {
    const int tfprev = (t == 0) ? 1 : tfl[t - 1];
    // ---- phase A: gh = h0_{t-1}@whh0^T (always); q = h1_{t-1}@M2^T (tf=0)
    if (!tfprev) {
      POLL_ISSUE(h1p + (t & 1) * 512, pb);
      HALF_DOTS(wh0s, h0c, 1);
      POLL_FINISH(h1p + (t & 1) * 512, pb, h1c, t);
      __syncthreads();
      HALF_DOTS(wq, h1c, 0);
    } else {
      HALF_DOTS(wh0s, h0c, 1);
    }
    __syncthreads();
    if (tid < 16) {
      float gi[3], gh[3];
#pragma unroll
      for (int g = 0; g < 3; ++g) {
        const float q = tfprev ? 0.f : (dotsS[0][cb][g][cjj] + d2v[g]);
        gi[g] = gihsv[g] + (tfprev ? piv[g] : q);
        gh[g] = dotsS[1][cb][g][cjj] + bh0v[g];
      }
      const float rr = 1.f / (1.f + __expf(-(gi[0] + gh[0])));
      const float zz = 1.f / (1.f + __expf(-(gi[1] + gh[1])));
      const float nn = tanhf(gi[2] + rr * gh[2]);
      const float h0n = (1.f - zz) * nn + zz * h0c[cb][cj];
      const unsigned long long pk =
          ((unsigned long long)(unsigned)(t + 1) << 32) | (unsigned long long)__float_as_uint(h0n);
      __hip_atomic_store(&h0p[((t + 1) & 1) * 512 + cb * 256 + cj], pk,
                         __ATOMIC_RELAXED, __HIP_MEMORY_SCOPE_AGENT);
    }
    if (tid < 16 && t + 1 < TT) {
#pragma unroll
      for (int g = 0; g < 3; ++g) {
        gihsv[g] = gihs[((long)cb * TT + (t + 1)) * 768 + g*256 + cj];
        piv[g]   = Pm[((long)cb * TT + t) * 768 + g*256 + cj];
      }
    }
    __syncthreads();   // phase-A readers of h0c/h1c done; dotsS consumed
    // ---- phase B: h0 exchange hidden under the independent wh1s half ------
    POLL_ISSUE(h0p + ((t + 1) & 1) * 512, hw);     // h0_t in flight
    if (tfprev) {
      POLL_ISSUE(h1p + (t & 1) * 512, qb);         // h1_{t-1}: landed long ago
      POLL_FINISH(h1p + (t & 1) * 512, qb, h1c, t);
      __syncthreads();                             // h1c ready
    }
    HALF_DOTS(wh1s, h1c, 1);                       // overlaps h0 RTT
    POLL_FINISH(h0p + ((t + 1) & 1) * 512, hw, h0c, t + 1);
    __syncthreads();                               // h0c ready
    HALF_DOTS(wi1s, h0c, 0);
    __syncthreads();
    if (tid < 16) {
      float gi[3], gh[3];
#pragma unroll
      for (int g = 0; g < 3; ++g) {
        gi[g] = dotsS[0][cb][g][cjj] + bi1v[g];
        gh[g] = dotsS[1][cb][g][cjj] + bh1v[g];
      }
      const float rr = 1.f / (1.f + __expf(-(gi[0] + gh[0])));
      const float zz = 1.f / (1.f + __expf(-(gi[1] + gh[1])));
      const float nn = tanhf(gi[2] + rr * gh[2]);
      const float h1n = (1.f - zz) * nn + zz * h1c[cb][cj];
      const unsigned hb = (unsigned)f2bf(h1n);
      asm volatile("global_store_short %0, %1, off sc0 sc1"
                   :: "v"(&h1sb[((long)cb * TT + t) * 256 + cj]), "v"(hb) : "memory");
      const unsigned long long pk =
          ((unsigned long long)(unsigned)(t + 1) << 32) | (unsigned long long)__float_as_uint(h1n);
      __hip_atomic_store(&h1p[((t + 1) & 1) * 512 + cb * 256 + cj], pk,
                         __ATOMIC_RELAXED, __HIP_MEMORY_SCOPE_AGENT);
    }
    if ((t & 15) == 15) {
      if (wave == 0) asm volatile("s_waitcnt vmcnt(0)" ::: "memory");
      if (tid == 0)
        __hip_atomic_store(&prog[wg * 16], (unsigned)(t + 1),
                           __ATOMIC_RELAXED, __HIP_MEMORY_SCOPE_AGENT);
    }
    __syncthreads();
  }
}

__global__ void loss_finalize(const float* __restrict__ lossp, int n, float* __restrict__ out) {
  __shared__ float red[256];
  float s = 0.f;
  for (int i = threadIdx.x; i < n; i += 256) s += lossp[i];
  red[threadIdx.x] = s;
  __syncthreads();
  for (int st = 128; st > 0; st >>= 1) {
    if (threadIdx.x < st) red[threadIdx.x] += red[threadIdx.x + st];
    __syncthreads();
  }
  if (threadIdx.x == 0) out[0] = red[0] * (1.0f / 71792640.0f);
}

// ---------------------------------------------------------------------------
extern "C" void kernel_launch(void* const* d_in, const int* in_sizes, int n_in,
                              void* d_out, int out_size, void* d_ws, size_t ws_size,
                              hipStream_t stream) {
  (void)in_sizes; (void)n_in; (void)out_size; (void)ws_size;
  const float* hs   = (const float*)d_in[0];
  const float* tmpl = (const float*)d_in[1];
  const float* vert = (const float*)d_in[2];
  const int*   tfm  = (const int*)  d_in[3];
  const float* wih0 = (const float*)d_in[4];
  const float* whh0 = (const float*)d_in[5];
  const float* bih0 = (const float*)d_in[6];
  const float* bhh0 = (const float*)d_in[7];
  const float* wih1 = (const float*)d_in[8];
  const float* whh1 = (const float*)d_in[9];
  const float* bih1 = (const float*)d_in[10];
  const float* bhh1 = (const float*)d_in[11];
  const float* fcw  = (const float*)d_in[12];
  const float* fcb  = (const float*)d_in[13];
  const float* redw = (const float*)d_in[14];
  const float* redb = (const float*)d_in[15];
  float* out = (float*)d_out;

  char* ws = (char*)d_ws;
  float*    LOSSP = (float*)(ws + 0);          // overlaps OUTG (dead after transpose)
  float*    OUTG  = (float*)(ws + 0);          // [768][1024]
  float*    OUTM  = (float*)(ws + 3145728);    // [768][256]
  float*    EXTRA = (float*)(ws + 3932160);    // [3][768]
  unsigned long long* H0P = (unsigned long long*)(ws + 3941376); // [2][512]
  unsigned long long* H1P = (unsigned long long*)(ws + 3949568); // [2][512]
  unsigned* PROG  = (unsigned*)(ws + 3957760); // 32 slots x 16 stride
  float*    GF    = (float*)(ws + 3960064);    // [1027][768]
  float*    MT    = (float*)(ws + 7115776);    // [256][768]
  float*    GIHS  = (float*)(ws + 7902208);    // [1024][768]
  float*    PM    = (float*)(ws + 11047936);   // [1027][768]
  float*    M2    = (float*)(ws + 14203648);   // [768][256]
  unsigned short* H1SB = (unsigned short*)(ws + 14990080); // [1024][256] bf16

  // zero split-K accumulators + EXTRA + tag buffers + progress (every call)
  hipMemsetAsync(d_ws, 0, 3960064, stream);

  // merged big V-contractions (252 + 63 blocks in one grid, single pass-ish)
  bigk_merged<<<dim3(5, 3, 21), 512, 0, stream>>>(redw, vert, fcw, OUTG, OUTM, 3344);
  gemv3<<<dim3(96, 8), 256, 0, stream>>>(redw, tmpl, fcb, EXTRA);

  // merged transposes (+red_b fold) + GF odd-row fixup
  transpose_merged<<<dim3(32, 24, 2), 256, 0, stream>>>(OUTG, OUTM, EXTRA, redb, GF, MT);

  // merged small GEMMs: gihs / PM / M2
  gemm128x3<<<dim3(9, 6, 3), 256, 0, stream>>>(hs, wih0, GIHS, bih0, GF, PM, MT, M2);

  // fused recurrence (32 producer WGs) + fc GEMM/MSE (224 consumer WGs)
  k3_fused<<<256, 512, 0, stream>>>(GIHS, PM, M2, whh0, bhh0, wih1, bih1, whh1, bhh1,
                                    tfm, H1SB, H0P, H1P, PROG,
                                    fcw, fcb, vert, out, LOSSP);

  loss_finalize<<<1, 256, 0, stream>>>(LOSSP, 4384, out + 71792640L);
}